// Round 4
// baseline (1428.383 us; speedup 1.0000x reference)
//
#include <hip/hip_runtime.h>
#include <math.h>

#define KG_E  50000
#define KG_R  500
#define E_DIM 300
#define CAP   1024
#define LRELU 0.2f

// MFMA GEMM geometry: Y[M,600(pad 640)] = X[M,300(pad 320)] @ Wcat
#define NK    10          // K-steps of 32 (K padded 300->320)
#define NT    40          // 16-col n-tiles (600 -> 640)
#define XS_LD 328         // LDS row stride in bf16 (+8 pad)

typedef __attribute__((ext_vector_type(8))) short bf16x8;
typedef __attribute__((ext_vector_type(4))) float f32x4;

__device__ __forceinline__ unsigned short f2bf(float x) {
  union { float f; unsigned u; } v; v.f = x;
  unsigned r = v.u + 0x7FFFu + ((v.u >> 16) & 1u);
  return (unsigned short)(r >> 16);
}

// ---------------- compaction: both r-matrices, chunked, ballot-aggregated --
#define NCH 5                      // chunks per row (KG_E/NCH = 10000)
__global__ __launch_bounds__(256) void k_compact2(
    const float* __restrict__ r_head, const float* __restrict__ r_tail,
    const float* __restrict__ be_L, const float* __restrict__ be_R,
    int* __restrict__ lidx, float* __restrict__ lsval,
    int* __restrict__ fill, float* __restrict__ rsum)
{
  int m = blockIdx.z;
  int r = blockIdx.y;
  const float* rowp = (m ? r_tail : r_head) + (size_t)r * KG_E;
  const float* be   = m ? be_R : be_L;
  int slot = m * KG_R + r;
  int*   li = lidx  + (size_t)slot * CAP;
  float* lv = lsval + (size_t)slot * CAP;
  int lane = threadIdx.x & 63;
  const int CH = KG_E / NCH;       // 10000
  int c0 = blockIdx.x * CH;
  const float4* rp4 = (const float4*)(rowp + c0);
  float lsum = 0.f;
  for (int i = threadIdx.x; i < CH / 4; i += 256) {
    float4 f = rp4[i];
    float vs[4] = {f.x, f.y, f.z, f.w};
    #pragma unroll
    for (int q = 0; q < 4; ++q) {
      float v = vs[q];
      lsum += v;
      bool nz = (v != 0.f);
      unsigned long long mask = __ballot(nz);
      if (mask) {
        int leader = (int)__ffsll(mask) - 1;
        int base = 0;
        if (lane == leader) base = atomicAdd(&fill[slot], (int)__popcll(mask));
        base = __shfl(base, leader, 64);
        if (nz) {
          int pos = base + (int)__popcll(mask & ((1ULL << lane) - 1));
          if (pos < CAP) {
            int e = c0 + 4 * i + q;
            li[pos] = e;
            lv[pos] = v * be[e];
          }
        }
      }
    }
  }
  #pragma unroll
  for (int off = 32; off > 0; off >>= 1) lsum += __shfl_xor(lsum, off, 64);
  if (lane == 0 && lsum != 0.f) atomicAdd(&rsum[slot], lsum);
}

__global__ __launch_bounds__(256) void k_rmeta(
    const int* __restrict__ fill, const float* __restrict__ rsum,
    int* __restrict__ cnt, float* __restrict__ inv)
{
  int i = blockIdx.x * 256 + threadIdx.x;
  if (i < 2 * KG_R) {
    int c = fill[i];
    cnt[i] = c > CAP ? CAP : c;
    float s = rsum[i];
    inv[i] = (s == 0.f) ? 0.f : 1.f / s;
  }
}

// ---------------- r-layer: w[m][r][d] = relu(inv * sum sval*E[e,d]) * atten -
__global__ __launch_bounds__(320) void k_rlayer(
    const float* __restrict__ E, const int* __restrict__ lidx,
    const float* __restrict__ lsval, const int* __restrict__ cnt,
    const float* __restrict__ inv, const float* __restrict__ atten,
    float* __restrict__ w)
{
  int b = blockIdx.x;           // 0..2*KG_R-1
  int m = b / KG_R, r = b % KG_R;
  int d = threadIdx.x;
  if (d >= E_DIM) return;
  int n = cnt[m*KG_R + r];
  const int*   li = lidx  + (size_t)(m*KG_R + r) * CAP;
  const float* lv = lsval + (size_t)(m*KG_R + r) * CAP;
  float acc = 0.f;
  #pragma unroll 4
  for (int i = 0; i < n; ++i) {
    int e = li[i];
    float s = lv[i];
    acc += s * E[(size_t)e * E_DIM + d];
  }
  float v = acc * inv[m*KG_R + r];
  v = v > 0.f ? v : 0.f;
  w[(size_t)(m*KG_R + r) * E_DIM + d] = v * atten[m*E_DIM + d];
}

// ---------------- CSR build: histogram, scan, scatter ----------------------
__global__ __launch_bounds__(256) void k_hist(
    const int* __restrict__ rows, int* __restrict__ cnt, int n)
{
  int i = blockIdx.x * 256 + threadIdx.x;
  if (i < n) atomicAdd(&cnt[rows[i]], 1);
}

__global__ __launch_bounds__(1024) void k_scan(
    const int* __restrict__ cnt, int* __restrict__ start, int n)
{
  __shared__ int buf[1024];
  __shared__ int carry;
  if (threadIdx.x == 0) carry = 0;
  __syncthreads();
  for (int base = 0; base < n; base += 1024) {
    int i = base + threadIdx.x;
    int v = (i < n) ? cnt[i] : 0;
    buf[threadIdx.x] = v;
    __syncthreads();
    for (int ofs = 1; ofs < 1024; ofs <<= 1) {
      int t = (threadIdx.x >= ofs) ? buf[threadIdx.x - ofs] : 0;
      __syncthreads();
      buf[threadIdx.x] += t;
      __syncthreads();
    }
    if (i < n) start[i] = carry + buf[threadIdx.x] - v;
    __syncthreads();
    if (threadIdx.x == 1023) carry += buf[1023];
    __syncthreads();
  }
  if (threadIdx.x == 0) start[n] = carry;
}

__global__ __launch_bounds__(256) void k_scatter_eer(
    const int* __restrict__ eidx, const int* __restrict__ erel,
    const int* __restrict__ start, int* __restrict__ fill,
    int* __restrict__ scol, int* __restrict__ srel, int neer)
{
  int i = blockIdx.x * 256 + threadIdx.x;
  if (i >= neer) return;
  int row = eidx[i];
  int pos = start[row] + atomicAdd(&fill[row], 1);
  scol[pos] = eidx[neer + i];
  srel[pos] = erel[i];
}

__global__ __launch_bounds__(256) void k_scatter_adj(
    const int* __restrict__ aidx, const float* __restrict__ adata,
    const int* __restrict__ start, int* __restrict__ fill,
    int* __restrict__ scol, float* __restrict__ sval, int ne)
{
  int i = blockIdx.x * 256 + threadIdx.x;
  if (i >= ne) return;
  int row = aidx[i];
  int pos = start[row] + atomicAdd(&fill[row], 1);
  scol[pos] = aidx[ne + i];
  sval[pos] = adata[i];
}

// ---------------- attention, CSR row-parallel, fused finalize --------------
__global__ __launch_bounds__(256) void k_att_csr(
    const float* __restrict__ E, const float* __restrict__ w,
    const int* __restrict__ start, const int* __restrict__ scol,
    const int* __restrict__ srel, const float* __restrict__ base,
    float alpha, float* __restrict__ out, unsigned short* __restrict__ outb)
{
  int wave = threadIdx.x >> 6, lane = threadIdx.x & 63;
  int row = blockIdx.x * 4 + wave;
  if (row >= KG_E) return;
  int s = start[row], e = start[row + 1];
  float er[5], acc[5] = {0.f, 0.f, 0.f, 0.f, 0.f};
  #pragma unroll
  for (int c = 0; c < 5; ++c) {
    int d = lane + c * 64;
    er[c] = (d < E_DIM) ? E[(size_t)row * E_DIM + d] : 0.f;
  }
  float rs = 0.f;
  for (int j = s; j < e; ++j) {
    int col = scol[j], rel = srel[j];
    const float* ec = E + (size_t)col * E_DIM;
    const float* wh = w + (size_t)rel * E_DIM;
    const float* wt = w + (size_t)(KG_R + rel) * E_DIM;
    float ecv[5];
    float p = 0.f;
    #pragma unroll
    for (int c = 0; c < 5; ++c) {
      int d = lane + c * 64;
      if (d < E_DIM) {
        float b = ec[d];
        ecv[c] = b;
        p += er[c] * wh[d] + b * wt[d];
      } else ecv[c] = 0.f;
    }
    #pragma unroll
    for (int off = 32; off > 0; off >>= 1) p += __shfl_xor(p, off, 64);
    float la = p >= 0.f ? p : LRELU * p;
    float at = __expf(-la);
    rs += at;
    #pragma unroll
    for (int c = 0; c < 5; ++c) acc[c] += at * ecv[c];
  }
  float iv = (rs == 0.f) ? 0.f : 1.f / rs;
  #pragma unroll
  for (int c = 0; c < 5; ++c) {
    int d = lane + c * 64;
    if (d < E_DIM) {
      size_t i = (size_t)row * E_DIM + d;
      float v = acc[c] * iv;
      v = v > 0.f ? v : 0.f;
      float o = base[i] + alpha * v;
      out[i] = o;
      if (outb) outb[i] = f2bf(o);
    }
  }
}

// ---------------- spmm CSR row-parallel: Y[row] = sum val*X[col] -----------
__global__ __launch_bounds__(256) void k_spmm_csr(
    const float* __restrict__ X, const int* __restrict__ start,
    const int* __restrict__ scol, const float* __restrict__ sval,
    float* __restrict__ Y)
{
  int wave = threadIdx.x >> 6, lane = threadIdx.x & 63;
  int row = blockIdx.x * 4 + wave;
  if (row >= KG_E) return;
  int s = start[row], e = start[row + 1];
  float acc[5] = {0.f, 0.f, 0.f, 0.f, 0.f};
  for (int j = s; j < e; ++j) {
    int col = scol[j];
    float v = sval[j];
    const float* xp = X + (size_t)col * E_DIM;
    #pragma unroll
    for (int c = 0; c < 5; ++c) {
      int d = lane + c * 64;
      if (d < E_DIM) acc[c] += v * xp[d];
    }
  }
  #pragma unroll
  for (int c = 0; c < 5; ++c) {
    int d = lane + c * 64;
    if (d < E_DIM) Y[(size_t)row * E_DIM + d] = acc[c];
  }
}

// ---------------- pack W into MFMA B-fragment layout -----------------------
__global__ __launch_bounds__(64) void k_packW(
    const float* __restrict__ W1, const float* __restrict__ W2,
    unsigned short* __restrict__ Wp)
{
  int lane = threadIdx.x;
  int t = blockIdx.x, s = blockIdx.y;
  int c = t * 16 + (lane & 15);
  unsigned short v[8];
  #pragma unroll
  for (int j = 0; j < 8; ++j) {
    int k = s * 32 + (lane >> 4) * 8 + j;
    float x = 0.f;
    if (k < E_DIM && c < 2 * E_DIM)
      x = (c < E_DIM) ? W1[(size_t)k * E_DIM + c]
                      : W2[(size_t)k * E_DIM + (c - E_DIM)];
    v[j] = f2bf(x);
  }
  size_t base = ((size_t)(t * NK + s) * 64 + lane) * 8;
  #pragma unroll
  for (int j = 0; j < 8; ++j) Wp[base + j] = v[j];
}

// ---------------- fused dual-GEMM: {Y1,Y2} = Xb @ {gcnW1,hwWr} (bf16 MFMA) -
__global__ __launch_bounds__(256) void k_gemm2_mfma(
    const unsigned short* __restrict__ Xb, const unsigned short* __restrict__ Wp,
    float* __restrict__ Y1, float* __restrict__ Y2, int M)
{
  __shared__ unsigned short Xs[32][XS_LD];
  int tid = threadIdx.x;
  int r0 = blockIdx.x * 32;
  int nb = blockIdx.y;               // 0..4, 128 cols each

  for (int t = tid; t < 32 * (XS_LD / 2); t += 256) {
    int r = t / (XS_LD / 2), u = t % (XS_LD / 2);
    unsigned v = 0;
    int rg = r0 + r;
    if (rg < M && u < E_DIM / 2) v = ((const unsigned*)Xb)[(size_t)rg * (E_DIM / 2) + u];
    ((unsigned*)&Xs[0][0])[r * (XS_LD / 2) + u] = v;
  }
  __syncthreads();

  int wid = tid >> 6, lane = tid & 63;
  int wave_m = wid >> 1, wave_n = wid & 1;
  int rowA = wave_m * 16 + (lane & 15);
  int kgrp = (lane >> 4) * 8;
  int tb0 = nb * 8 + wave_n * 4;

  const bf16x8* wfrag = (const bf16x8*)Wp + (size_t)tb0 * (NK * 64) + lane;

  f32x4 acc[4] = {{0,0,0,0},{0,0,0,0},{0,0,0,0},{0,0,0,0}};
  #pragma unroll 2
  for (int ks = 0; ks < NK; ++ks) {
    bf16x8 a = *(const bf16x8*)&Xs[rowA][ks * 32 + kgrp];
    #pragma unroll
    for (int nt = 0; nt < 4; ++nt) {
      bf16x8 b = wfrag[(nt * NK + ks) * 64];
      acc[nt] = __builtin_amdgcn_mfma_f32_16x16x32_bf16(a, b, acc[nt], 0, 0, 0);
    }
  }

  int rbase = r0 + wave_m * 16 + ((lane >> 4) << 2);
  #pragma unroll
  for (int nt = 0; nt < 4; ++nt) {
    int c = (tb0 + nt) * 16 + (lane & 15);
    #pragma unroll
    for (int j = 0; j < 4; ++j) {
      int row = rbase + j;
      if (row < M) {
        float v = acc[nt][j];
        if (c < E_DIM)            Y1[(size_t)row * E_DIM + c] = v;
        else if (c < 2 * E_DIM)   Y2[(size_t)row * E_DIM + (c - E_DIM)] = v;
      }
    }
  }
}

// ---------------- highway: out = sig(gl+br)*relu(y) + (1-sig)*base ---------
__global__ __launch_bounds__(320) void k_highway(
    const float* __restrict__ base, const float* __restrict__ y,
    const float* __restrict__ gateLin, const float* __restrict__ br,
    float* __restrict__ out, unsigned short* __restrict__ outb)
{
  int r = blockIdx.x, d = threadIdx.x;
  if (d >= E_DIM) return;
  size_t i = (size_t)r * E_DIM + d;
  float g = 1.f / (1.f + __expf(-(gateLin[i] + br[d])));
  float yy = y[i]; yy = yy > 0.f ? yy : 0.f;
  float b = base[i];
  float o = g * yy + (1.f - g) * b;
  out[i] = o;
  if (outb) outb[i] = f2bf(o);
}

extern "C" void kernel_launch(void* const* d_in, const int* in_sizes, int n_in,
                              void* d_out, int out_size, void* d_ws, size_t ws_size,
                              hipStream_t stream)
{
  const float* primal      = (const float*)d_in[0];
  const float* r_head      = (const float*)d_in[1];
  const float* r_tail      = (const float*)d_in[2];
  const float* e_adj_data  = (const float*)d_in[3];
  const float* be_L        = (const float*)d_in[4];
  const float* be_R        = (const float*)d_in[5];
  const float* atten_r     = (const float*)d_in[6];
  const float* gcnW1       = (const float*)d_in[7];
  const float* hwWr        = (const float*)d_in[8];
  const float* hwbr        = (const float*)d_in[9];
  const int*   e_adj_index = (const int*)d_in[10];
  const int*   eer_idx     = (const int*)d_in[11];
  const int*   eer_rel     = (const int*)d_in[12];
  int ne   = in_sizes[10] / 2;
  int neer = in_sizes[11] / 2;

  char* ws = (char*)d_ws;
  size_t off = 0;
  auto take = [&](size_t bytes) {
    void* p = ws + off;
    off = (off + bytes + 255) & ~(size_t)255;
    return p;
  };
  int*   cnt      = (int*)  take((size_t)2 * KG_R * sizeof(int));
  float* inv      = (float*)take((size_t)2 * KG_R * sizeof(float));
  int*   rfill    = (int*)  take((size_t)2 * KG_R * sizeof(int));
  float* rsumb    = (float*)take((size_t)2 * KG_R * sizeof(float));
  int*   lidx     = (int*)  take((size_t)2 * KG_R * CAP * sizeof(int));
  float* lsv      = (float*)take((size_t)2 * KG_R * CAP * sizeof(float));
  float* wbuf     = (float*)take((size_t)2 * KG_R * E_DIM * sizeof(float));
  int*   hcnt     = (int*)  take((size_t)KG_E * sizeof(int));
  int*   hfill    = (int*)  take((size_t)KG_E * sizeof(int));
  int*   eer_start= (int*)  take((size_t)(KG_E + 1) * sizeof(int));
  int*   adj_start= (int*)  take((size_t)(KG_E + 1) * sizeof(int));
  int*   eer_scol = (int*)  take((size_t)neer * sizeof(int));
  int*   eer_srel = (int*)  take((size_t)neer * sizeof(int));
  int*   adj_scol = (int*)  take((size_t)ne * sizeof(int));
  float* adj_sval = (float*)take((size_t)ne * sizeof(float));
  unsigned short* Wp = (unsigned short*)take((size_t)NT * NK * 64 * 8 * sizeof(unsigned short));
  unsigned short* Xbf= (unsigned short*)take((size_t)KG_E * E_DIM * sizeof(unsigned short));
  float* D        = (float*)take((size_t)KG_E * E_DIM * sizeof(float));
  float* E        = (float*)take((size_t)KG_E * E_DIM * sizeof(float));
  float* F        = (float*)take((size_t)KG_E * E_DIM * sizeof(float));
  float* G        = (float*)take((size_t)KG_E * E_DIM * sizeof(float));
  float* out      = (float*)d_out;
  (void)ws_size; (void)n_in; (void)out_size;

  int eg = (neer + 255) / 256;
  int ag = (ne + 255) / 256;

  // ---- build CSR for eer edges ----
  hipMemsetAsync(hcnt, 0, (size_t)KG_E * sizeof(int), stream);
  k_hist<<<eg, 256, 0, stream>>>(eer_idx, hcnt, neer);
  k_scan<<<1, 1024, 0, stream>>>(hcnt, eer_start, KG_E);
  hipMemsetAsync(hfill, 0, (size_t)KG_E * sizeof(int), stream);
  k_scatter_eer<<<eg, 256, 0, stream>>>(eer_idx, eer_rel, eer_start, hfill,
                                        eer_scol, eer_srel, neer);
  // ---- build CSR for e_adj edges ----
  hipMemsetAsync(hcnt, 0, (size_t)KG_E * sizeof(int), stream);
  k_hist<<<ag, 256, 0, stream>>>(e_adj_index, hcnt, ne);
  k_scan<<<1, 1024, 0, stream>>>(hcnt, adj_start, KG_E);
  hipMemsetAsync(hfill, 0, (size_t)KG_E * sizeof(int), stream);
  k_scatter_adj<<<ag, 256, 0, stream>>>(e_adj_index, e_adj_data, adj_start, hfill,
                                        adj_scol, adj_sval, ne);

  // ---- compact r_head/r_tail (chunked, ballot-aggregated) + pack weights ----
  hipMemsetAsync(rfill, 0, (size_t)2 * KG_R * sizeof(int), stream);
  hipMemsetAsync(rsumb, 0, (size_t)2 * KG_R * sizeof(float), stream);
  k_compact2<<<dim3(NCH, KG_R, 2), 256, 0, stream>>>(r_head, r_tail, be_L, be_R,
                                                     lidx, lsv, rfill, rsumb);
  k_rmeta<<<(2 * KG_R + 255) / 256, 256, 0, stream>>>(rfill, rsumb, cnt, inv);
  k_packW<<<dim3(NT, NK), 64, 0, stream>>>(gcnW1, hwWr, Wp);

  int rg = (KG_E + 3) / 4;

  // ---- attention layer 1: e1 = primal + 0.1*att(primal) -> E ----
  k_rlayer<<<2 * KG_R, 320, 0, stream>>>(primal, lidx, lsv, cnt, inv, atten_r, wbuf);
  k_att_csr<<<rg, 256, 0, stream>>>(primal, wbuf, eer_start, eer_scol, eer_srel,
                                    primal, 0.1f, E, (unsigned short*)nullptr);
  // ---- attention layer 2: e2 = primal + 0.3*att(e1) -> D (+ bf16 Xbf) ----
  k_rlayer<<<2 * KG_R, 320, 0, stream>>>(E, lidx, lsv, cnt, inv, atten_r, wbuf);
  k_att_csr<<<rg, 256, 0, stream>>>(E, wbuf, eer_start, eer_scol, eer_srel,
                                    primal, 0.3f, D, Xbf);

  // ---- GCN + highway 1: F = e2@gcnW1, G = e2@hwWr; g2 -> E (+ bf16 Xbf) ----
  dim3 gg((KG_E + 31) / 32, 5);
  k_gemm2_mfma<<<gg, 256, 0, stream>>>(Xbf, Wp, F, G, KG_E);
  k_spmm_csr<<<rg, 256, 0, stream>>>(F, adj_start, adj_scol, adj_sval, out);
  k_highway<<<KG_E, 320, 0, stream>>>(D, out, G, hwbr, E, Xbf);

  // ---- GCN + highway 2: F = g2@gcnW1, G = g2@hwWr; out = highway ----
  k_gemm2_mfma<<<gg, 256, 0, stream>>>(Xbf, Wp, F, G, KG_E);
  k_spmm_csr<<<rg, 256, 0, stream>>>(F, adj_start, adj_scol, adj_sval, out);
  k_highway<<<KG_E, 320, 0, stream>>>(E, out, G, hwbr, out, (unsigned short*)nullptr);
}

// Round 5
// 1240.445 us; speedup vs baseline: 1.1515x; 1.1515x over previous
//
#include <hip/hip_runtime.h>
#include <math.h>

#define KG_E  50000
#define KG_R  500
#define E_DIM 300
#define CAP   1024
#define LRELU 0.2f

// MFMA GEMM geometry: Y[M,600(pad 640)] = X[M,300(pad 320)] @ Wcat
#define NK    10          // K-steps of 32 (K padded 300->320)
#define NT    40          // 16-col n-tiles (600 -> 640)
#define XS_LD 328         // LDS row stride in bf16 (+8 pad)

typedef __attribute__((ext_vector_type(8))) short bf16x8;
typedef __attribute__((ext_vector_type(4))) float f32x4;

__device__ __forceinline__ unsigned short f2bf(float x) {
  union { float f; unsigned u; } v; v.f = x;
  unsigned r = v.u + 0x7FFFu + ((v.u >> 16) & 1u);
  return (unsigned short)(r >> 16);
}

// ---------------- compaction: LDS-staged, one global atomic per block ------
#define NCH 5                      // chunks per row (KG_E/NCH = 10000)
#define SCAP 1024                  // LDS staging capacity (mean occupancy ~100)
__global__ __launch_bounds__(256) void k_compact2(
    const float* __restrict__ r_head, const float* __restrict__ r_tail,
    const float* __restrict__ be_L, const float* __restrict__ be_R,
    int* __restrict__ lidx, float* __restrict__ lsval,
    int* __restrict__ fill, float* __restrict__ rsum)
{
  __shared__ int   ls_e[SCAP];
  __shared__ float ls_v[SCAP];
  __shared__ int   ls_cnt;
  __shared__ float ls_sum;
  __shared__ int   ls_base;
  int m = blockIdx.z;
  int r = blockIdx.y;
  const float* rowp = (m ? r_tail : r_head) + (size_t)r * KG_E;
  const float* be   = m ? be_R : be_L;
  int slot = m * KG_R + r;
  int lane = threadIdx.x & 63;
  if (threadIdx.x == 0) { ls_cnt = 0; ls_sum = 0.f; }
  __syncthreads();

  const int CH = KG_E / NCH;       // 10000
  int c0 = blockIdx.x * CH;
  const float4* rp4 = (const float4*)(rowp + c0);
  float lsum = 0.f;
  for (int i = threadIdx.x; i < CH / 4; i += 256) {
    float4 f = rp4[i];
    float vs[4] = {f.x, f.y, f.z, f.w};
    #pragma unroll
    for (int q = 0; q < 4; ++q) {
      float v = vs[q];
      lsum += v;
      bool nz = (v != 0.f);
      unsigned long long mask = __ballot(nz);
      if (mask) {
        int leader = (int)__ffsll(mask) - 1;
        int wbase = 0;
        if (lane == leader) wbase = atomicAdd(&ls_cnt, (int)__popcll(mask));
        wbase = __shfl(wbase, leader, 64);
        if (nz) {
          int pos = wbase + (int)__popcll(mask & ((1ULL << lane) - 1));
          if (pos < SCAP) {
            int e = c0 + 4 * i + q;
            ls_e[pos] = e;
            ls_v[pos] = v * be[e];
          }
        }
      }
    }
  }
  #pragma unroll
  for (int off = 32; off > 0; off >>= 1) lsum += __shfl_xor(lsum, off, 64);
  if (lane == 0 && lsum != 0.f) atomicAdd(&ls_sum, lsum);
  __syncthreads();

  int total = ls_cnt < SCAP ? ls_cnt : SCAP;
  if (threadIdx.x == 0) {
    ls_base = atomicAdd(&fill[slot], total);
    if (ls_sum != 0.f) atomicAdd(&rsum[slot], ls_sum);
  }
  __syncthreads();
  int gbase = ls_base;
  int*   li = lidx  + (size_t)slot * CAP;
  float* lv = lsval + (size_t)slot * CAP;
  for (int i = threadIdx.x; i < total; i += 256) {
    int pos = gbase + i;
    if (pos < CAP) { li[pos] = ls_e[i]; lv[pos] = ls_v[i]; }
  }
}

__global__ __launch_bounds__(256) void k_rmeta(
    const int* __restrict__ fill, const float* __restrict__ rsum,
    int* __restrict__ cnt, float* __restrict__ inv)
{
  int i = blockIdx.x * 256 + threadIdx.x;
  if (i < 2 * KG_R) {
    int c = fill[i];
    cnt[i] = c > CAP ? CAP : c;
    float s = rsum[i];
    inv[i] = (s == 0.f) ? 0.f : 1.f / s;
  }
}

// ---------------- r-layer: w[m][r][d] = relu(inv * sum sval*E[e,d]) * atten -
__global__ __launch_bounds__(320) void k_rlayer(
    const float* __restrict__ E, const int* __restrict__ lidx,
    const float* __restrict__ lsval, const int* __restrict__ cnt,
    const float* __restrict__ inv, const float* __restrict__ atten,
    float* __restrict__ w)
{
  int b = blockIdx.x;           // 0..2*KG_R-1
  int m = b / KG_R, r = b % KG_R;
  int d = threadIdx.x;
  if (d >= E_DIM) return;
  int n = cnt[m*KG_R + r];
  const int*   li = lidx  + (size_t)(m*KG_R + r) * CAP;
  const float* lv = lsval + (size_t)(m*KG_R + r) * CAP;
  float acc = 0.f;
  #pragma unroll 4
  for (int i = 0; i < n; ++i) {
    int e = li[i];
    float s = lv[i];
    acc += s * E[(size_t)e * E_DIM + d];
  }
  float v = acc * inv[m*KG_R + r];
  v = v > 0.f ? v : 0.f;
  w[(size_t)(m*KG_R + r) * E_DIM + d] = v * atten[m*E_DIM + d];
}

// ---------------- CSR build: histogram, scan, scatter ----------------------
__global__ __launch_bounds__(256) void k_hist(
    const int* __restrict__ rows, int* __restrict__ cnt, int n)
{
  int i = blockIdx.x * 256 + threadIdx.x;
  if (i < n) atomicAdd(&cnt[rows[i]], 1);
}

__global__ __launch_bounds__(1024) void k_scan(
    const int* __restrict__ cnt, int* __restrict__ start, int n)
{
  __shared__ int buf[1024];
  __shared__ int carry;
  if (threadIdx.x == 0) carry = 0;
  __syncthreads();
  for (int base = 0; base < n; base += 1024) {
    int i = base + threadIdx.x;
    int v = (i < n) ? cnt[i] : 0;
    buf[threadIdx.x] = v;
    __syncthreads();
    for (int ofs = 1; ofs < 1024; ofs <<= 1) {
      int t = (threadIdx.x >= ofs) ? buf[threadIdx.x - ofs] : 0;
      __syncthreads();
      buf[threadIdx.x] += t;
      __syncthreads();
    }
    if (i < n) start[i] = carry + buf[threadIdx.x] - v;
    __syncthreads();
    if (threadIdx.x == 1023) carry += buf[1023];
    __syncthreads();
  }
  if (threadIdx.x == 0) start[n] = carry;
}

__global__ __launch_bounds__(256) void k_scatter_eer(
    const int* __restrict__ eidx, const int* __restrict__ erel,
    const int* __restrict__ start, int* __restrict__ fill,
    int* __restrict__ scol, int* __restrict__ srel, int neer)
{
  int i = blockIdx.x * 256 + threadIdx.x;
  if (i >= neer) return;
  int row = eidx[i];
  int pos = start[row] + atomicAdd(&fill[row], 1);
  scol[pos] = eidx[neer + i];
  srel[pos] = erel[i];
}

__global__ __launch_bounds__(256) void k_scatter_adj(
    const int* __restrict__ aidx, const float* __restrict__ adata,
    const int* __restrict__ start, int* __restrict__ fill,
    int* __restrict__ scol, float* __restrict__ sval, int ne)
{
  int i = blockIdx.x * 256 + threadIdx.x;
  if (i >= ne) return;
  int row = aidx[i];
  int pos = start[row] + atomicAdd(&fill[row], 1);
  scol[pos] = aidx[ne + i];
  sval[pos] = adata[i];
}

// ---------------- attention, CSR row-parallel, fused finalize --------------
__global__ __launch_bounds__(256) void k_att_csr(
    const float* __restrict__ E, const float* __restrict__ w,
    const int* __restrict__ start, const int* __restrict__ scol,
    const int* __restrict__ srel, const float* __restrict__ base,
    float alpha, float* __restrict__ out, unsigned short* __restrict__ outb)
{
  int wave = threadIdx.x >> 6, lane = threadIdx.x & 63;
  int row = blockIdx.x * 4 + wave;
  if (row >= KG_E) return;
  int s = start[row], e = start[row + 1];
  float er[5], acc[5] = {0.f, 0.f, 0.f, 0.f, 0.f};
  #pragma unroll
  for (int c = 0; c < 5; ++c) {
    int d = lane + c * 64;
    er[c] = (d < E_DIM) ? E[(size_t)row * E_DIM + d] : 0.f;
  }
  float rs = 0.f;
  for (int j = s; j < e; ++j) {
    int col = scol[j], rel = srel[j];
    const float* ec = E + (size_t)col * E_DIM;
    const float* wh = w + (size_t)rel * E_DIM;
    const float* wt = w + (size_t)(KG_R + rel) * E_DIM;
    float ecv[5];
    float p = 0.f;
    #pragma unroll
    for (int c = 0; c < 5; ++c) {
      int d = lane + c * 64;
      if (d < E_DIM) {
        float b = ec[d];
        ecv[c] = b;
        p += er[c] * wh[d] + b * wt[d];
      } else ecv[c] = 0.f;
    }
    #pragma unroll
    for (int off = 32; off > 0; off >>= 1) p += __shfl_xor(p, off, 64);
    float la = p >= 0.f ? p : LRELU * p;
    float at = __expf(-la);
    rs += at;
    #pragma unroll
    for (int c = 0; c < 5; ++c) acc[c] += at * ecv[c];
  }
  float iv = (rs == 0.f) ? 0.f : 1.f / rs;
  #pragma unroll
  for (int c = 0; c < 5; ++c) {
    int d = lane + c * 64;
    if (d < E_DIM) {
      size_t i = (size_t)row * E_DIM + d;
      float v = acc[c] * iv;
      v = v > 0.f ? v : 0.f;
      float o = base[i] + alpha * v;
      out[i] = o;
      if (outb) outb[i] = f2bf(o);
    }
  }
}

// ---------------- spmm CSR row-parallel: Y[row] = sum val*X[col] -----------
__global__ __launch_bounds__(256) void k_spmm_csr(
    const float* __restrict__ X, const int* __restrict__ start,
    const int* __restrict__ scol, const float* __restrict__ sval,
    float* __restrict__ Y)
{
  int wave = threadIdx.x >> 6, lane = threadIdx.x & 63;
  int row = blockIdx.x * 4 + wave;
  if (row >= KG_E) return;
  int s = start[row], e = start[row + 1];
  float acc[5] = {0.f, 0.f, 0.f, 0.f, 0.f};
  for (int j = s; j < e; ++j) {
    int col = scol[j];
    float v = sval[j];
    const float* xp = X + (size_t)col * E_DIM;
    #pragma unroll
    for (int c = 0; c < 5; ++c) {
      int d = lane + c * 64;
      if (d < E_DIM) acc[c] += v * xp[d];
    }
  }
  #pragma unroll
  for (int c = 0; c < 5; ++c) {
    int d = lane + c * 64;
    if (d < E_DIM) Y[(size_t)row * E_DIM + d] = acc[c];
  }
}

// ---------------- pack W into MFMA B-fragment layout -----------------------
__global__ __launch_bounds__(64) void k_packW(
    const float* __restrict__ W1, const float* __restrict__ W2,
    unsigned short* __restrict__ Wp)
{
  int lane = threadIdx.x;
  int t = blockIdx.x, s = blockIdx.y;
  int c = t * 16 + (lane & 15);
  unsigned short v[8];
  #pragma unroll
  for (int j = 0; j < 8; ++j) {
    int k = s * 32 + (lane >> 4) * 8 + j;
    float x = 0.f;
    if (k < E_DIM && c < 2 * E_DIM)
      x = (c < E_DIM) ? W1[(size_t)k * E_DIM + c]
                      : W2[(size_t)k * E_DIM + (c - E_DIM)];
    v[j] = f2bf(x);
  }
  size_t base = ((size_t)(t * NK + s) * 64 + lane) * 8;
  #pragma unroll
  for (int j = 0; j < 8; ++j) Wp[base + j] = v[j];
}

// ---------------- fused dual-GEMM: {Y1,Y2} = Xb @ {gcnW1,hwWr} (bf16 MFMA) -
__global__ __launch_bounds__(256) void k_gemm2_mfma(
    const unsigned short* __restrict__ Xb, const unsigned short* __restrict__ Wp,
    float* __restrict__ Y1, float* __restrict__ Y2, int M)
{
  __shared__ unsigned short Xs[32][XS_LD];
  int tid = threadIdx.x;
  int r0 = blockIdx.x * 32;
  int nb = blockIdx.y;               // 0..4, 128 cols each

  for (int t = tid; t < 32 * (XS_LD / 2); t += 256) {
    int r = t / (XS_LD / 2), u = t % (XS_LD / 2);
    unsigned v = 0;
    int rg = r0 + r;
    if (rg < M && u < E_DIM / 2) v = ((const unsigned*)Xb)[(size_t)rg * (E_DIM / 2) + u];
    ((unsigned*)&Xs[0][0])[r * (XS_LD / 2) + u] = v;
  }
  __syncthreads();

  int wid = tid >> 6, lane = tid & 63;
  int wave_m = wid >> 1, wave_n = wid & 1;
  int rowA = wave_m * 16 + (lane & 15);
  int kgrp = (lane >> 4) * 8;
  int tb0 = nb * 8 + wave_n * 4;

  const bf16x8* wfrag = (const bf16x8*)Wp + (size_t)tb0 * (NK * 64) + lane;

  f32x4 acc[4] = {{0,0,0,0},{0,0,0,0},{0,0,0,0},{0,0,0,0}};
  #pragma unroll 2
  for (int ks = 0; ks < NK; ++ks) {
    bf16x8 a = *(const bf16x8*)&Xs[rowA][ks * 32 + kgrp];
    #pragma unroll
    for (int nt = 0; nt < 4; ++nt) {
      bf16x8 b = wfrag[(nt * NK + ks) * 64];
      acc[nt] = __builtin_amdgcn_mfma_f32_16x16x32_bf16(a, b, acc[nt], 0, 0, 0);
    }
  }

  int rbase = r0 + wave_m * 16 + ((lane >> 4) << 2);
  #pragma unroll
  for (int nt = 0; nt < 4; ++nt) {
    int c = (tb0 + nt) * 16 + (lane & 15);
    #pragma unroll
    for (int j = 0; j < 4; ++j) {
      int row = rbase + j;
      if (row < M) {
        float v = acc[nt][j];
        if (c < E_DIM)            Y1[(size_t)row * E_DIM + c] = v;
        else if (c < 2 * E_DIM)   Y2[(size_t)row * E_DIM + (c - E_DIM)] = v;
      }
    }
  }
}

// ---------------- highway: out = sig(gl+br)*relu(y) + (1-sig)*base ---------
__global__ __launch_bounds__(320) void k_highway(
    const float* __restrict__ base, const float* __restrict__ y,
    const float* __restrict__ gateLin, const float* __restrict__ br,
    float* __restrict__ out, unsigned short* __restrict__ outb)
{
  int r = blockIdx.x, d = threadIdx.x;
  if (d >= E_DIM) return;
  size_t i = (size_t)r * E_DIM + d;
  float g = 1.f / (1.f + __expf(-(gateLin[i] + br[d])));
  float yy = y[i]; yy = yy > 0.f ? yy : 0.f;
  float b = base[i];
  float o = g * yy + (1.f - g) * b;
  out[i] = o;
  if (outb) outb[i] = f2bf(o);
}

extern "C" void kernel_launch(void* const* d_in, const int* in_sizes, int n_in,
                              void* d_out, int out_size, void* d_ws, size_t ws_size,
                              hipStream_t stream)
{
  const float* primal      = (const float*)d_in[0];
  const float* r_head      = (const float*)d_in[1];
  const float* r_tail      = (const float*)d_in[2];
  const float* e_adj_data  = (const float*)d_in[3];
  const float* be_L        = (const float*)d_in[4];
  const float* be_R        = (const float*)d_in[5];
  const float* atten_r     = (const float*)d_in[6];
  const float* gcnW1       = (const float*)d_in[7];
  const float* hwWr        = (const float*)d_in[8];
  const float* hwbr        = (const float*)d_in[9];
  const int*   e_adj_index = (const int*)d_in[10];
  const int*   eer_idx     = (const int*)d_in[11];
  const int*   eer_rel     = (const int*)d_in[12];
  int ne   = in_sizes[10] / 2;
  int neer = in_sizes[11] / 2;

  char* ws = (char*)d_ws;
  size_t off = 0;
  auto take = [&](size_t bytes) {
    void* p = ws + off;
    off = (off + bytes + 255) & ~(size_t)255;
    return p;
  };
  int*   cnt      = (int*)  take((size_t)2 * KG_R * sizeof(int));
  float* inv      = (float*)take((size_t)2 * KG_R * sizeof(float));
  int*   rfill    = (int*)  take((size_t)2 * KG_R * sizeof(int));
  float* rsumb    = (float*)take((size_t)2 * KG_R * sizeof(float));
  int*   lidx     = (int*)  take((size_t)2 * KG_R * CAP * sizeof(int));
  float* lsv      = (float*)take((size_t)2 * KG_R * CAP * sizeof(float));
  float* wbuf     = (float*)take((size_t)2 * KG_R * E_DIM * sizeof(float));
  int*   hcnt     = (int*)  take((size_t)KG_E * sizeof(int));
  int*   hfill    = (int*)  take((size_t)KG_E * sizeof(int));
  int*   eer_start= (int*)  take((size_t)(KG_E + 1) * sizeof(int));
  int*   adj_start= (int*)  take((size_t)(KG_E + 1) * sizeof(int));
  int*   eer_scol = (int*)  take((size_t)neer * sizeof(int));
  int*   eer_srel = (int*)  take((size_t)neer * sizeof(int));
  int*   adj_scol = (int*)  take((size_t)ne * sizeof(int));
  float* adj_sval = (float*)take((size_t)ne * sizeof(float));
  unsigned short* Wp = (unsigned short*)take((size_t)NT * NK * 64 * 8 * sizeof(unsigned short));
  unsigned short* Xbf= (unsigned short*)take((size_t)KG_E * E_DIM * sizeof(unsigned short));
  float* D        = (float*)take((size_t)KG_E * E_DIM * sizeof(float));
  float* E        = (float*)take((size_t)KG_E * E_DIM * sizeof(float));
  float* F        = (float*)take((size_t)KG_E * E_DIM * sizeof(float));
  float* G        = (float*)take((size_t)KG_E * E_DIM * sizeof(float));
  float* out      = (float*)d_out;
  (void)ws_size; (void)n_in; (void)out_size;

  int eg = (neer + 255) / 256;
  int ag = (ne + 255) / 256;

  // ---- build CSR for eer edges ----
  hipMemsetAsync(hcnt, 0, (size_t)KG_E * sizeof(int), stream);
  k_hist<<<eg, 256, 0, stream>>>(eer_idx, hcnt, neer);
  k_scan<<<1, 1024, 0, stream>>>(hcnt, eer_start, KG_E);
  hipMemsetAsync(hfill, 0, (size_t)KG_E * sizeof(int), stream);
  k_scatter_eer<<<eg, 256, 0, stream>>>(eer_idx, eer_rel, eer_start, hfill,
                                        eer_scol, eer_srel, neer);
  // ---- build CSR for e_adj edges ----
  hipMemsetAsync(hcnt, 0, (size_t)KG_E * sizeof(int), stream);
  k_hist<<<ag, 256, 0, stream>>>(e_adj_index, hcnt, ne);
  k_scan<<<1, 1024, 0, stream>>>(hcnt, adj_start, KG_E);
  hipMemsetAsync(hfill, 0, (size_t)KG_E * sizeof(int), stream);
  k_scatter_adj<<<ag, 256, 0, stream>>>(e_adj_index, e_adj_data, adj_start, hfill,
                                        adj_scol, adj_sval, ne);

  // ---- compact r_head/r_tail (LDS-staged) + pack weights ----
  hipMemsetAsync(rfill, 0, (size_t)2 * KG_R * sizeof(int), stream);
  hipMemsetAsync(rsumb, 0, (size_t)2 * KG_R * sizeof(float), stream);
  k_compact2<<<dim3(NCH, KG_R, 2), 256, 0, stream>>>(r_head, r_tail, be_L, be_R,
                                                     lidx, lsv, rfill, rsumb);
  k_rmeta<<<(2 * KG_R + 255) / 256, 256, 0, stream>>>(rfill, rsumb, cnt, inv);
  k_packW<<<dim3(NT, NK), 64, 0, stream>>>(gcnW1, hwWr, Wp);

  int rg = (KG_E + 3) / 4;

  // ---- attention layer 1: e1 = primal + 0.1*att(primal) -> E ----
  k_rlayer<<<2 * KG_R, 320, 0, stream>>>(primal, lidx, lsv, cnt, inv, atten_r, wbuf);
  k_att_csr<<<rg, 256, 0, stream>>>(primal, wbuf, eer_start, eer_scol, eer_srel,
                                    primal, 0.1f, E, (unsigned short*)nullptr);
  // ---- attention layer 2: e2 = primal + 0.3*att(e1) -> D (+ bf16 Xbf) ----
  k_rlayer<<<2 * KG_R, 320, 0, stream>>>(E, lidx, lsv, cnt, inv, atten_r, wbuf);
  k_att_csr<<<rg, 256, 0, stream>>>(E, wbuf, eer_start, eer_scol, eer_srel,
                                    primal, 0.3f, D, Xbf);

  // ---- GCN + highway 1: F = e2@gcnW1, G = e2@hwWr; g2 -> E (+ bf16 Xbf) ----
  dim3 gg((KG_E + 31) / 32, 5);
  k_gemm2_mfma<<<gg, 256, 0, stream>>>(Xbf, Wp, F, G, KG_E);
  k_spmm_csr<<<rg, 256, 0, stream>>>(F, adj_start, adj_scol, adj_sval, out);
  k_highway<<<KG_E, 320, 0, stream>>>(D, out, G, hwbr, E, Xbf);

  // ---- GCN + highway 2: F = g2@gcnW1, G = g2@hwWr; out = highway ----
  k_gemm2_mfma<<<gg, 256, 0, stream>>>(Xbf, Wp, F, G, KG_E);
  k_spmm_csr<<<rg, 256, 0, stream>>>(F, adj_start, adj_scol, adj_sval, out);
  k_highway<<<KG_E, 320, 0, stream>>>(E, out, G, hwbr, out, (unsigned short*)nullptr);
}

// Round 6
// 1143.380 us; speedup vs baseline: 1.2493x; 1.0849x over previous
//
#include <hip/hip_runtime.h>
#include <math.h>

#define KG_E  50000
#define KG_R  500
#define E_DIM 300
#define CAP   1024
#define LRELU 0.2f

// MFMA GEMM geometry: Y[M,600(pad 640)] = X[M,300(pad 320)] @ Wcat
#define NK    10          // K-steps of 32 (K padded 300->320)
#define NT    40          // 16-col n-tiles (600 -> 640)
#define XS_LD 328         // LDS row stride in bf16 (+8 pad)

typedef __attribute__((ext_vector_type(8))) short bf16x8;
typedef __attribute__((ext_vector_type(4))) float f32x4;

__device__ __forceinline__ unsigned short f2bf(float x) {
  union { float f; unsigned u; } v; v.f = x;
  unsigned r = v.u + 0x7FFFu + ((v.u >> 16) & 1u);
  return (unsigned short)(r >> 16);
}
__device__ __forceinline__ float bf2f(unsigned short x) {
  union { unsigned u; float f; } v; v.u = ((unsigned)x) << 16; return v.f;
}

// ---------------- f32 -> bf16 table conversion -----------------------------
__global__ __launch_bounds__(256) void k_tobf(
    const float* __restrict__ src, unsigned short* __restrict__ dst, int n4)
{
  int i = blockIdx.x * 256 + threadIdx.x;
  if (i >= n4) return;
  float4 f = ((const float4*)src)[i];
  ushort4 o;
  o.x = f2bf(f.x); o.y = f2bf(f.y); o.z = f2bf(f.z); o.w = f2bf(f.w);
  ((ushort4*)dst)[i] = o;
}

// ---------------- compaction: LDS-staged, one global atomic per block ------
#define NCH 5                      // chunks per row (KG_E/NCH = 10000)
#define SCAP 1024
__global__ __launch_bounds__(256) void k_compact2(
    const float* __restrict__ r_head, const float* __restrict__ r_tail,
    const float* __restrict__ be_L, const float* __restrict__ be_R,
    int* __restrict__ lidx, float* __restrict__ lsval,
    int* __restrict__ fill, float* __restrict__ rsum)
{
  __shared__ int   ls_e[SCAP];
  __shared__ float ls_v[SCAP];
  __shared__ int   ls_cnt;
  __shared__ float ls_sum;
  __shared__ int   ls_base;
  int m = blockIdx.z;
  int r = blockIdx.y;
  const float* rowp = (m ? r_tail : r_head) + (size_t)r * KG_E;
  const float* be   = m ? be_R : be_L;
  int slot = m * KG_R + r;
  int lane = threadIdx.x & 63;
  if (threadIdx.x == 0) { ls_cnt = 0; ls_sum = 0.f; }
  __syncthreads();

  const int CH = KG_E / NCH;
  int c0 = blockIdx.x * CH;
  const float4* rp4 = (const float4*)(rowp + c0);
  float lsum = 0.f;
  for (int i = threadIdx.x; i < CH / 4; i += 256) {
    float4 f = rp4[i];
    float vs[4] = {f.x, f.y, f.z, f.w};
    #pragma unroll
    for (int q = 0; q < 4; ++q) {
      float v = vs[q];
      lsum += v;
      bool nz = (v != 0.f);
      unsigned long long mask = __ballot(nz);
      if (mask) {
        int leader = (int)__ffsll(mask) - 1;
        int wbase = 0;
        if (lane == leader) wbase = atomicAdd(&ls_cnt, (int)__popcll(mask));
        wbase = __shfl(wbase, leader, 64);
        if (nz) {
          int pos = wbase + (int)__popcll(mask & ((1ULL << lane) - 1));
          if (pos < SCAP) {
            int e = c0 + 4 * i + q;
            ls_e[pos] = e;
            ls_v[pos] = v * be[e];
          }
        }
      }
    }
  }
  #pragma unroll
  for (int off = 32; off > 0; off >>= 1) lsum += __shfl_xor(lsum, off, 64);
  if (lane == 0 && lsum != 0.f) atomicAdd(&ls_sum, lsum);
  __syncthreads();

  int total = ls_cnt < SCAP ? ls_cnt : SCAP;
  if (threadIdx.x == 0) {
    ls_base = atomicAdd(&fill[slot], total);
    if (ls_sum != 0.f) atomicAdd(&rsum[slot], ls_sum);
  }
  __syncthreads();
  int gbase = ls_base;
  int*   li = lidx  + (size_t)slot * CAP;
  float* lv = lsval + (size_t)slot * CAP;
  for (int i = threadIdx.x; i < total; i += 256) {
    int pos = gbase + i;
    if (pos < CAP) { li[pos] = ls_e[i]; lv[pos] = ls_v[i]; }
  }
}

__global__ __launch_bounds__(256) void k_rmeta(
    const int* __restrict__ fill, const float* __restrict__ rsum,
    int* __restrict__ cnt, float* __restrict__ inv)
{
  int i = blockIdx.x * 256 + threadIdx.x;
  if (i < 2 * KG_R) {
    int c = fill[i];
    cnt[i] = c > CAP ? CAP : c;
    float s = rsum[i];
    inv[i] = (s == 0.f) ? 0.f : 1.f / s;
  }
}

// ---------------- r-layer: bf16 gathers --------------------------------------
__global__ __launch_bounds__(320) void k_rlayer(
    const unsigned short* __restrict__ Eb, const int* __restrict__ lidx,
    const float* __restrict__ lsval, const int* __restrict__ cnt,
    const float* __restrict__ inv, const float* __restrict__ atten,
    float* __restrict__ w)
{
  int b = blockIdx.x;           // 0..2*KG_R-1
  int m = b / KG_R, r = b % KG_R;
  int d = threadIdx.x;
  if (d >= E_DIM) return;
  int n = cnt[m*KG_R + r];
  const int*   li = lidx  + (size_t)(m*KG_R + r) * CAP;
  const float* lv = lsval + (size_t)(m*KG_R + r) * CAP;
  float acc = 0.f;
  #pragma unroll 4
  for (int i = 0; i < n; ++i) {
    int e = li[i];
    float s = lv[i];
    acc += s * bf2f(Eb[(size_t)e * E_DIM + d]);
  }
  float v = acc * inv[m*KG_R + r];
  v = v > 0.f ? v : 0.f;
  w[(size_t)(m*KG_R + r) * E_DIM + d] = v * atten[m*E_DIM + d];
}

// ---------------- CSR build: histogram, scan, scatter ----------------------
__global__ __launch_bounds__(256) void k_hist(
    const int* __restrict__ rows, int* __restrict__ cnt, int n)
{
  int i = blockIdx.x * 256 + threadIdx.x;
  if (i < n) atomicAdd(&cnt[rows[i]], 1);
}

__global__ __launch_bounds__(1024) void k_scan(
    const int* __restrict__ cnt, int* __restrict__ start, int n)
{
  __shared__ int buf[1024];
  __shared__ int carry;
  if (threadIdx.x == 0) carry = 0;
  __syncthreads();
  for (int base = 0; base < n; base += 1024) {
    int i = base + threadIdx.x;
    int v = (i < n) ? cnt[i] : 0;
    buf[threadIdx.x] = v;
    __syncthreads();
    for (int ofs = 1; ofs < 1024; ofs <<= 1) {
      int t = (threadIdx.x >= ofs) ? buf[threadIdx.x - ofs] : 0;
      __syncthreads();
      buf[threadIdx.x] += t;
      __syncthreads();
    }
    if (i < n) start[i] = carry + buf[threadIdx.x] - v;
    __syncthreads();
    if (threadIdx.x == 1023) carry += buf[1023];
    __syncthreads();
  }
  if (threadIdx.x == 0) start[n] = carry;
}

__global__ __launch_bounds__(256) void k_scatter_eer(
    const int* __restrict__ eidx, const int* __restrict__ erel,
    const int* __restrict__ start, int* __restrict__ fill,
    int* __restrict__ scol, int* __restrict__ srel, int neer)
{
  int i = blockIdx.x * 256 + threadIdx.x;
  if (i >= neer) return;
  int row = eidx[i];
  int pos = start[row] + atomicAdd(&fill[row], 1);
  scol[pos] = eidx[neer + i];
  srel[pos] = erel[i];
}

__global__ __launch_bounds__(256) void k_scatter_adj(
    const int* __restrict__ aidx, const float* __restrict__ adata,
    const int* __restrict__ start, int* __restrict__ fill,
    int* __restrict__ scol, float* __restrict__ sval, int ne)
{
  int i = blockIdx.x * 256 + threadIdx.x;
  if (i >= ne) return;
  int row = aidx[i];
  int pos = start[row] + atomicAdd(&fill[row], 1);
  scol[pos] = aidx[ne + i];
  sval[pos] = adata[i];
}

// ---------------- attention, CSR row-parallel, bf16 gathers ----------------
__global__ __launch_bounds__(256) void k_att_csr(
    const float* __restrict__ E, const unsigned short* __restrict__ Eb,
    const float* __restrict__ w,
    const int* __restrict__ start, const int* __restrict__ scol,
    const int* __restrict__ srel, const float* __restrict__ base,
    float alpha, float* __restrict__ out, unsigned short* __restrict__ outb)
{
  int wave = threadIdx.x >> 6, lane = threadIdx.x & 63;
  int row = blockIdx.x * 4 + wave;
  if (row >= KG_E) return;
  int s = start[row], e = start[row + 1];
  float er[5], acc[5] = {0.f, 0.f, 0.f, 0.f, 0.f};
  #pragma unroll
  for (int c = 0; c < 5; ++c) {
    int d = lane + c * 64;
    er[c] = (d < E_DIM) ? E[(size_t)row * E_DIM + d] : 0.f;
  }
  float rs = 0.f;
  for (int j = s; j < e; ++j) {
    int col = scol[j], rel = srel[j];
    const unsigned short* ec = Eb + (size_t)col * E_DIM;
    const float* wh = w + (size_t)rel * E_DIM;
    const float* wt = w + (size_t)(KG_R + rel) * E_DIM;
    float ecv[5];
    float p = 0.f;
    #pragma unroll
    for (int c = 0; c < 5; ++c) {
      int d = lane + c * 64;
      if (d < E_DIM) {
        float b = bf2f(ec[d]);
        ecv[c] = b;
        p += er[c] * wh[d] + b * wt[d];
      } else ecv[c] = 0.f;
    }
    #pragma unroll
    for (int off = 32; off > 0; off >>= 1) p += __shfl_xor(p, off, 64);
    float la = p >= 0.f ? p : LRELU * p;
    float at = __expf(-la);
    rs += at;
    #pragma unroll
    for (int c = 0; c < 5; ++c) acc[c] += at * ecv[c];
  }
  float iv = (rs == 0.f) ? 0.f : 1.f / rs;
  #pragma unroll
  for (int c = 0; c < 5; ++c) {
    int d = lane + c * 64;
    if (d < E_DIM) {
      size_t i = (size_t)row * E_DIM + d;
      float v = acc[c] * iv;
      v = v > 0.f ? v : 0.f;
      float o = base[i] + alpha * v;
      out[i] = o;
      if (outb) outb[i] = f2bf(o);
    }
  }
}

// ---------------- spmm CSR row-parallel, bf16 gather table -----------------
__global__ __launch_bounds__(256) void k_spmm_csr(
    const unsigned short* __restrict__ Xb, const int* __restrict__ start,
    const int* __restrict__ scol, const float* __restrict__ sval,
    float* __restrict__ Y)
{
  int wave = threadIdx.x >> 6, lane = threadIdx.x & 63;
  int row = blockIdx.x * 4 + wave;
  if (row >= KG_E) return;
  int s = start[row], e = start[row + 1];
  float acc[5] = {0.f, 0.f, 0.f, 0.f, 0.f};
  for (int j = s; j < e; ++j) {
    int col = scol[j];
    float v = sval[j];
    const unsigned short* xp = Xb + (size_t)col * E_DIM;
    #pragma unroll
    for (int c = 0; c < 5; ++c) {
      int d = lane + c * 64;
      if (d < E_DIM) acc[c] += v * bf2f(xp[d]);
    }
  }
  #pragma unroll
  for (int c = 0; c < 5; ++c) {
    int d = lane + c * 64;
    if (d < E_DIM) Y[(size_t)row * E_DIM + d] = acc[c];
  }
}

// ---------------- pack W into MFMA B-fragment layout -----------------------
__global__ __launch_bounds__(64) void k_packW(
    const float* __restrict__ W1, const float* __restrict__ W2,
    unsigned short* __restrict__ Wp)
{
  int lane = threadIdx.x;
  int t = blockIdx.x, s = blockIdx.y;
  int c = t * 16 + (lane & 15);
  unsigned short v[8];
  #pragma unroll
  for (int j = 0; j < 8; ++j) {
    int k = s * 32 + (lane >> 4) * 8 + j;
    float x = 0.f;
    if (k < E_DIM && c < 2 * E_DIM)
      x = (c < E_DIM) ? W1[(size_t)k * E_DIM + c]
                      : W2[(size_t)k * E_DIM + (c - E_DIM)];
    v[j] = f2bf(x);
  }
  size_t base = ((size_t)(t * NK + s) * 64 + lane) * 8;
  #pragma unroll
  for (int j = 0; j < 8; ++j) Wp[base + j] = v[j];
}

// ---------------- fused dual-GEMM: Y1(bf16) = X@gcnW1, Y2(f32) = X@hwWr ----
__global__ __launch_bounds__(256) void k_gemm2_mfma(
    const unsigned short* __restrict__ Xb, const unsigned short* __restrict__ Wp,
    unsigned short* __restrict__ Y1, float* __restrict__ Y2, int M)
{
  __shared__ unsigned short Xs[32][XS_LD];
  int tid = threadIdx.x;
  int r0 = blockIdx.x * 32;
  int nb = blockIdx.y;               // 0..4, 128 cols each

  for (int t = tid; t < 32 * (XS_LD / 2); t += 256) {
    int r = t / (XS_LD / 2), u = t % (XS_LD / 2);
    unsigned v = 0;
    int rg = r0 + r;
    if (rg < M && u < E_DIM / 2) v = ((const unsigned*)Xb)[(size_t)rg * (E_DIM / 2) + u];
    ((unsigned*)&Xs[0][0])[r * (XS_LD / 2) + u] = v;
  }
  __syncthreads();

  int wid = tid >> 6, lane = tid & 63;
  int wave_m = wid >> 1, wave_n = wid & 1;
  int rowA = wave_m * 16 + (lane & 15);
  int kgrp = (lane >> 4) * 8;
  int tb0 = nb * 8 + wave_n * 4;

  const bf16x8* wfrag = (const bf16x8*)Wp + (size_t)tb0 * (NK * 64) + lane;

  f32x4 acc[4] = {{0,0,0,0},{0,0,0,0},{0,0,0,0},{0,0,0,0}};
  #pragma unroll 2
  for (int ks = 0; ks < NK; ++ks) {
    bf16x8 a = *(const bf16x8*)&Xs[rowA][ks * 32 + kgrp];
    #pragma unroll
    for (int nt = 0; nt < 4; ++nt) {
      bf16x8 b = wfrag[(nt * NK + ks) * 64];
      acc[nt] = __builtin_amdgcn_mfma_f32_16x16x32_bf16(a, b, acc[nt], 0, 0, 0);
    }
  }

  int rbase = r0 + wave_m * 16 + ((lane >> 4) << 2);
  #pragma unroll
  for (int nt = 0; nt < 4; ++nt) {
    int c = (tb0 + nt) * 16 + (lane & 15);
    #pragma unroll
    for (int j = 0; j < 4; ++j) {
      int row = rbase + j;
      if (row < M) {
        float v = acc[nt][j];
        if (c < E_DIM)            Y1[(size_t)row * E_DIM + c] = f2bf(v);
        else if (c < 2 * E_DIM)   Y2[(size_t)row * E_DIM + (c - E_DIM)] = v;
      }
    }
  }
}

// ---------------- highway: out = sig(gl+br)*relu(y) + (1-sig)*base ---------
__global__ __launch_bounds__(320) void k_highway(
    const float* __restrict__ base, const float* __restrict__ y,
    const float* __restrict__ gateLin, const float* __restrict__ br,
    float* __restrict__ out, unsigned short* __restrict__ outb)
{
  int r = blockIdx.x, d = threadIdx.x;
  if (d >= E_DIM) return;
  size_t i = (size_t)r * E_DIM + d;
  float g = 1.f / (1.f + __expf(-(gateLin[i] + br[d])));
  float yy = y[i]; yy = yy > 0.f ? yy : 0.f;
  float b = base[i];
  float o = g * yy + (1.f - g) * b;
  out[i] = o;
  if (outb) outb[i] = f2bf(o);
}

extern "C" void kernel_launch(void* const* d_in, const int* in_sizes, int n_in,
                              void* d_out, int out_size, void* d_ws, size_t ws_size,
                              hipStream_t stream)
{
  const float* primal      = (const float*)d_in[0];
  const float* r_head      = (const float*)d_in[1];
  const float* r_tail      = (const float*)d_in[2];
  const float* e_adj_data  = (const float*)d_in[3];
  const float* be_L        = (const float*)d_in[4];
  const float* be_R        = (const float*)d_in[5];
  const float* atten_r     = (const float*)d_in[6];
  const float* gcnW1       = (const float*)d_in[7];
  const float* hwWr        = (const float*)d_in[8];
  const float* hwbr        = (const float*)d_in[9];
  const int*   e_adj_index = (const int*)d_in[10];
  const int*   eer_idx     = (const int*)d_in[11];
  const int*   eer_rel     = (const int*)d_in[12];
  int ne   = in_sizes[10] / 2;
  int neer = in_sizes[11] / 2;

  char* ws = (char*)d_ws;
  size_t off = 0;
  auto take = [&](size_t bytes) {
    void* p = ws + off;
    off = (off + bytes + 255) & ~(size_t)255;
    return p;
  };
  int*   cnt      = (int*)  take((size_t)2 * KG_R * sizeof(int));
  float* inv      = (float*)take((size_t)2 * KG_R * sizeof(float));
  int*   rfill    = (int*)  take((size_t)2 * KG_R * sizeof(int));
  float* rsumb    = (float*)take((size_t)2 * KG_R * sizeof(float));
  int*   lidx     = (int*)  take((size_t)2 * KG_R * CAP * sizeof(int));
  float* lsv      = (float*)take((size_t)2 * KG_R * CAP * sizeof(float));
  float* wbuf     = (float*)take((size_t)2 * KG_R * E_DIM * sizeof(float));
  int*   hcnt     = (int*)  take((size_t)KG_E * sizeof(int));
  int*   hfill    = (int*)  take((size_t)KG_E * sizeof(int));
  int*   eer_start= (int*)  take((size_t)(KG_E + 1) * sizeof(int));
  int*   adj_start= (int*)  take((size_t)(KG_E + 1) * sizeof(int));
  int*   eer_scol = (int*)  take((size_t)neer * sizeof(int));
  int*   eer_srel = (int*)  take((size_t)neer * sizeof(int));
  int*   adj_scol = (int*)  take((size_t)ne * sizeof(int));
  float* adj_sval = (float*)take((size_t)ne * sizeof(float));
  unsigned short* Wp  = (unsigned short*)take((size_t)NT * NK * 64 * 8 * sizeof(unsigned short));
  unsigned short* Xbf = (unsigned short*)take((size_t)KG_E * E_DIM * sizeof(unsigned short));
  unsigned short* B0  = (unsigned short*)take((size_t)KG_E * E_DIM * sizeof(unsigned short)); // primal bf16, later Fb
  unsigned short* B1  = (unsigned short*)take((size_t)KG_E * E_DIM * sizeof(unsigned short)); // e1 bf16
  float* D        = (float*)take((size_t)KG_E * E_DIM * sizeof(float));
  float* E        = (float*)take((size_t)KG_E * E_DIM * sizeof(float));
  float* G        = (float*)take((size_t)KG_E * E_DIM * sizeof(float));
  float* out      = (float*)d_out;
  unsigned short* Fb = B0;   // reuse: primal-bf16 dead after att layer 1
  (void)ws_size; (void)n_in; (void)out_size;

  int eg = (neer + 255) / 256;
  int ag = (ne + 255) / 256;

  // ---- build CSR for eer edges ----
  hipMemsetAsync(hcnt, 0, (size_t)KG_E * sizeof(int), stream);
  k_hist<<<eg, 256, 0, stream>>>(eer_idx, hcnt, neer);
  k_scan<<<1, 1024, 0, stream>>>(hcnt, eer_start, KG_E);
  hipMemsetAsync(hfill, 0, (size_t)KG_E * sizeof(int), stream);
  k_scatter_eer<<<eg, 256, 0, stream>>>(eer_idx, eer_rel, eer_start, hfill,
                                        eer_scol, eer_srel, neer);
  // ---- build CSR for e_adj edges ----
  hipMemsetAsync(hcnt, 0, (size_t)KG_E * sizeof(int), stream);
  k_hist<<<ag, 256, 0, stream>>>(e_adj_index, hcnt, ne);
  k_scan<<<1, 1024, 0, stream>>>(hcnt, adj_start, KG_E);
  hipMemsetAsync(hfill, 0, (size_t)KG_E * sizeof(int), stream);
  k_scatter_adj<<<ag, 256, 0, stream>>>(e_adj_index, e_adj_data, adj_start, hfill,
                                        adj_scol, adj_sval, ne);

  // ---- compact r_head/r_tail + pack weights + primal bf16 ----
  hipMemsetAsync(rfill, 0, (size_t)2 * KG_R * sizeof(int), stream);
  hipMemsetAsync(rsumb, 0, (size_t)2 * KG_R * sizeof(float), stream);
  k_compact2<<<dim3(NCH, KG_R, 2), 256, 0, stream>>>(r_head, r_tail, be_L, be_R,
                                                     lidx, lsv, rfill, rsumb);
  k_rmeta<<<(2 * KG_R + 255) / 256, 256, 0, stream>>>(rfill, rsumb, cnt, inv);
  k_packW<<<dim3(NT, NK), 64, 0, stream>>>(gcnW1, hwWr, Wp);
  int n4 = KG_E * E_DIM / 4;
  k_tobf<<<(n4 + 255) / 256, 256, 0, stream>>>(primal, B0, n4);

  int rg = (KG_E + 3) / 4;

  // ---- attention layer 1: e1 = primal + 0.1*att(primal) -> E (+bf16 B1) ----
  k_rlayer<<<2 * KG_R, 320, 0, stream>>>(B0, lidx, lsv, cnt, inv, atten_r, wbuf);
  k_att_csr<<<rg, 256, 0, stream>>>(primal, B0, wbuf, eer_start, eer_scol, eer_srel,
                                    primal, 0.1f, E, B1);
  // ---- attention layer 2: e2 = primal + 0.3*att(e1) -> D (+bf16 Xbf) ----
  k_rlayer<<<2 * KG_R, 320, 0, stream>>>(B1, lidx, lsv, cnt, inv, atten_r, wbuf);
  k_att_csr<<<rg, 256, 0, stream>>>(E, B1, wbuf, eer_start, eer_scol, eer_srel,
                                    primal, 0.3f, D, Xbf);

  // ---- GCN + highway 1: Fb = e2@gcnW1 (bf16), G = e2@hwWr; g2 -> E (+Xbf) ----
  dim3 gg((KG_E + 31) / 32, 5);
  k_gemm2_mfma<<<gg, 256, 0, stream>>>(Xbf, Wp, Fb, G, KG_E);
  k_spmm_csr<<<rg, 256, 0, stream>>>(Fb, adj_start, adj_scol, adj_sval, out);
  k_highway<<<KG_E, 320, 0, stream>>>(D, out, G, hwbr, E, Xbf);

  // ---- GCN + highway 2: Fb = g2@gcnW1, G = g2@hwWr; out = highway ----
  k_gemm2_mfma<<<gg, 256, 0, stream>>>(Xbf, Wp, Fb, G, KG_E);
  k_spmm_csr<<<rg, 256, 0, stream>>>(Fb, adj_start, adj_scol, adj_sval, out);
  k_highway<<<KG_E, 320, 0, stream>>>(E, out, G, hwbr, out, (unsigned short*)nullptr);
}

// Round 7
// 886.687 us; speedup vs baseline: 1.6109x; 1.2895x over previous
//
#include <hip/hip_runtime.h>
#include <math.h>

#define KG_E  50000
#define KG_R  500
#define E_DIM 300
#define CAP   1024
#define LRELU 0.2f

// MFMA GEMM geometry: Y[M,600(pad 640)] = X[M,300(pad 320)] @ Wcat
#define NK    10          // K-steps of 32 (K padded 300->320)
#define NT    40          // 16-col n-tiles (600 -> 640)
#define XS_LD 328         // LDS row stride in bf16 (+8 pad)

#define NB_SCAN 49        // ceil(KG_E/1024)

typedef __attribute__((ext_vector_type(8))) short bf16x8;
typedef __attribute__((ext_vector_type(4))) float f32x4;

__device__ __forceinline__ unsigned short f2bf(float x) {
  union { float f; unsigned u; } v; v.f = x;
  unsigned r = v.u + 0x7FFFu + ((v.u >> 16) & 1u);
  return (unsigned short)(r >> 16);
}
__device__ __forceinline__ float bf2f(unsigned short x) {
  union { unsigned u; float f; } v; v.u = ((unsigned)x) << 16; return v.f;
}

// ---------------- f32 -> bf16 table conversion -----------------------------
__global__ __launch_bounds__(256) void k_tobf(
    const float* __restrict__ src, unsigned short* __restrict__ dst, int n4)
{
  int i = blockIdx.x * 256 + threadIdx.x;
  if (i >= n4) return;
  float4 f = ((const float4*)src)[i];
  ushort4 o;
  o.x = f2bf(f.x); o.y = f2bf(f.y); o.z = f2bf(f.z); o.w = f2bf(f.w);
  ((ushort4*)dst)[i] = o;
}

// ---------------- compaction: LDS-staged, one global atomic per block ------
#define NCH 5
#define SCAP 1024
__global__ __launch_bounds__(256) void k_compact2(
    const float* __restrict__ r_head, const float* __restrict__ r_tail,
    const float* __restrict__ be_L, const float* __restrict__ be_R,
    int* __restrict__ lidx, float* __restrict__ lsval,
    int* __restrict__ fill, float* __restrict__ rsum)
{
  __shared__ int   ls_e[SCAP];
  __shared__ float ls_v[SCAP];
  __shared__ int   ls_cnt;
  __shared__ float ls_sum;
  __shared__ int   ls_base;
  int m = blockIdx.z;
  int r = blockIdx.y;
  const float* rowp = (m ? r_tail : r_head) + (size_t)r * KG_E;
  const float* be   = m ? be_R : be_L;
  int slot = m * KG_R + r;
  int lane = threadIdx.x & 63;
  if (threadIdx.x == 0) { ls_cnt = 0; ls_sum = 0.f; }
  __syncthreads();

  const int CH = KG_E / NCH;
  int c0 = blockIdx.x * CH;
  const float4* rp4 = (const float4*)(rowp + c0);
  float lsum = 0.f;
  for (int i = threadIdx.x; i < CH / 4; i += 256) {
    float4 f = rp4[i];
    float vs[4] = {f.x, f.y, f.z, f.w};
    #pragma unroll
    for (int q = 0; q < 4; ++q) {
      float v = vs[q];
      lsum += v;
      bool nz = (v != 0.f);
      unsigned long long mask = __ballot(nz);
      if (mask) {
        int leader = (int)__ffsll(mask) - 1;
        int wbase = 0;
        if (lane == leader) wbase = atomicAdd(&ls_cnt, (int)__popcll(mask));
        wbase = __shfl(wbase, leader, 64);
        if (nz) {
          int pos = wbase + (int)__popcll(mask & ((1ULL << lane) - 1));
          if (pos < SCAP) {
            int e = c0 + 4 * i + q;
            ls_e[pos] = e;
            ls_v[pos] = v * be[e];
          }
        }
      }
    }
  }
  #pragma unroll
  for (int off = 32; off > 0; off >>= 1) lsum += __shfl_xor(lsum, off, 64);
  if (lane == 0 && lsum != 0.f) atomicAdd(&ls_sum, lsum);
  __syncthreads();

  int total = ls_cnt < SCAP ? ls_cnt : SCAP;
  if (threadIdx.x == 0) {
    ls_base = atomicAdd(&fill[slot], total);
    if (ls_sum != 0.f) atomicAdd(&rsum[slot], ls_sum);
  }
  __syncthreads();
  int gbase = ls_base;
  int*   li = lidx  + (size_t)slot * CAP;
  float* lv = lsval + (size_t)slot * CAP;
  for (int i = threadIdx.x; i < total; i += 256) {
    int pos = gbase + i;
    if (pos < CAP) { li[pos] = ls_e[i]; lv[pos] = ls_v[i]; }
  }
}

__global__ __launch_bounds__(256) void k_rmeta(
    const int* __restrict__ fill, const float* __restrict__ rsum,
    int* __restrict__ cnt, float* __restrict__ inv)
{
  int i = blockIdx.x * 256 + threadIdx.x;
  if (i < 2 * KG_R) {
    int c = fill[i];
    cnt[i] = c > CAP ? CAP : c;
    float s = rsum[i];
    inv[i] = (s == 0.f) ? 0.f : 1.f / s;
  }
}

// ---------------- r-layer: bf16 gathers ------------------------------------
__global__ __launch_bounds__(320) void k_rlayer(
    const unsigned short* __restrict__ Eb, const int* __restrict__ lidx,
    const float* __restrict__ lsval, const int* __restrict__ cnt,
    const float* __restrict__ inv, const float* __restrict__ atten,
    float* __restrict__ w)
{
  int b = blockIdx.x;
  int m = b / KG_R, r = b % KG_R;
  int d = threadIdx.x;
  if (d >= E_DIM) return;
  int n = cnt[m*KG_R + r];
  const int*   li = lidx  + (size_t)(m*KG_R + r) * CAP;
  const float* lv = lsval + (size_t)(m*KG_R + r) * CAP;
  float acc = 0.f;
  #pragma unroll 4
  for (int i = 0; i < n; ++i) {
    int e = li[i];
    float s = lv[i];
    acc += s * bf2f(Eb[(size_t)e * E_DIM + d]);
  }
  float v = acc * inv[m*KG_R + r];
  v = v > 0.f ? v : 0.f;
  w[(size_t)(m*KG_R + r) * E_DIM + d] = v * atten[m*E_DIM + d];
}

// ---------------- CSR build: histogram, 3-phase scan, scatter --------------
__global__ __launch_bounds__(256) void k_hist(
    const int* __restrict__ rows, int* __restrict__ cnt, int n)
{
  int i = blockIdx.x * 256 + threadIdx.x;
  if (i < n) atomicAdd(&cnt[rows[i]], 1);
}

// phase A: per-block sums of 1024 elements; grid (NB_SCAN, 2)
__global__ __launch_bounds__(256) void k_scan_a(
    const int* __restrict__ c0, const int* __restrict__ c1,
    int* __restrict__ bsum, int n)
{
  const int* c = blockIdx.y ? c1 : c0;
  int base = blockIdx.x * 1024;
  int s = 0;
  #pragma unroll
  for (int k = 0; k < 4; ++k) {
    int i = base + k * 256 + threadIdx.x;
    if (i < n) s += c[i];
  }
  #pragma unroll
  for (int off = 32; off > 0; off >>= 1) s += __shfl_xor(s, off, 64);
  __shared__ int ws[4];
  if ((threadIdx.x & 63) == 0) ws[threadIdx.x >> 6] = s;
  __syncthreads();
  if (threadIdx.x == 0)
    bsum[blockIdx.y * (NB_SCAN + 1) + blockIdx.x] = ws[0] + ws[1] + ws[2] + ws[3];
}

// phase B: exclusive-scan the 49 block sums (both arrays)
__global__ __launch_bounds__(64) void k_scan_b(int* __restrict__ bsum)
{
  if (threadIdx.x < 2) {
    int* b = bsum + threadIdx.x * (NB_SCAN + 1);
    int acc = 0;
    for (int i = 0; i < NB_SCAN; ++i) { int v = b[i]; b[i] = acc; acc += v; }
    b[NB_SCAN] = acc;
  }
}

// phase C: per-block exclusive scan + block offset; grid (NB_SCAN, 2)
__global__ __launch_bounds__(256) void k_scan_c(
    const int* __restrict__ c0, const int* __restrict__ c1,
    const int* __restrict__ bsum,
    int* __restrict__ s0, int* __restrict__ s1, int n)
{
  const int* c = blockIdx.y ? c1 : c0;
  int* sO = blockIdx.y ? s1 : s0;
  if (blockIdx.x == 0 && threadIdx.x == 0)
    sO[n] = bsum[blockIdx.y * (NB_SCAN + 1) + NB_SCAN];
  int boff = bsum[blockIdx.y * (NB_SCAN + 1) + blockIdx.x];
  int i0 = blockIdx.x * 1024 + threadIdx.x * 4;
  int4 v = {0, 0, 0, 0};
  if (i0 < n) v = ((const int4*)c)[i0 >> 2];
  int tsum = v.x + v.y + v.z + v.w;
  int lane = threadIdx.x & 63, wid = threadIdx.x >> 6;
  int inc = tsum;
  #pragma unroll
  for (int off = 1; off < 64; off <<= 1) {
    int u = __shfl_up(inc, off, 64);
    if (lane >= off) inc += u;
  }
  __shared__ int ws[4];
  if (lane == 63) ws[wid] = inc;
  __syncthreads();
  int woff = 0;
  if (wid > 0) woff += ws[0];
  if (wid > 1) woff += ws[1];
  if (wid > 2) woff += ws[2];
  int ex = boff + woff + inc - tsum;
  if (i0 < n) {
    int4 o;
    o.x = ex; o.y = ex + v.x; o.z = o.y + v.y; o.w = o.z + v.z;
    ((int4*)sO)[i0 >> 2] = o;
  }
}

__global__ __launch_bounds__(256) void k_scatter_eer(
    const int* __restrict__ eidx, const int* __restrict__ erel,
    const int* __restrict__ start, int* __restrict__ fill,
    int* __restrict__ scol, int* __restrict__ srel, int neer)
{
  int i = blockIdx.x * 256 + threadIdx.x;
  if (i >= neer) return;
  int row = eidx[i];
  int pos = start[row] + atomicAdd(&fill[row], 1);
  scol[pos] = eidx[neer + i];
  srel[pos] = erel[i];
}

__global__ __launch_bounds__(256) void k_scatter_adj(
    const int* __restrict__ aidx, const float* __restrict__ adata,
    const int* __restrict__ start, int* __restrict__ fill,
    int* __restrict__ scol, float* __restrict__ sval, int ne)
{
  int i = blockIdx.x * 256 + threadIdx.x;
  if (i >= ne) return;
  int row = aidx[i];
  int pos = start[row] + atomicAdd(&fill[row], 1);
  scol[pos] = aidx[ne + i];
  sval[pos] = adata[i];
}

// ---------------- attention, CSR row-parallel, all-bf16 tables -------------
// outb[row] = bf16( base[row] + alpha * relu( (sum at_j*E[col_j]) / sum at_j ) )
__global__ __launch_bounds__(256) void k_att_csr(
    const unsigned short* __restrict__ Eb, const float* __restrict__ w,
    const int* __restrict__ start, const int* __restrict__ scol,
    const int* __restrict__ srel, const unsigned short* __restrict__ baseb,
    float alpha, unsigned short* __restrict__ outb)
{
  int wave = threadIdx.x >> 6, lane = threadIdx.x & 63;
  int row = blockIdx.x * 4 + wave;
  if (row >= KG_E) return;
  int s = start[row], e = start[row + 1];
  float er[5], acc[5] = {0.f, 0.f, 0.f, 0.f, 0.f};
  #pragma unroll
  for (int c = 0; c < 5; ++c) {
    int d = lane + c * 64;
    er[c] = (d < E_DIM) ? bf2f(Eb[(size_t)row * E_DIM + d]) : 0.f;
  }
  float rs = 0.f;
  for (int j = s; j < e; ++j) {
    int col = scol[j], rel = srel[j];
    const unsigned short* ec = Eb + (size_t)col * E_DIM;
    const float* wh = w + (size_t)rel * E_DIM;
    const float* wt = w + (size_t)(KG_R + rel) * E_DIM;
    float ecv[5];
    float p = 0.f;
    #pragma unroll
    for (int c = 0; c < 5; ++c) {
      int d = lane + c * 64;
      if (d < E_DIM) {
        float b = bf2f(ec[d]);
        ecv[c] = b;
        p += er[c] * wh[d] + b * wt[d];
      } else ecv[c] = 0.f;
    }
    #pragma unroll
    for (int off = 32; off > 0; off >>= 1) p += __shfl_xor(p, off, 64);
    float la = p >= 0.f ? p : LRELU * p;
    float at = __expf(-la);
    rs += at;
    #pragma unroll
    for (int c = 0; c < 5; ++c) acc[c] += at * ecv[c];
  }
  float iv = (rs == 0.f) ? 0.f : 1.f / rs;
  #pragma unroll
  for (int c = 0; c < 5; ++c) {
    int d = lane + c * 64;
    if (d < E_DIM) {
      size_t i = (size_t)row * E_DIM + d;
      float v = acc[c] * iv;
      v = v > 0.f ? v : 0.f;
      outb[i] = f2bf(bf2f(baseb[i]) + alpha * v);
    }
  }
}

// ---------------- fused spmm + highway -------------------------------------
// y = sum val*X[col]; g = sig(Gb+br); out = g*relu(y) + (1-g)*base
__global__ __launch_bounds__(256) void k_spmm_hw(
    const unsigned short* __restrict__ Xb, const int* __restrict__ start,
    const int* __restrict__ scol, const float* __restrict__ sval,
    const unsigned short* __restrict__ Gb, const unsigned short* __restrict__ baseb,
    const float* __restrict__ br,
    unsigned short* __restrict__ outb, float* __restrict__ outf)
{
  int wave = threadIdx.x >> 6, lane = threadIdx.x & 63;
  int row = blockIdx.x * 4 + wave;
  if (row >= KG_E) return;
  int s = start[row], e = start[row + 1];
  float acc[5] = {0.f, 0.f, 0.f, 0.f, 0.f};
  for (int j = s; j < e; ++j) {
    int col = scol[j];
    float v = sval[j];
    const unsigned short* xp = Xb + (size_t)col * E_DIM;
    #pragma unroll
    for (int c = 0; c < 5; ++c) {
      int d = lane + c * 64;
      if (d < E_DIM) acc[c] += v * bf2f(xp[d]);
    }
  }
  #pragma unroll
  for (int c = 0; c < 5; ++c) {
    int d = lane + c * 64;
    if (d < E_DIM) {
      size_t i = (size_t)row * E_DIM + d;
      float g = 1.f / (1.f + __expf(-(bf2f(Gb[i]) + br[d])));
      float yy = acc[c] > 0.f ? acc[c] : 0.f;
      float b = bf2f(baseb[i]);
      float o = g * yy + (1.f - g) * b;
      if (outb) outb[i] = f2bf(o);
      else      outf[i] = o;
    }
  }
}

// ---------------- pack W into MFMA B-fragment layout -----------------------
__global__ __launch_bounds__(64) void k_packW(
    const float* __restrict__ W1, const float* __restrict__ W2,
    unsigned short* __restrict__ Wp)
{
  int lane = threadIdx.x;
  int t = blockIdx.x, s = blockIdx.y;
  int c = t * 16 + (lane & 15);
  unsigned short v[8];
  #pragma unroll
  for (int j = 0; j < 8; ++j) {
    int k = s * 32 + (lane >> 4) * 8 + j;
    float x = 0.f;
    if (k < E_DIM && c < 2 * E_DIM)
      x = (c < E_DIM) ? W1[(size_t)k * E_DIM + c]
                      : W2[(size_t)k * E_DIM + (c - E_DIM)];
    v[j] = f2bf(x);
  }
  size_t base = ((size_t)(t * NK + s) * 64 + lane) * 8;
  #pragma unroll
  for (int j = 0; j < 8; ++j) Wp[base + j] = v[j];
}

// ---------------- fused dual-GEMM: Y1,Y2 (bf16) = X @ {gcnW1, hwWr} --------
__global__ __launch_bounds__(256) void k_gemm2_mfma(
    const unsigned short* __restrict__ Xb, const unsigned short* __restrict__ Wp,
    unsigned short* __restrict__ Y1, unsigned short* __restrict__ Y2, int M)
{
  __shared__ unsigned short Xs[32][XS_LD];
  int tid = threadIdx.x;
  int r0 = blockIdx.x * 32;
  int nb = blockIdx.y;

  for (int t = tid; t < 32 * (XS_LD / 2); t += 256) {
    int r = t / (XS_LD / 2), u = t % (XS_LD / 2);
    unsigned v = 0;
    int rg = r0 + r;
    if (rg < M && u < E_DIM / 2) v = ((const unsigned*)Xb)[(size_t)rg * (E_DIM / 2) + u];
    ((unsigned*)&Xs[0][0])[r * (XS_LD / 2) + u] = v;
  }
  __syncthreads();

  int wid = tid >> 6, lane = tid & 63;
  int wave_m = wid >> 1, wave_n = wid & 1;
  int rowA = wave_m * 16 + (lane & 15);
  int kgrp = (lane >> 4) * 8;
  int tb0 = nb * 8 + wave_n * 4;

  const bf16x8* wfrag = (const bf16x8*)Wp + (size_t)tb0 * (NK * 64) + lane;

  f32x4 acc[4] = {{0,0,0,0},{0,0,0,0},{0,0,0,0},{0,0,0,0}};
  #pragma unroll 2
  for (int ks = 0; ks < NK; ++ks) {
    bf16x8 a = *(const bf16x8*)&Xs[rowA][ks * 32 + kgrp];
    #pragma unroll
    for (int nt = 0; nt < 4; ++nt) {
      bf16x8 b = wfrag[(nt * NK + ks) * 64];
      acc[nt] = __builtin_amdgcn_mfma_f32_16x16x32_bf16(a, b, acc[nt], 0, 0, 0);
    }
  }

  int rbase = r0 + wave_m * 16 + ((lane >> 4) << 2);
  #pragma unroll
  for (int nt = 0; nt < 4; ++nt) {
    int c = (tb0 + nt) * 16 + (lane & 15);
    #pragma unroll
    for (int j = 0; j < 4; ++j) {
      int row = rbase + j;
      if (row < M) {
        unsigned short hv = f2bf(acc[nt][j]);
        if (c < E_DIM)            Y1[(size_t)row * E_DIM + c] = hv;
        else if (c < 2 * E_DIM)   Y2[(size_t)row * E_DIM + (c - E_DIM)] = hv;
      }
    }
  }
}

extern "C" void kernel_launch(void* const* d_in, const int* in_sizes, int n_in,
                              void* d_out, int out_size, void* d_ws, size_t ws_size,
                              hipStream_t stream)
{
  const float* primal      = (const float*)d_in[0];
  const float* r_head      = (const float*)d_in[1];
  const float* r_tail      = (const float*)d_in[2];
  const float* e_adj_data  = (const float*)d_in[3];
  const float* be_L        = (const float*)d_in[4];
  const float* be_R        = (const float*)d_in[5];
  const float* atten_r     = (const float*)d_in[6];
  const float* gcnW1       = (const float*)d_in[7];
  const float* hwWr        = (const float*)d_in[8];
  const float* hwbr        = (const float*)d_in[9];
  const int*   e_adj_index = (const int*)d_in[10];
  const int*   eer_idx     = (const int*)d_in[11];
  const int*   eer_rel     = (const int*)d_in[12];
  int ne   = in_sizes[10] / 2;
  int neer = in_sizes[11] / 2;

  char* ws = (char*)d_ws;
  size_t off = 0;
  auto take = [&](size_t bytes) {
    void* p = ws + off;
    off = (off + bytes + 255) & ~(size_t)255;
    return p;
  };
  int*   cnt      = (int*)  take((size_t)2 * KG_R * sizeof(int));
  float* inv      = (float*)take((size_t)2 * KG_R * sizeof(float));
  int*   rfill    = (int*)  take((size_t)2 * KG_R * sizeof(int));
  float* rsumb    = (float*)take((size_t)2 * KG_R * sizeof(float));
  int*   lidx     = (int*)  take((size_t)2 * KG_R * CAP * sizeof(int));
  float* lsv      = (float*)take((size_t)2 * KG_R * CAP * sizeof(float));
  float* wbuf     = (float*)take((size_t)2 * KG_R * E_DIM * sizeof(float));
  int*   hcntA    = (int*)  take((size_t)KG_E * sizeof(int));
  int*   hcntB    = (int*)  take((size_t)KG_E * sizeof(int));
  int*   hfillA   = (int*)  take((size_t)KG_E * sizeof(int));
  int*   hfillB   = (int*)  take((size_t)KG_E * sizeof(int));
  int*   bsum     = (int*)  take((size_t)2 * (NB_SCAN + 1) * sizeof(int));
  int*   eer_start= (int*)  take((size_t)(KG_E + 4) * sizeof(int));
  int*   adj_start= (int*)  take((size_t)(KG_E + 4) * sizeof(int));
  int*   eer_scol = (int*)  take((size_t)neer * sizeof(int));
  int*   eer_srel = (int*)  take((size_t)neer * sizeof(int));
  int*   adj_scol = (int*)  take((size_t)ne * sizeof(int));
  float* adj_sval = (float*)take((size_t)ne * sizeof(float));
  unsigned short* Wp = (unsigned short*)take((size_t)NT * NK * 64 * 8 * sizeof(unsigned short));
  unsigned short* B0 = (unsigned short*)take((size_t)KG_E * E_DIM * sizeof(unsigned short)); // primal bf16
  unsigned short* B1 = (unsigned short*)take((size_t)KG_E * E_DIM * sizeof(unsigned short)); // e1 / g2
  unsigned short* B2 = (unsigned short*)take((size_t)KG_E * E_DIM * sizeof(unsigned short)); // e2
  unsigned short* Fb = (unsigned short*)take((size_t)KG_E * E_DIM * sizeof(unsigned short)); // X@gcnW1
  unsigned short* Gb = (unsigned short*)take((size_t)KG_E * E_DIM * sizeof(unsigned short)); // X@hwWr
  float* out      = (float*)d_out;
  (void)ws_size; (void)n_in; (void)out_size;

  int eg = (neer + 255) / 256;
  int ag = (ne + 255) / 256;

  // ---- CSR builds (both graphs; shared 3-phase scan) ----
  hipMemsetAsync(hcntA, 0, (size_t)KG_E * sizeof(int), stream);
  hipMemsetAsync(hcntB, 0, (size_t)KG_E * sizeof(int), stream);
  k_hist<<<eg, 256, 0, stream>>>(eer_idx, hcntA, neer);
  k_hist<<<ag, 256, 0, stream>>>(e_adj_index, hcntB, ne);
  k_scan_a<<<dim3(NB_SCAN, 2), 256, 0, stream>>>(hcntA, hcntB, bsum, KG_E);
  k_scan_b<<<1, 64, 0, stream>>>(bsum);
  k_scan_c<<<dim3(NB_SCAN, 2), 256, 0, stream>>>(hcntA, hcntB, bsum,
                                                 eer_start, adj_start, KG_E);
  hipMemsetAsync(hfillA, 0, (size_t)KG_E * sizeof(int), stream);
  hipMemsetAsync(hfillB, 0, (size_t)KG_E * sizeof(int), stream);
  k_scatter_eer<<<eg, 256, 0, stream>>>(eer_idx, eer_rel, eer_start, hfillA,
                                        eer_scol, eer_srel, neer);
  k_scatter_adj<<<ag, 256, 0, stream>>>(e_adj_index, e_adj_data, adj_start, hfillB,
                                        adj_scol, adj_sval, ne);

  // ---- compact r_head/r_tail + pack weights + primal bf16 ----
  hipMemsetAsync(rfill, 0, (size_t)2 * KG_R * sizeof(int), stream);
  hipMemsetAsync(rsumb, 0, (size_t)2 * KG_R * sizeof(float), stream);
  k_compact2<<<dim3(NCH, KG_R, 2), 256, 0, stream>>>(r_head, r_tail, be_L, be_R,
                                                     lidx, lsv, rfill, rsumb);
  k_rmeta<<<(2 * KG_R + 255) / 256, 256, 0, stream>>>(rfill, rsumb, cnt, inv);
  k_packW<<<dim3(NT, NK), 64, 0, stream>>>(gcnW1, hwWr, Wp);
  int n4 = KG_E * E_DIM / 4;
  k_tobf<<<(n4 + 255) / 256, 256, 0, stream>>>(primal, B0, n4);

  int rg = (KG_E + 3) / 4;

  // ---- attention layer 1: e1 = primal + 0.1*att(primal) -> B1 ----
  k_rlayer<<<2 * KG_R, 320, 0, stream>>>(B0, lidx, lsv, cnt, inv, atten_r, wbuf);
  k_att_csr<<<rg, 256, 0, stream>>>(B0, wbuf, eer_start, eer_scol, eer_srel,
                                    B0, 0.1f, B1);
  // ---- attention layer 2: e2 = primal + 0.3*att(e1) -> B2 ----
  k_rlayer<<<2 * KG_R, 320, 0, stream>>>(B1, lidx, lsv, cnt, inv, atten_r, wbuf);
  k_att_csr<<<rg, 256, 0, stream>>>(B1, wbuf, eer_start, eer_scol, eer_srel,
                                    B0, 0.3f, B2);

  // ---- GCN + highway 1: Fb,Gb = e2 @ {gcnW1,hwWr}; g2 -> B1 ----
  dim3 gg((KG_E + 31) / 32, 5);
  k_gemm2_mfma<<<gg, 256, 0, stream>>>(B2, Wp, Fb, Gb, KG_E);
  k_spmm_hw<<<rg, 256, 0, stream>>>(Fb, adj_start, adj_scol, adj_sval,
                                    Gb, B2, hwbr, B1, (float*)nullptr);

  // ---- GCN + highway 2: Fb,Gb = g2 @ {gcnW1,hwWr}; out = highway ----
  k_gemm2_mfma<<<gg, 256, 0, stream>>>(B1, Wp, Fb, Gb, KG_E);
  k_spmm_hw<<<rg, 256, 0, stream>>>(Fb, adj_start, adj_scol, adj_sval,
                                    Gb, B1, hwbr, (unsigned short*)nullptr, out);
}

// Round 8
// 866.774 us; speedup vs baseline: 1.6479x; 1.0230x over previous
//
#include <hip/hip_runtime.h>
#include <math.h>

#define KG_E  50000
#define KG_R  500
#define E_DIM 300
#define NPAIR 150         // E_DIM/2, bf16 pairs per row
#define CAP   1024
#define LRELU 0.2f

// MFMA GEMM geometry: Y[M,600(pad 640)] = X[M,300(pad 320)] @ Wcat
#define NK    10
#define NT    40
#define XS_LD 328

#define NB_SCAN 49        // ceil(KG_E/1024)

typedef __attribute__((ext_vector_type(8))) short bf16x8;
typedef __attribute__((ext_vector_type(4))) float f32x4;

__device__ __forceinline__ unsigned short f2bf(float x) {
  union { float f; unsigned u; } v; v.f = x;
  unsigned r = v.u + 0x7FFFu + ((v.u >> 16) & 1u);
  return (unsigned short)(r >> 16);
}
__device__ __forceinline__ float bf2f(unsigned short x) {
  union { unsigned u; float f; } v; v.u = ((unsigned)x) << 16; return v.f;
}
__device__ __forceinline__ float plo(unsigned u) {     // low bf16 of pair
  union { unsigned u; float f; } v; v.u = u << 16; return v.f;
}
__device__ __forceinline__ float phi(unsigned u) {     // high bf16 of pair
  union { unsigned u; float f; } v; v.u = u & 0xFFFF0000u; return v.f;
}
__device__ __forceinline__ unsigned packbf(float lo, float hi) {
  return (unsigned)f2bf(lo) | ((unsigned)f2bf(hi) << 16);
}

// ---------------- f32 -> bf16 table conversion -----------------------------
__global__ __launch_bounds__(256) void k_tobf(
    const float* __restrict__ src, unsigned short* __restrict__ dst, int n4)
{
  int i = blockIdx.x * 256 + threadIdx.x;
  if (i >= n4) return;
  float4 f = ((const float4*)src)[i];
  ushort4 o;
  o.x = f2bf(f.x); o.y = f2bf(f.y); o.z = f2bf(f.z); o.w = f2bf(f.w);
  ((ushort4*)dst)[i] = o;
}

// ---------------- compaction: LDS-staged, one global atomic per block ------
#define NCH 5
#define SCAP 1024
__global__ __launch_bounds__(256) void k_compact2(
    const float* __restrict__ r_head, const float* __restrict__ r_tail,
    const float* __restrict__ be_L, const float* __restrict__ be_R,
    int* __restrict__ lidx, float* __restrict__ lsval,
    int* __restrict__ fill, float* __restrict__ rsum)
{
  __shared__ int   ls_e[SCAP];
  __shared__ float ls_v[SCAP];
  __shared__ int   ls_cnt;
  __shared__ float ls_sum;
  __shared__ int   ls_base;
  int m = blockIdx.z;
  int r = blockIdx.y;
  const float* rowp = (m ? r_tail : r_head) + (size_t)r * KG_E;
  const float* be   = m ? be_R : be_L;
  int slot = m * KG_R + r;
  int lane = threadIdx.x & 63;
  if (threadIdx.x == 0) { ls_cnt = 0; ls_sum = 0.f; }
  __syncthreads();

  const int CH = KG_E / NCH;
  int c0 = blockIdx.x * CH;
  const float4* rp4 = (const float4*)(rowp + c0);
  float lsum = 0.f;
  for (int i = threadIdx.x; i < CH / 4; i += 256) {
    float4 f = rp4[i];
    float vs[4] = {f.x, f.y, f.z, f.w};
    #pragma unroll
    for (int q = 0; q < 4; ++q) {
      float v = vs[q];
      lsum += v;
      bool nz = (v != 0.f);
      unsigned long long mask = __ballot(nz);
      if (mask) {
        int leader = (int)__ffsll(mask) - 1;
        int wbase = 0;
        if (lane == leader) wbase = atomicAdd(&ls_cnt, (int)__popcll(mask));
        wbase = __shfl(wbase, leader, 64);
        if (nz) {
          int pos = wbase + (int)__popcll(mask & ((1ULL << lane) - 1));
          if (pos < SCAP) {
            int e = c0 + 4 * i + q;
            ls_e[pos] = e;
            ls_v[pos] = v * be[e];
          }
        }
      }
    }
  }
  #pragma unroll
  for (int off = 32; off > 0; off >>= 1) lsum += __shfl_xor(lsum, off, 64);
  if (lane == 0 && lsum != 0.f) atomicAdd(&ls_sum, lsum);
  __syncthreads();

  int total = ls_cnt < SCAP ? ls_cnt : SCAP;
  if (threadIdx.x == 0) {
    ls_base = atomicAdd(&fill[slot], total);
    if (ls_sum != 0.f) atomicAdd(&rsum[slot], ls_sum);
  }
  __syncthreads();
  int gbase = ls_base;
  int*   li = lidx  + (size_t)slot * CAP;
  float* lv = lsval + (size_t)slot * CAP;
  for (int i = threadIdx.x; i < total; i += 256) {
    int pos = gbase + i;
    if (pos < CAP) { li[pos] = ls_e[i]; lv[pos] = ls_v[i]; }
  }
}

__global__ __launch_bounds__(256) void k_rmeta(
    const int* __restrict__ fill, const float* __restrict__ rsum,
    int* __restrict__ cnt, float* __restrict__ inv)
{
  int i = blockIdx.x * 256 + threadIdx.x;
  if (i < 2 * KG_R) {
    int c = fill[i];
    cnt[i] = c > CAP ? CAP : c;
    float s = rsum[i];
    inv[i] = (s == 0.f) ? 0.f : 1.f / s;
  }
}

// ---------------- r-layer: pair gathers, packed-bf16 w output --------------
__global__ __launch_bounds__(192) void k_rlayer(
    const unsigned short* __restrict__ Eb, const int* __restrict__ lidx,
    const float* __restrict__ lsval, const int* __restrict__ cnt,
    const float* __restrict__ inv, const float* __restrict__ atten,
    unsigned* __restrict__ wpk)
{
  int b = blockIdx.x;
  int m = b / KG_R, r = b % KG_R;
  int p = threadIdx.x;
  if (p >= NPAIR) return;
  int slot = m * KG_R + r;
  int n = cnt[slot];
  const int*   li = lidx  + (size_t)slot * CAP;
  const float* lv = lsval + (size_t)slot * CAP;
  float alo = 0.f, ahi = 0.f;
  #pragma unroll 4
  for (int i = 0; i < n; ++i) {
    int e = li[i];
    float s = lv[i];
    unsigned u = ((const unsigned*)(Eb + (size_t)e * E_DIM))[p];
    alo += s * plo(u);
    ahi += s * phi(u);
  }
  float iv = inv[slot];
  float vlo = alo * iv; vlo = vlo > 0.f ? vlo : 0.f;
  float vhi = ahi * iv; vhi = vhi > 0.f ? vhi : 0.f;
  vlo *= atten[m * E_DIM + 2 * p];
  vhi *= atten[m * E_DIM + 2 * p + 1];
  wpk[(size_t)slot * NPAIR + p] = packbf(vlo, vhi);
}

// ---------------- CSR build: histogram, 3-phase scan, scatter --------------
__global__ __launch_bounds__(256) void k_hist(
    const int* __restrict__ rows, int* __restrict__ cnt, int n)
{
  int i = blockIdx.x * 256 + threadIdx.x;
  if (i < n) atomicAdd(&cnt[rows[i]], 1);
}

__global__ __launch_bounds__(256) void k_scan_a(
    const int* __restrict__ c0, const int* __restrict__ c1,
    int* __restrict__ bsum, int n)
{
  const int* c = blockIdx.y ? c1 : c0;
  int base = blockIdx.x * 1024;
  int s = 0;
  #pragma unroll
  for (int k = 0; k < 4; ++k) {
    int i = base + k * 256 + threadIdx.x;
    if (i < n) s += c[i];
  }
  #pragma unroll
  for (int off = 32; off > 0; off >>= 1) s += __shfl_xor(s, off, 64);
  __shared__ int ws[4];
  if ((threadIdx.x & 63) == 0) ws[threadIdx.x >> 6] = s;
  __syncthreads();
  if (threadIdx.x == 0)
    bsum[blockIdx.y * (NB_SCAN + 1) + blockIdx.x] = ws[0] + ws[1] + ws[2] + ws[3];
}

__global__ __launch_bounds__(64) void k_scan_b(int* __restrict__ bsum)
{
  if (threadIdx.x < 2) {
    int* b = bsum + threadIdx.x * (NB_SCAN + 1);
    int acc = 0;
    for (int i = 0; i < NB_SCAN; ++i) { int v = b[i]; b[i] = acc; acc += v; }
    b[NB_SCAN] = acc;
  }
}

__global__ __launch_bounds__(256) void k_scan_c(
    const int* __restrict__ c0, const int* __restrict__ c1,
    const int* __restrict__ bsum,
    int* __restrict__ s0, int* __restrict__ s1, int n)
{
  const int* c = blockIdx.y ? c1 : c0;
  int* sO = blockIdx.y ? s1 : s0;
  if (blockIdx.x == 0 && threadIdx.x == 0)
    sO[n] = bsum[blockIdx.y * (NB_SCAN + 1) + NB_SCAN];
  int boff = bsum[blockIdx.y * (NB_SCAN + 1) + blockIdx.x];
  int i0 = blockIdx.x * 1024 + threadIdx.x * 4;
  int4 v = {0, 0, 0, 0};
  if (i0 < n) v = ((const int4*)c)[i0 >> 2];
  int tsum = v.x + v.y + v.z + v.w;
  int lane = threadIdx.x & 63, wid = threadIdx.x >> 6;
  int inc = tsum;
  #pragma unroll
  for (int off = 1; off < 64; off <<= 1) {
    int u = __shfl_up(inc, off, 64);
    if (lane >= off) inc += u;
  }
  __shared__ int ws[4];
  if (lane == 63) ws[wid] = inc;
  __syncthreads();
  int woff = 0;
  if (wid > 0) woff += ws[0];
  if (wid > 1) woff += ws[1];
  if (wid > 2) woff += ws[2];
  int ex = boff + woff + inc - tsum;
  if (i0 < n) {
    int4 o;
    o.x = ex; o.y = ex + v.x; o.z = o.y + v.y; o.w = o.z + v.z;
    ((int4*)sO)[i0 >> 2] = o;
  }
}

__global__ __launch_bounds__(256) void k_scatter_eer(
    const int* __restrict__ eidx, const int* __restrict__ erel,
    const int* __restrict__ start, int* __restrict__ fill,
    int* __restrict__ scol, int* __restrict__ srel, int neer)
{
  int i = blockIdx.x * 256 + threadIdx.x;
  if (i >= neer) return;
  int row = eidx[i];
  int pos = start[row] + atomicAdd(&fill[row], 1);
  scol[pos] = eidx[neer + i];
  srel[pos] = erel[i];
}

__global__ __launch_bounds__(256) void k_scatter_adj(
    const int* __restrict__ aidx, const float* __restrict__ adata,
    const int* __restrict__ start, int* __restrict__ fill,
    int* __restrict__ scol, float* __restrict__ sval, int ne)
{
  int i = blockIdx.x * 256 + threadIdx.x;
  if (i >= ne) return;
  int row = aidx[i];
  int pos = start[row] + atomicAdd(&fill[row], 1);
  scol[pos] = aidx[ne + i];
  sval[pos] = adata[i];
}

// ---------------- attention, CSR row-parallel, pair loads ------------------
__global__ __launch_bounds__(256) void k_att_csr(
    const unsigned short* __restrict__ Eb, const unsigned* __restrict__ wpk,
    const int* __restrict__ start, const int* __restrict__ scol,
    const int* __restrict__ srel, const unsigned short* __restrict__ baseb,
    float alpha, unsigned short* __restrict__ outb)
{
  int wave = threadIdx.x >> 6, lane = threadIdx.x & 63;
  int row = blockIdx.x * 4 + wave;
  if (row >= KG_E) return;
  int s = start[row], e = start[row + 1];
  const unsigned* erp = (const unsigned*)(Eb + (size_t)row * E_DIM);
  float erlo[3], erhi[3];
  float acclo[3] = {0.f, 0.f, 0.f}, acchi[3] = {0.f, 0.f, 0.f};
  #pragma unroll
  for (int c = 0; c < 3; ++c) {
    int p = lane + c * 64;
    if (p < NPAIR) { unsigned u = erp[p]; erlo[c] = plo(u); erhi[c] = phi(u); }
    else { erlo[c] = 0.f; erhi[c] = 0.f; }
  }
  float rs = 0.f;
  for (int j = s; j < e; ++j) {
    int col = scol[j], rel = srel[j];
    const unsigned* ecp = (const unsigned*)(Eb + (size_t)col * E_DIM);
    const unsigned* whp = wpk + (size_t)rel * NPAIR;
    const unsigned* wtp = wpk + (size_t)(KG_R + rel) * NPAIR;
    float eclo[3], echi[3];
    float p4 = 0.f;
    #pragma unroll
    for (int c = 0; c < 3; ++c) {
      int p = lane + c * 64;
      if (p < NPAIR) {
        unsigned uc = ecp[p], uh = whp[p], ut = wtp[p];
        float clo = plo(uc), chi = phi(uc);
        eclo[c] = clo; echi[c] = chi;
        p4 += erlo[c] * plo(uh) + erhi[c] * phi(uh)
            + clo * plo(ut) + chi * phi(ut);
      } else { eclo[c] = 0.f; echi[c] = 0.f; }
    }
    #pragma unroll
    for (int off = 32; off > 0; off >>= 1) p4 += __shfl_xor(p4, off, 64);
    float la = p4 >= 0.f ? p4 : LRELU * p4;
    float at = __expf(-la);
    rs += at;
    #pragma unroll
    for (int c = 0; c < 3; ++c) { acclo[c] += at * eclo[c]; acchi[c] += at * echi[c]; }
  }
  float iv = (rs == 0.f) ? 0.f : 1.f / rs;
  const unsigned* bp = (const unsigned*)(baseb + (size_t)row * E_DIM);
  unsigned* op = (unsigned*)(outb + (size_t)row * E_DIM);
  #pragma unroll
  for (int c = 0; c < 3; ++c) {
    int p = lane + c * 64;
    if (p < NPAIR) {
      unsigned ub = bp[p];
      float vlo = acclo[c] * iv; vlo = vlo > 0.f ? vlo : 0.f;
      float vhi = acchi[c] * iv; vhi = vhi > 0.f ? vhi : 0.f;
      float olo = plo(ub) + alpha * vlo;
      float ohi = phi(ub) + alpha * vhi;
      op[p] = packbf(olo, ohi);
    }
  }
}

// ---------------- fused spmm + highway, pair loads -------------------------
__global__ __launch_bounds__(256) void k_spmm_hw(
    const unsigned short* __restrict__ Xb, const int* __restrict__ start,
    const int* __restrict__ scol, const float* __restrict__ sval,
    const unsigned short* __restrict__ Gb, const unsigned short* __restrict__ baseb,
    const float* __restrict__ br,
    unsigned short* __restrict__ outb, float* __restrict__ outf)
{
  int wave = threadIdx.x >> 6, lane = threadIdx.x & 63;
  int row = blockIdx.x * 4 + wave;
  if (row >= KG_E) return;
  int s = start[row], e = start[row + 1];
  float acclo[3] = {0.f, 0.f, 0.f}, acchi[3] = {0.f, 0.f, 0.f};
  for (int j = s; j < e; ++j) {
    int col = scol[j];
    float v = sval[j];
    const unsigned* xp = (const unsigned*)(Xb + (size_t)col * E_DIM);
    #pragma unroll
    for (int c = 0; c < 3; ++c) {
      int p = lane + c * 64;
      if (p < NPAIR) {
        unsigned u = xp[p];
        acclo[c] += v * plo(u);
        acchi[c] += v * phi(u);
      }
    }
  }
  const unsigned* gp = (const unsigned*)(Gb + (size_t)row * E_DIM);
  const unsigned* bp = (const unsigned*)(baseb + (size_t)row * E_DIM);
  #pragma unroll
  for (int c = 0; c < 3; ++c) {
    int p = lane + c * 64;
    if (p < NPAIR) {
      unsigned ug = gp[p], ub = bp[p];
      float glo = 1.f / (1.f + __expf(-(plo(ug) + br[2 * p])));
      float ghi = 1.f / (1.f + __expf(-(phi(ug) + br[2 * p + 1])));
      float ylo = acclo[c] > 0.f ? acclo[c] : 0.f;
      float yhi = acchi[c] > 0.f ? acchi[c] : 0.f;
      float olo = glo * ylo + (1.f - glo) * plo(ub);
      float ohi = ghi * yhi + (1.f - ghi) * phi(ub);
      if (outb) {
        ((unsigned*)(outb + (size_t)row * E_DIM))[p] = packbf(olo, ohi);
      } else {
        float2 o2; o2.x = olo; o2.y = ohi;
        ((float2*)(outf + (size_t)row * E_DIM))[p] = o2;
      }
    }
  }
}

// ---------------- pack W into MFMA B-fragment layout -----------------------
__global__ __launch_bounds__(64) void k_packW(
    const float* __restrict__ W1, const float* __restrict__ W2,
    unsigned short* __restrict__ Wp)
{
  int lane = threadIdx.x;
  int t = blockIdx.x, s = blockIdx.y;
  int c = t * 16 + (lane & 15);
  unsigned short v[8];
  #pragma unroll
  for (int j = 0; j < 8; ++j) {
    int k = s * 32 + (lane >> 4) * 8 + j;
    float x = 0.f;
    if (k < E_DIM && c < 2 * E_DIM)
      x = (c < E_DIM) ? W1[(size_t)k * E_DIM + c]
                      : W2[(size_t)k * E_DIM + (c - E_DIM)];
    v[j] = f2bf(x);
  }
  size_t base = ((size_t)(t * NK + s) * 64 + lane) * 8;
  #pragma unroll
  for (int j = 0; j < 8; ++j) Wp[base + j] = v[j];
}

// ---------------- fused dual-GEMM: Y1,Y2 (bf16) = X @ {gcnW1, hwWr} --------
__global__ __launch_bounds__(256) void k_gemm2_mfma(
    const unsigned short* __restrict__ Xb, const unsigned short* __restrict__ Wp,
    unsigned short* __restrict__ Y1, unsigned short* __restrict__ Y2, int M)
{
  __shared__ unsigned short Xs[32][XS_LD];
  int tid = threadIdx.x;
  int r0 = blockIdx.x * 32;
  int nb = blockIdx.y;

  for (int t = tid; t < 32 * (XS_LD / 2); t += 256) {
    int r = t / (XS_LD / 2), u = t % (XS_LD / 2);
    unsigned v = 0;
    int rg = r0 + r;
    if (rg < M && u < E_DIM / 2) v = ((const unsigned*)Xb)[(size_t)rg * (E_DIM / 2) + u];
    ((unsigned*)&Xs[0][0])[r * (XS_LD / 2) + u] = v;
  }
  __syncthreads();

  int wid = tid >> 6, lane = tid & 63;
  int wave_m = wid >> 1, wave_n = wid & 1;
  int rowA = wave_m * 16 + (lane & 15);
  int kgrp = (lane >> 4) * 8;
  int tb0 = nb * 8 + wave_n * 4;

  const bf16x8* wfrag = (const bf16x8*)Wp + (size_t)tb0 * (NK * 64) + lane;

  f32x4 acc[4] = {{0,0,0,0},{0,0,0,0},{0,0,0,0},{0,0,0,0}};
  #pragma unroll 2
  for (int ks = 0; ks < NK; ++ks) {
    bf16x8 a = *(const bf16x8*)&Xs[rowA][ks * 32 + kgrp];
    #pragma unroll
    for (int nt = 0; nt < 4; ++nt) {
      bf16x8 b = wfrag[(nt * NK + ks) * 64];
      acc[nt] = __builtin_amdgcn_mfma_f32_16x16x32_bf16(a, b, acc[nt], 0, 0, 0);
    }
  }

  int rbase = r0 + wave_m * 16 + ((lane >> 4) << 2);
  #pragma unroll
  for (int nt = 0; nt < 4; ++nt) {
    int c = (tb0 + nt) * 16 + (lane & 15);
    #pragma unroll
    for (int j = 0; j < 4; ++j) {
      int row = rbase + j;
      if (row < M) {
        unsigned short hv = f2bf(acc[nt][j]);
        if (c < E_DIM)            Y1[(size_t)row * E_DIM + c] = hv;
        else if (c < 2 * E_DIM)   Y2[(size_t)row * E_DIM + (c - E_DIM)] = hv;
      }
    }
  }
}

extern "C" void kernel_launch(void* const* d_in, const int* in_sizes, int n_in,
                              void* d_out, int out_size, void* d_ws, size_t ws_size,
                              hipStream_t stream)
{
  const float* primal      = (const float*)d_in[0];
  const float* r_head      = (const float*)d_in[1];
  const float* r_tail      = (const float*)d_in[2];
  const float* e_adj_data  = (const float*)d_in[3];
  const float* be_L        = (const float*)d_in[4];
  const float* be_R        = (const float*)d_in[5];
  const float* atten_r     = (const float*)d_in[6];
  const float* gcnW1       = (const float*)d_in[7];
  const float* hwWr        = (const float*)d_in[8];
  const float* hwbr        = (const float*)d_in[9];
  const int*   e_adj_index = (const int*)d_in[10];
  const int*   eer_idx     = (const int*)d_in[11];
  const int*   eer_rel     = (const int*)d_in[12];
  int ne   = in_sizes[10] / 2;
  int neer = in_sizes[11] / 2;

  char* ws = (char*)d_ws;
  size_t off = 0;
  auto take = [&](size_t bytes) {
    void* p = ws + off;
    off = (off + bytes + 255) & ~(size_t)255;
    return p;
  };
  int*   cnt      = (int*)  take((size_t)2 * KG_R * sizeof(int));
  float* inv      = (float*)take((size_t)2 * KG_R * sizeof(float));
  // ---- contiguous zero-init block (single memset) ----
  size_t z0 = off;
  int*   hcntA    = (int*)  take((size_t)KG_E * sizeof(int));
  int*   hcntB    = (int*)  take((size_t)KG_E * sizeof(int));
  int*   hfillA   = (int*)  take((size_t)KG_E * sizeof(int));
  int*   hfillB   = (int*)  take((size_t)KG_E * sizeof(int));
  int*   rfill    = (int*)  take((size_t)2 * KG_R * sizeof(int));
  float* rsumb    = (float*)take((size_t)2 * KG_R * sizeof(float));
  size_t z1 = off;
  // ----------------------------------------------------
  int*   lidx     = (int*)  take((size_t)2 * KG_R * CAP * sizeof(int));
  float* lsv      = (float*)take((size_t)2 * KG_R * CAP * sizeof(float));
  unsigned* wpk   = (unsigned*)take((size_t)2 * KG_R * NPAIR * sizeof(unsigned));
  int*   bsum     = (int*)  take((size_t)2 * (NB_SCAN + 1) * sizeof(int));
  int*   eer_start= (int*)  take((size_t)(KG_E + 4) * sizeof(int));
  int*   adj_start= (int*)  take((size_t)(KG_E + 4) * sizeof(int));
  int*   eer_scol = (int*)  take((size_t)neer * sizeof(int));
  int*   eer_srel = (int*)  take((size_t)neer * sizeof(int));
  int*   adj_scol = (int*)  take((size_t)ne * sizeof(int));
  float* adj_sval = (float*)take((size_t)ne * sizeof(float));
  unsigned short* Wp = (unsigned short*)take((size_t)NT * NK * 64 * 8 * sizeof(unsigned short));
  unsigned short* B0 = (unsigned short*)take((size_t)KG_E * E_DIM * sizeof(unsigned short)); // primal bf16
  unsigned short* B1 = (unsigned short*)take((size_t)KG_E * E_DIM * sizeof(unsigned short)); // e1 / g2
  unsigned short* B2 = (unsigned short*)take((size_t)KG_E * E_DIM * sizeof(unsigned short)); // e2
  unsigned short* Fb = (unsigned short*)take((size_t)KG_E * E_DIM * sizeof(unsigned short)); // X@gcnW1
  unsigned short* Gb = (unsigned short*)take((size_t)KG_E * E_DIM * sizeof(unsigned short)); // X@hwWr
  float* out      = (float*)d_out;
  (void)ws_size; (void)n_in; (void)out_size;

  int eg = (neer + 255) / 256;
  int ag = (ne + 255) / 256;

  // ---- single memset for all zero-init scratch ----
  hipMemsetAsync(ws + z0, 0, z1 - z0, stream);

  // ---- CSR builds (both graphs; shared 3-phase scan) ----
  k_hist<<<eg, 256, 0, stream>>>(eer_idx, hcntA, neer);
  k_hist<<<ag, 256, 0, stream>>>(e_adj_index, hcntB, ne);
  k_scan_a<<<dim3(NB_SCAN, 2), 256, 0, stream>>>(hcntA, hcntB, bsum, KG_E);
  k_scan_b<<<1, 64, 0, stream>>>(bsum);
  k_scan_c<<<dim3(NB_SCAN, 2), 256, 0, stream>>>(hcntA, hcntB, bsum,
                                                 eer_start, adj_start, KG_E);
  k_scatter_eer<<<eg, 256, 0, stream>>>(eer_idx, eer_rel, eer_start, hfillA,
                                        eer_scol, eer_srel, neer);
  k_scatter_adj<<<ag, 256, 0, stream>>>(e_adj_index, e_adj_data, adj_start, hfillB,
                                        adj_scol, adj_sval, ne);

  // ---- compact r_head/r_tail + pack weights + primal bf16 ----
  k_compact2<<<dim3(NCH, KG_R, 2), 256, 0, stream>>>(r_head, r_tail, be_L, be_R,
                                                     lidx, lsv, rfill, rsumb);
  k_rmeta<<<(2 * KG_R + 255) / 256, 256, 0, stream>>>(rfill, rsumb, cnt, inv);
  k_packW<<<dim3(NT, NK), 64, 0, stream>>>(gcnW1, hwWr, Wp);
  int n4 = KG_E * E_DIM / 4;
  k_tobf<<<(n4 + 255) / 256, 256, 0, stream>>>(primal, B0, n4);

  int rg = (KG_E + 3) / 4;

  // ---- attention layer 1: e1 = primal + 0.1*att(primal) -> B1 ----
  k_rlayer<<<2 * KG_R, 192, 0, stream>>>(B0, lidx, lsv, cnt, inv, atten_r, wpk);
  k_att_csr<<<rg, 256, 0, stream>>>(B0, wpk, eer_start, eer_scol, eer_srel,
                                    B0, 0.1f, B1);
  // ---- attention layer 2: e2 = primal + 0.3*att(e1) -> B2 ----
  k_rlayer<<<2 * KG_R, 192, 0, stream>>>(B1, lidx, lsv, cnt, inv, atten_r, wpk);
  k_att_csr<<<rg, 256, 0, stream>>>(B1, wpk, eer_start, eer_scol, eer_srel,
                                    B0, 0.3f, B2);

  // ---- GCN + highway 1: Fb,Gb = e2 @ {gcnW1,hwWr}; g2 -> B1 ----
  dim3 gg((KG_E + 31) / 32, 5);
  k_gemm2_mfma<<<gg, 256, 0, stream>>>(B2, Wp, Fb, Gb, KG_E);
  k_spmm_hw<<<rg, 256, 0, stream>>>(Fb, adj_start, adj_scol, adj_sval,
                                    Gb, B2, hwbr, B1, (float*)nullptr);

  // ---- GCN + highway 2: Fb,Gb = g2 @ {gcnW1,hwWr}; out = highway ----
  k_gemm2_mfma<<<gg, 256, 0, stream>>>(B1, Wp, Fb, Gb, KG_E);
  k_spmm_hw<<<rg, 256, 0, stream>>>(Fb, adj_start, adj_scol, adj_sval,
                                    Gb, B1, hwbr, (unsigned short*)nullptr, out);
}

// Round 9
// 830.881 us; speedup vs baseline: 1.7191x; 1.0432x over previous
//
#include <hip/hip_runtime.h>
#include <math.h>

#define KG_E  50000
#define KG_R  500
#define E_DIM 300
#define NPAIR 150         // E_DIM/2 bf16 pairs per row
#define NP2   75          // E_DIM/4 uint2 per row
#define CAP   1024
#define LRELU 0.2f

// MFMA GEMM geometry: Y[M,600(pad 640)] = X[M,300(pad 320)] @ Wcat
#define NK    10
#define NT    40
#define XS_LD 328

#define NB_SCAN 49        // ceil(KG_E/1024)

typedef __attribute__((ext_vector_type(8))) short bf16x8;
typedef __attribute__((ext_vector_type(4))) float f32x4;

__device__ __forceinline__ unsigned short f2bf(float x) {
  union { float f; unsigned u; } v; v.f = x;
  unsigned r = v.u + 0x7FFFu + ((v.u >> 16) & 1u);
  return (unsigned short)(r >> 16);
}
__device__ __forceinline__ float bf2f(unsigned short x) {
  union { unsigned u; float f; } v; v.u = ((unsigned)x) << 16; return v.f;
}
__device__ __forceinline__ float plo(unsigned u) {
  union { unsigned u; float f; } v; v.u = u << 16; return v.f;
}
__device__ __forceinline__ float phi(unsigned u) {
  union { unsigned u; float f; } v; v.u = u & 0xFFFF0000u; return v.f;
}
__device__ __forceinline__ unsigned packbf(float lo, float hi) {
  return (unsigned)f2bf(lo) | ((unsigned)f2bf(hi) << 16);
}

// ---------------- f32 -> bf16 table conversion -----------------------------
__global__ __launch_bounds__(256) void k_tobf(
    const float* __restrict__ src, unsigned short* __restrict__ dst, int n4)
{
  int i = blockIdx.x * 256 + threadIdx.x;
  if (i >= n4) return;
  float4 f = ((const float4*)src)[i];
  ushort4 o;
  o.x = f2bf(f.x); o.y = f2bf(f.y); o.z = f2bf(f.z); o.w = f2bf(f.w);
  ((ushort4*)dst)[i] = o;
}

// ---------------- compaction: LDS-staged, one global atomic per block ------
#define NCH 5
#define SCAP 1024
__global__ __launch_bounds__(256) void k_compact2(
    const float* __restrict__ r_head, const float* __restrict__ r_tail,
    const float* __restrict__ be_L, const float* __restrict__ be_R,
    int* __restrict__ lidx, float* __restrict__ lsval,
    int* __restrict__ fill, float* __restrict__ rsum)
{
  __shared__ int   ls_e[SCAP];
  __shared__ float ls_v[SCAP];
  __shared__ int   ls_cnt;
  __shared__ float ls_sum;
  __shared__ int   ls_base;
  int m = blockIdx.z;
  int r = blockIdx.y;
  const float* rowp = (m ? r_tail : r_head) + (size_t)r * KG_E;
  const float* be   = m ? be_R : be_L;
  int slot = m * KG_R + r;
  int lane = threadIdx.x & 63;
  if (threadIdx.x == 0) { ls_cnt = 0; ls_sum = 0.f; }
  __syncthreads();

  const int CH = KG_E / NCH;
  int c0 = blockIdx.x * CH;
  const float4* rp4 = (const float4*)(rowp + c0);
  float lsum = 0.f;
  for (int i = threadIdx.x; i < CH / 4; i += 256) {
    float4 f = rp4[i];
    float vs[4] = {f.x, f.y, f.z, f.w};
    #pragma unroll
    for (int q = 0; q < 4; ++q) {
      float v = vs[q];
      lsum += v;
      bool nz = (v != 0.f);
      unsigned long long mask = __ballot(nz);
      if (mask) {
        int leader = (int)__ffsll(mask) - 1;
        int wbase = 0;
        if (lane == leader) wbase = atomicAdd(&ls_cnt, (int)__popcll(mask));
        wbase = __shfl(wbase, leader, 64);
        if (nz) {
          int pos = wbase + (int)__popcll(mask & ((1ULL << lane) - 1));
          if (pos < SCAP) {
            int e = c0 + 4 * i + q;
            ls_e[pos] = e;
            ls_v[pos] = v * be[e];
          }
        }
      }
    }
  }
  #pragma unroll
  for (int off = 32; off > 0; off >>= 1) lsum += __shfl_xor(lsum, off, 64);
  if (lane == 0 && lsum != 0.f) atomicAdd(&ls_sum, lsum);
  __syncthreads();

  int total = ls_cnt < SCAP ? ls_cnt : SCAP;
  if (threadIdx.x == 0) {
    ls_base = atomicAdd(&fill[slot], total);
    if (ls_sum != 0.f) atomicAdd(&rsum[slot], ls_sum);
  }
  __syncthreads();
  int gbase = ls_base;
  int*   li = lidx  + (size_t)slot * CAP;
  float* lv = lsval + (size_t)slot * CAP;
  for (int i = threadIdx.x; i < total; i += 256) {
    int pos = gbase + i;
    if (pos < CAP) { li[pos] = ls_e[i]; lv[pos] = ls_v[i]; }
  }
}

__global__ __launch_bounds__(256) void k_rmeta(
    const int* __restrict__ fill, const float* __restrict__ rsum,
    int* __restrict__ cnt, float* __restrict__ inv)
{
  int i = blockIdx.x * 256 + threadIdx.x;
  if (i < 2 * KG_R) {
    int c = fill[i];
    cnt[i] = c > CAP ? CAP : c;
    float s = rsum[i];
    inv[i] = (s == 0.f) ? 0.f : 1.f / s;
  }
}

// ---------------- r-layer: pair gathers, packed-bf16 w output --------------
__global__ __launch_bounds__(192) void k_rlayer(
    const unsigned short* __restrict__ Eb, const int* __restrict__ lidx,
    const float* __restrict__ lsval, const int* __restrict__ cnt,
    const float* __restrict__ inv, const float* __restrict__ atten,
    unsigned* __restrict__ wpk)
{
  int b = blockIdx.x;
  int m = b / KG_R, r = b % KG_R;
  int p = threadIdx.x;
  if (p >= NPAIR) return;
  int slot = m * KG_R + r;
  int n = cnt[slot];
  const int*   li = lidx  + (size_t)slot * CAP;
  const float* lv = lsval + (size_t)slot * CAP;
  float alo = 0.f, ahi = 0.f;
  #pragma unroll 4
  for (int i = 0; i < n; ++i) {
    int e = li[i];
    float s = lv[i];
    unsigned u = ((const unsigned*)(Eb + (size_t)e * E_DIM))[p];
    alo += s * plo(u);
    ahi += s * phi(u);
  }
  float iv = inv[slot];
  float vlo = alo * iv; vlo = vlo > 0.f ? vlo : 0.f;
  float vhi = ahi * iv; vhi = vhi > 0.f ? vhi : 0.f;
  vlo *= atten[m * E_DIM + 2 * p];
  vhi *= atten[m * E_DIM + 2 * p + 1];
  wpk[(size_t)slot * NPAIR + p] = packbf(vlo, vhi);
}

// ---------------- CSR build: histogram, 3-phase scan, scatter --------------
__global__ __launch_bounds__(256) void k_hist(
    const int* __restrict__ rows, int* __restrict__ cnt, int n)
{
  int i = blockIdx.x * 256 + threadIdx.x;
  if (i < n) atomicAdd(&cnt[rows[i]], 1);
}

__global__ __launch_bounds__(256) void k_scan_a(
    const int* __restrict__ c0, const int* __restrict__ c1,
    int* __restrict__ bsum, int n)
{
  const int* c = blockIdx.y ? c1 : c0;
  int base = blockIdx.x * 1024;
  int s = 0;
  #pragma unroll
  for (int k = 0; k < 4; ++k) {
    int i = base + k * 256 + threadIdx.x;
    if (i < n) s += c[i];
  }
  #pragma unroll
  for (int off = 32; off > 0; off >>= 1) s += __shfl_xor(s, off, 64);
  __shared__ int ws[4];
  if ((threadIdx.x & 63) == 0) ws[threadIdx.x >> 6] = s;
  __syncthreads();
  if (threadIdx.x == 0)
    bsum[blockIdx.y * (NB_SCAN + 1) + blockIdx.x] = ws[0] + ws[1] + ws[2] + ws[3];
}

__global__ __launch_bounds__(64) void k_scan_b(int* __restrict__ bsum)
{
  if (threadIdx.x < 2) {
    int* b = bsum + threadIdx.x * (NB_SCAN + 1);
    int acc = 0;
    for (int i = 0; i < NB_SCAN; ++i) { int v = b[i]; b[i] = acc; acc += v; }
    b[NB_SCAN] = acc;
  }
}

__global__ __launch_bounds__(256) void k_scan_c(
    const int* __restrict__ c0, const int* __restrict__ c1,
    const int* __restrict__ bsum,
    int* __restrict__ s0, int* __restrict__ s1, int n)
{
  const int* c = blockIdx.y ? c1 : c0;
  int* sO = blockIdx.y ? s1 : s0;
  if (blockIdx.x == 0 && threadIdx.x == 0)
    sO[n] = bsum[blockIdx.y * (NB_SCAN + 1) + NB_SCAN];
  int boff = bsum[blockIdx.y * (NB_SCAN + 1) + blockIdx.x];
  int i0 = blockIdx.x * 1024 + threadIdx.x * 4;
  int4 v = {0, 0, 0, 0};
  if (i0 < n) v = ((const int4*)c)[i0 >> 2];
  int tsum = v.x + v.y + v.z + v.w;
  int lane = threadIdx.x & 63, wid = threadIdx.x >> 6;
  int inc = tsum;
  #pragma unroll
  for (int off = 1; off < 64; off <<= 1) {
    int u = __shfl_up(inc, off, 64);
    if (lane >= off) inc += u;
  }
  __shared__ int ws[4];
  if (lane == 63) ws[wid] = inc;
  __syncthreads();
  int woff = 0;
  if (wid > 0) woff += ws[0];
  if (wid > 1) woff += ws[1];
  if (wid > 2) woff += ws[2];
  int ex = boff + woff + inc - tsum;
  if (i0 < n) {
    int4 o;
    o.x = ex; o.y = ex + v.x; o.z = o.y + v.y; o.w = o.z + v.z;
    ((int4*)sO)[i0 >> 2] = o;
  }
}

__global__ __launch_bounds__(256) void k_scatter_eer(
    const int* __restrict__ eidx, const int* __restrict__ erel,
    const int* __restrict__ start, int* __restrict__ fill,
    int* __restrict__ scol, int* __restrict__ srel, int neer)
{
  int i = blockIdx.x * 256 + threadIdx.x;
  if (i >= neer) return;
  int row = eidx[i];
  int pos = start[row] + atomicAdd(&fill[row], 1);
  scol[pos] = eidx[neer + i];
  srel[pos] = erel[i];
}

__global__ __launch_bounds__(256) void k_scatter_adj(
    const int* __restrict__ aidx, const float* __restrict__ adata,
    const int* __restrict__ start, int* __restrict__ fill,
    int* __restrict__ scol, float* __restrict__ sval, int ne)
{
  int i = blockIdx.x * 256 + threadIdx.x;
  if (i >= ne) return;
  int row = aidx[i];
  int pos = start[row] + atomicAdd(&fill[row], 1);
  scol[pos] = aidx[ne + i];
  sval[pos] = adata[i];
}

// ---------------- attention: half-wave (2 edges/wave), uint2 loads ---------
__global__ __launch_bounds__(256) void k_att_csr(
    const unsigned short* __restrict__ Eb, const unsigned* __restrict__ wpk,
    const int* __restrict__ start, const int* __restrict__ scol,
    const int* __restrict__ srel, const unsigned short* __restrict__ baseb,
    float alpha, unsigned short* __restrict__ outb)
{
  int wave = threadIdx.x >> 6, lane = threadIdx.x & 63;
  int half = lane >> 5, hl = lane & 31;
  int row = blockIdx.x * 4 + wave;
  if (row >= KG_E) return;
  int s = start[row], e = start[row + 1];
  // er: uint2 m = c*32+hl covers dims 4m..4m+3 (m < NP2)
  const uint2* erp = (const uint2*)(Eb + (size_t)row * E_DIM);
  float er0[3], er1[3], er2[3], er3[3];
  float ac0[3] = {0,0,0}, ac1[3] = {0,0,0}, ac2[3] = {0,0,0}, ac3[3] = {0,0,0};
  #pragma unroll
  for (int c = 0; c < 3; ++c) {
    int m = c * 32 + hl;
    if (m < NP2) {
      uint2 u = erp[m];
      er0[c] = plo(u.x); er1[c] = phi(u.x); er2[c] = plo(u.y); er3[c] = phi(u.y);
    } else { er0[c] = er1[c] = er2[c] = er3[c] = 0.f; }
  }
  float rs = 0.f;
  int nIter = (e - s + 1) >> 1;
  for (int it = 0; it < nIter; ++it) {
    int j = s + 2 * it + half;
    bool act = j < e;
    int col = act ? scol[j] : 0;
    int rel = act ? srel[j] : 0;
    const uint2* ecp = (const uint2*)(Eb + (size_t)col * E_DIM);
    const uint2* whp = (const uint2*)(wpk + (size_t)rel * NPAIR);
    const uint2* wtp = (const uint2*)(wpk + (size_t)(KG_R + rel) * NPAIR);
    float e0[3], e1[3], e2[3], e3[3];
    float p4 = 0.f;
    #pragma unroll
    for (int c = 0; c < 3; ++c) {
      int m = c * 32 + hl;
      if (m < NP2) {
        uint2 uc = ecp[m], uh = whp[m], ut = wtp[m];
        float c0 = plo(uc.x), c1 = phi(uc.x), c2 = plo(uc.y), c3 = phi(uc.y);
        e0[c] = c0; e1[c] = c1; e2[c] = c2; e3[c] = c3;
        p4 += er0[c] * plo(uh.x) + er1[c] * phi(uh.x)
            + er2[c] * plo(uh.y) + er3[c] * phi(uh.y)
            + c0 * plo(ut.x) + c1 * phi(ut.x)
            + c2 * plo(ut.y) + c3 * phi(ut.y);
      } else { e0[c] = e1[c] = e2[c] = e3[c] = 0.f; }
    }
    #pragma unroll
    for (int off = 16; off > 0; off >>= 1) p4 += __shfl_xor(p4, off, 64);
    float la = p4 >= 0.f ? p4 : LRELU * p4;
    float at = act ? __expf(-la) : 0.f;
    rs += at;
    #pragma unroll
    for (int c = 0; c < 3; ++c) {
      ac0[c] += at * e0[c]; ac1[c] += at * e1[c];
      ac2[c] += at * e2[c]; ac3[c] += at * e3[c];
    }
  }
  // merge the two halves
  rs += __shfl_xor(rs, 32, 64);
  #pragma unroll
  for (int c = 0; c < 3; ++c) {
    ac0[c] += __shfl_xor(ac0[c], 32, 64);
    ac1[c] += __shfl_xor(ac1[c], 32, 64);
    ac2[c] += __shfl_xor(ac2[c], 32, 64);
    ac3[c] += __shfl_xor(ac3[c], 32, 64);
  }
  if (half == 0) {
    float iv = (rs == 0.f) ? 0.f : 1.f / rs;
    const uint2* bp = (const uint2*)(baseb + (size_t)row * E_DIM);
    uint2* op = (uint2*)(outb + (size_t)row * E_DIM);
    #pragma unroll
    for (int c = 0; c < 3; ++c) {
      int m = c * 32 + hl;
      if (m < NP2) {
        uint2 ub = bp[m];
        float v0 = ac0[c] * iv; v0 = v0 > 0.f ? v0 : 0.f;
        float v1 = ac1[c] * iv; v1 = v1 > 0.f ? v1 : 0.f;
        float v2 = ac2[c] * iv; v2 = v2 > 0.f ? v2 : 0.f;
        float v3 = ac3[c] * iv; v3 = v3 > 0.f ? v3 : 0.f;
        uint2 o2;
        o2.x = packbf(plo(ub.x) + alpha * v0, phi(ub.x) + alpha * v1);
        o2.y = packbf(plo(ub.y) + alpha * v2, phi(ub.y) + alpha * v3);
        op[m] = o2;
      }
    }
  }
}

// ---------------- fused spmm + highway: half-wave, uint2 loads -------------
__global__ __launch_bounds__(256) void k_spmm_hw(
    const unsigned short* __restrict__ Xb, const int* __restrict__ start,
    const int* __restrict__ scol, const float* __restrict__ sval,
    const unsigned short* __restrict__ Gb, const unsigned short* __restrict__ baseb,
    const float* __restrict__ br,
    unsigned short* __restrict__ outb, float* __restrict__ outf)
{
  int wave = threadIdx.x >> 6, lane = threadIdx.x & 63;
  int half = lane >> 5, hl = lane & 31;
  int row = blockIdx.x * 4 + wave;
  if (row >= KG_E) return;
  int s = start[row], e = start[row + 1];
  float ac0[3] = {0,0,0}, ac1[3] = {0,0,0}, ac2[3] = {0,0,0}, ac3[3] = {0,0,0};
  int nIter = (e - s + 1) >> 1;
  for (int it = 0; it < nIter; ++it) {
    int j = s + 2 * it + half;
    bool act = j < e;
    int col = act ? scol[j] : 0;
    float v = act ? sval[j] : 0.f;
    const uint2* xp = (const uint2*)(Xb + (size_t)col * E_DIM);
    #pragma unroll
    for (int c = 0; c < 3; ++c) {
      int m = c * 32 + hl;
      if (m < NP2) {
        uint2 u = xp[m];
        ac0[c] += v * plo(u.x); ac1[c] += v * phi(u.x);
        ac2[c] += v * plo(u.y); ac3[c] += v * phi(u.y);
      }
    }
  }
  #pragma unroll
  for (int c = 0; c < 3; ++c) {
    ac0[c] += __shfl_xor(ac0[c], 32, 64);
    ac1[c] += __shfl_xor(ac1[c], 32, 64);
    ac2[c] += __shfl_xor(ac2[c], 32, 64);
    ac3[c] += __shfl_xor(ac3[c], 32, 64);
  }
  if (half == 0) {
    const uint2* gp = (const uint2*)(Gb + (size_t)row * E_DIM);
    const uint2* bp = (const uint2*)(baseb + (size_t)row * E_DIM);
    #pragma unroll
    for (int c = 0; c < 3; ++c) {
      int m = c * 32 + hl;
      if (m < NP2) {
        uint2 ug = gp[m], ub = bp[m];
        float4 b4 = ((const float4*)br)[m];
        float g0 = 1.f / (1.f + __expf(-(plo(ug.x) + b4.x)));
        float g1 = 1.f / (1.f + __expf(-(phi(ug.x) + b4.y)));
        float g2 = 1.f / (1.f + __expf(-(plo(ug.y) + b4.z)));
        float g3 = 1.f / (1.f + __expf(-(phi(ug.y) + b4.w)));
        float y0 = ac0[c] > 0.f ? ac0[c] : 0.f;
        float y1 = ac1[c] > 0.f ? ac1[c] : 0.f;
        float y2 = ac2[c] > 0.f ? ac2[c] : 0.f;
        float y3 = ac3[c] > 0.f ? ac3[c] : 0.f;
        float o0 = g0 * y0 + (1.f - g0) * plo(ub.x);
        float o1 = g1 * y1 + (1.f - g1) * phi(ub.x);
        float o2 = g2 * y2 + (1.f - g2) * plo(ub.y);
        float o3 = g3 * y3 + (1.f - g3) * phi(ub.y);
        if (outb) {
          uint2 ov;
          ov.x = packbf(o0, o1); ov.y = packbf(o2, o3);
          ((uint2*)(outb + (size_t)row * E_DIM))[m] = ov;
        } else {
          float4 of; of.x = o0; of.y = o1; of.z = o2; of.w = o3;
          ((float4*)(outf + (size_t)row * E_DIM))[m] = of;
        }
      }
    }
  }
}

// ---------------- pack W into MFMA B-fragment layout -----------------------
__global__ __launch_bounds__(64) void k_packW(
    const float* __restrict__ W1, const float* __restrict__ W2,
    unsigned short* __restrict__ Wp)
{
  int lane = threadIdx.x;
  int t = blockIdx.x, s = blockIdx.y;
  int c = t * 16 + (lane & 15);
  unsigned short v[8];
  #pragma unroll
  for (int j = 0; j < 8; ++j) {
    int k = s * 32 + (lane >> 4) * 8 + j;
    float x = 0.f;
    if (k < E_DIM && c < 2 * E_DIM)
      x = (c < E_DIM) ? W1[(size_t)k * E_DIM + c]
                      : W2[(size_t)k * E_DIM + (c - E_DIM)];
    v[j] = f2bf(x);
  }
  size_t base = ((size_t)(t * NK + s) * 64 + lane) * 8;
  #pragma unroll
  for (int j = 0; j < 8; ++j) Wp[base + j] = v[j];
}

// ---------------- fused dual-GEMM: Y1,Y2 (bf16) = X @ {gcnW1, hwWr} --------
__global__ __launch_bounds__(256) void k_gemm2_mfma(
    const unsigned short* __restrict__ Xb, const unsigned short* __restrict__ Wp,
    unsigned short* __restrict__ Y1, unsigned short* __restrict__ Y2, int M)
{
  __shared__ unsigned short Xs[32][XS_LD];
  int tid = threadIdx.x;
  int r0 = blockIdx.x * 32;
  int nb = blockIdx.y;

  for (int t = tid; t < 32 * (XS_LD / 2); t += 256) {
    int r = t / (XS_LD / 2), u = t % (XS_LD / 2);
    unsigned v = 0;
    int rg = r0 + r;
    if (rg < M && u < E_DIM / 2) v = ((const unsigned*)Xb)[(size_t)rg * (E_DIM / 2) + u];
    ((unsigned*)&Xs[0][0])[r * (XS_LD / 2) + u] = v;
  }
  __syncthreads();

  int wid = tid >> 6, lane = tid & 63;
  int wave_m = wid >> 1, wave_n = wid & 1;
  int rowA = wave_m * 16 + (lane & 15);
  int kgrp = (lane >> 4) * 8;
  int tb0 = nb * 8 + wave_n * 4;

  const bf16x8* wfrag = (const bf16x8*)Wp + (size_t)tb0 * (NK * 64) + lane;

  f32x4 acc[4] = {{0,0,0,0},{0,0,0,0},{0,0,0,0},{0,0,0,0}};
  #pragma unroll 2
  for (int ks = 0; ks < NK; ++ks) {
    bf16x8 a = *(const bf16x8*)&Xs[rowA][ks * 32 + kgrp];
    #pragma unroll
    for (int nt = 0; nt < 4; ++nt) {
      bf16x8 b = wfrag[(nt * NK + ks) * 64];
      acc[nt] = __builtin_amdgcn_mfma_f32_16x16x32_bf16(a, b, acc[nt], 0, 0, 0);
    }
  }

  int rbase = r0 + wave_m * 16 + ((lane >> 4) << 2);
  #pragma unroll
  for (int nt = 0; nt < 4; ++nt) {
    int c = (tb0 + nt) * 16 + (lane & 15);
    #pragma unroll
    for (int j = 0; j < 4; ++j) {
      int row = rbase + j;
      if (row < M) {
        unsigned short hv = f2bf(acc[nt][j]);
        if (c < E_DIM)            Y1[(size_t)row * E_DIM + c] = hv;
        else if (c < 2 * E_DIM)   Y2[(size_t)row * E_DIM + (c - E_DIM)] = hv;
      }
    }
  }
}

extern "C" void kernel_launch(void* const* d_in, const int* in_sizes, int n_in,
                              void* d_out, int out_size, void* d_ws, size_t ws_size,
                              hipStream_t stream)
{
  const float* primal      = (const float*)d_in[0];
  const float* r_head      = (const float*)d_in[1];
  const float* r_tail      = (const float*)d_in[2];
  const float* e_adj_data  = (const float*)d_in[3];
  const float* be_L        = (const float*)d_in[4];
  const float* be_R        = (const float*)d_in[5];
  const float* atten_r     = (const float*)d_in[6];
  const float* gcnW1       = (const float*)d_in[7];
  const float* hwWr        = (const float*)d_in[8];
  const float* hwbr        = (const float*)d_in[9];
  const int*   e_adj_index = (const int*)d_in[10];
  const int*   eer_idx     = (const int*)d_in[11];
  const int*   eer_rel     = (const int*)d_in[12];
  int ne   = in_sizes[10] / 2;
  int neer = in_sizes[11] / 2;

  char* ws = (char*)d_ws;
  size_t off = 0;
  auto take = [&](size_t bytes) {
    void* p = ws + off;
    off = (off + bytes + 255) & ~(size_t)255;
    return p;
  };
  int*   cnt      = (int*)  take((size_t)2 * KG_R * sizeof(int));
  float* inv      = (float*)take((size_t)2 * KG_R * sizeof(float));
  // ---- contiguous zero-init block (single memset) ----
  size_t z0 = off;
  int*   hcntA    = (int*)  take((size_t)KG_E * sizeof(int));
  int*   hcntB    = (int*)  take((size_t)KG_E * sizeof(int));
  int*   hfillA   = (int*)  take((size_t)KG_E * sizeof(int));
  int*   hfillB   = (int*)  take((size_t)KG_E * sizeof(int));
  int*   rfill    = (int*)  take((size_t)2 * KG_R * sizeof(int));
  float* rsumb    = (float*)take((size_t)2 * KG_R * sizeof(float));
  size_t z1 = off;
  // ----------------------------------------------------
  int*   lidx     = (int*)  take((size_t)2 * KG_R * CAP * sizeof(int));
  float* lsv      = (float*)take((size_t)2 * KG_R * CAP * sizeof(float));
  unsigned* wpk   = (unsigned*)take((size_t)2 * KG_R * NPAIR * sizeof(unsigned));
  int*   bsum     = (int*)  take((size_t)2 * (NB_SCAN + 1) * sizeof(int));
  int*   eer_start= (int*)  take((size_t)(KG_E + 4) * sizeof(int));
  int*   adj_start= (int*)  take((size_t)(KG_E + 4) * sizeof(int));
  int*   eer_scol = (int*)  take((size_t)neer * sizeof(int));
  int*   eer_srel = (int*)  take((size_t)neer * sizeof(int));
  int*   adj_scol = (int*)  take((size_t)ne * sizeof(int));
  float* adj_sval = (float*)take((size_t)ne * sizeof(float));
  unsigned short* Wp = (unsigned short*)take((size_t)NT * NK * 64 * 8 * sizeof(unsigned short));
  unsigned short* B0 = (unsigned short*)take((size_t)KG_E * E_DIM * sizeof(unsigned short)); // primal bf16
  unsigned short* B1 = (unsigned short*)take((size_t)KG_E * E_DIM * sizeof(unsigned short)); // e1 / g2
  unsigned short* B2 = (unsigned short*)take((size_t)KG_E * E_DIM * sizeof(unsigned short)); // e2
  unsigned short* Fb = (unsigned short*)take((size_t)KG_E * E_DIM * sizeof(unsigned short)); // X@gcnW1
  unsigned short* Gb = (unsigned short*)take((size_t)KG_E * E_DIM * sizeof(unsigned short)); // X@hwWr
  float* out      = (float*)d_out;
  (void)ws_size; (void)n_in; (void)out_size;

  int eg = (neer + 255) / 256;
  int ag = (ne + 255) / 256;

  // ---- single memset for all zero-init scratch ----
  hipMemsetAsync(ws + z0, 0, z1 - z0, stream);

  // ---- CSR builds (both graphs; shared 3-phase scan) ----
  k_hist<<<eg, 256, 0, stream>>>(eer_idx, hcntA, neer);
  k_hist<<<ag, 256, 0, stream>>>(e_adj_index, hcntB, ne);
  k_scan_a<<<dim3(NB_SCAN, 2), 256, 0, stream>>>(hcntA, hcntB, bsum, KG_E);
  k_scan_b<<<1, 64, 0, stream>>>(bsum);
  k_scan_c<<<dim3(NB_SCAN, 2), 256, 0, stream>>>(hcntA, hcntB, bsum,
                                                 eer_start, adj_start, KG_E);
  k_scatter_eer<<<eg, 256, 0, stream>>>(eer_idx, eer_rel, eer_start, hfillA,
                                        eer_scol, eer_srel, neer);
  k_scatter_adj<<<ag, 256, 0, stream>>>(e_adj_index, e_adj_data, adj_start, hfillB,
                                        adj_scol, adj_sval, ne);

  // ---- compact r_head/r_tail + pack weights + primal bf16 ----
  k_compact2<<<dim3(NCH, KG_R, 2), 256, 0, stream>>>(r_head, r_tail, be_L, be_R,
                                                     lidx, lsv, rfill, rsumb);
  k_rmeta<<<(2 * KG_R + 255) / 256, 256, 0, stream>>>(rfill, rsumb, cnt, inv);
  k_packW<<<dim3(NT, NK), 64, 0, stream>>>(gcnW1, hwWr, Wp);
  int n4 = KG_E * E_DIM / 4;
  k_tobf<<<(n4 + 255) / 256, 256, 0, stream>>>(primal, B0, n4);

  int rg = (KG_E + 3) / 4;

  // ---- attention layer 1: e1 = primal + 0.1*att(primal) -> B1 ----
  k_rlayer<<<2 * KG_R, 192, 0, stream>>>(B0, lidx, lsv, cnt, inv, atten_r, wpk);
  k_att_csr<<<rg, 256, 0, stream>>>(B0, wpk, eer_start, eer_scol, eer_srel,
                                    B0, 0.1f, B1);
  // ---- attention layer 2: e2 = primal + 0.3*att(e1) -> B2 ----
  k_rlayer<<<2 * KG_R, 192, 0, stream>>>(B1, lidx, lsv, cnt, inv, atten_r, wpk);
  k_att_csr<<<rg, 256, 0, stream>>>(B1, wpk, eer_start, eer_scol, eer_srel,
                                    B0, 0.3f, B2);

  // ---- GCN + highway 1: Fb,Gb = e2 @ {gcnW1,hwWr}; g2 -> B1 ----
  dim3 gg((KG_E + 31) / 32, 5);
  k_gemm2_mfma<<<gg, 256, 0, stream>>>(B2, Wp, Fb, Gb, KG_E);
  k_spmm_hw<<<rg, 256, 0, stream>>>(Fb, adj_start, adj_scol, adj_sval,
                                    Gb, B2, hwbr, B1, (float*)nullptr);

  // ---- GCN + highway 2: Fb,Gb = g2 @ {gcnW1,hwWr}; out = highway ----
  k_gemm2_mfma<<<gg, 256, 0, stream>>>(B1, Wp, Fb, Gb, KG_E);
  k_spmm_hw<<<rg, 256, 0, stream>>>(Fb, adj_start, adj_scol, adj_sval,
                                    Gb, B1, hwbr, (unsigned short*)nullptr, out);
}

// Round 10
// 803.043 us; speedup vs baseline: 1.7787x; 1.0347x over previous
//
#include <hip/hip_runtime.h>
#include <hip/hip_fp16.h>
#include <math.h>

#define KG_E  50000
#define KG_R  500
#define E_DIM 300
#define NPAIR 150         // E_DIM/2 fp16 pairs per row
#define NP2   75          // E_DIM/4 uint2 per row
#define CAP   1024
#define LRELU 0.2f

// MFMA GEMM geometry: Y[M,600(pad 640)] = X[M,300(pad 320)] @ Wcat
#define NK    10
#define NT    40
#define XS_LD 328

#define NB_SCAN 49        // ceil(KG_E/1024)

typedef __attribute__((ext_vector_type(8))) _Float16 f16x8;
typedef __attribute__((ext_vector_type(4))) float f32x4;

__device__ __forceinline__ __half2 u2h2(unsigned u) {
  union { unsigned u; __half2 h; } v; v.u = u; return v.h;
}
__device__ __forceinline__ unsigned h22u(__half2 h) {
  union { unsigned u; __half2 h; } v; v.h = h; return v.u;
}
__device__ __forceinline__ float hlo(unsigned u) { return __low2float(u2h2(u)); }
__device__ __forceinline__ float hhi(unsigned u) { return __high2float(u2h2(u)); }
__device__ __forceinline__ unsigned packh(float lo, float hi) {
  return h22u(__floats2half2_rn(lo, hi));
}

// ---------------- f32 -> fp16 table conversion -----------------------------
__global__ __launch_bounds__(256) void k_toh(
    const float* __restrict__ src, __half* __restrict__ dst, int n4)
{
  int i = blockIdx.x * 256 + threadIdx.x;
  if (i >= n4) return;
  float4 f = ((const float4*)src)[i];
  uint2 o;
  o.x = packh(f.x, f.y);
  o.y = packh(f.z, f.w);
  ((uint2*)dst)[i] = o;
}

// ---------------- compaction: LDS-staged, one global atomic per block ------
#define NCH 5
#define SCAP 1024
__global__ __launch_bounds__(256) void k_compact2(
    const float* __restrict__ r_head, const float* __restrict__ r_tail,
    const float* __restrict__ be_L, const float* __restrict__ be_R,
    int* __restrict__ lidx, float* __restrict__ lsval,
    int* __restrict__ fill, float* __restrict__ rsum)
{
  __shared__ int   ls_e[SCAP];
  __shared__ float ls_v[SCAP];
  __shared__ int   ls_cnt;
  __shared__ float ls_sum;
  __shared__ int   ls_base;
  int m = blockIdx.z;
  int r = blockIdx.y;
  const float* rowp = (m ? r_tail : r_head) + (size_t)r * KG_E;
  const float* be   = m ? be_R : be_L;
  int slot = m * KG_R + r;
  int lane = threadIdx.x & 63;
  if (threadIdx.x == 0) { ls_cnt = 0; ls_sum = 0.f; }
  __syncthreads();

  const int CH = KG_E / NCH;
  int c0 = blockIdx.x * CH;
  const float4* rp4 = (const float4*)(rowp + c0);
  float lsum = 0.f;
  for (int i = threadIdx.x; i < CH / 4; i += 256) {
    float4 f = rp4[i];
    float vs[4] = {f.x, f.y, f.z, f.w};
    #pragma unroll
    for (int q = 0; q < 4; ++q) {
      float v = vs[q];
      lsum += v;
      bool nz = (v != 0.f);
      unsigned long long mask = __ballot(nz);
      if (mask) {
        int leader = (int)__ffsll(mask) - 1;
        int wbase = 0;
        if (lane == leader) wbase = atomicAdd(&ls_cnt, (int)__popcll(mask));
        wbase = __shfl(wbase, leader, 64);
        if (nz) {
          int pos = wbase + (int)__popcll(mask & ((1ULL << lane) - 1));
          if (pos < SCAP) {
            int e = c0 + 4 * i + q;
            ls_e[pos] = e;
            ls_v[pos] = v * be[e];
          }
        }
      }
    }
  }
  #pragma unroll
  for (int off = 32; off > 0; off >>= 1) lsum += __shfl_xor(lsum, off, 64);
  if (lane == 0 && lsum != 0.f) atomicAdd(&ls_sum, lsum);
  __syncthreads();

  int total = ls_cnt < SCAP ? ls_cnt : SCAP;
  if (threadIdx.x == 0) {
    ls_base = atomicAdd(&fill[slot], total);
    if (ls_sum != 0.f) atomicAdd(&rsum[slot], ls_sum);
  }
  __syncthreads();
  int gbase = ls_base;
  int*   li = lidx  + (size_t)slot * CAP;
  float* lv = lsval + (size_t)slot * CAP;
  for (int i = threadIdx.x; i < total; i += 256) {
    int pos = gbase + i;
    if (pos < CAP) { li[pos] = ls_e[i]; lv[pos] = ls_v[i]; }
  }
}

__global__ __launch_bounds__(256) void k_rmeta(
    const int* __restrict__ fill, const float* __restrict__ rsum,
    int* __restrict__ cnt, float* __restrict__ inv)
{
  int i = blockIdx.x * 256 + threadIdx.x;
  if (i < 2 * KG_R) {
    int c = fill[i];
    cnt[i] = c > CAP ? CAP : c;
    float s = rsum[i];
    inv[i] = (s == 0.f) ? 0.f : 1.f / s;
  }
}

// ---------------- r-layer: fp16 pair gathers, f32 accum, packed-h2 out -----
__global__ __launch_bounds__(192) void k_rlayer(
    const __half* __restrict__ Eb, const int* __restrict__ lidx,
    const float* __restrict__ lsval, const int* __restrict__ cnt,
    const float* __restrict__ inv, const float* __restrict__ atten,
    unsigned* __restrict__ wpk)
{
  int b = blockIdx.x;
  int m = b / KG_R, r = b % KG_R;
  int p = threadIdx.x;
  if (p >= NPAIR) return;
  int slot = m * KG_R + r;
  int n = cnt[slot];
  const int*   li = lidx  + (size_t)slot * CAP;
  const float* lv = lsval + (size_t)slot * CAP;
  float alo = 0.f, ahi = 0.f;
  #pragma unroll 4
  for (int i = 0; i < n; ++i) {
    int e = li[i];
    float s = lv[i];
    unsigned u = ((const unsigned*)(Eb + (size_t)e * E_DIM))[p];
    alo += s * hlo(u);
    ahi += s * hhi(u);
  }
  float iv = inv[slot];
  float vlo = alo * iv; vlo = vlo > 0.f ? vlo : 0.f;
  float vhi = ahi * iv; vhi = vhi > 0.f ? vhi : 0.f;
  vlo *= atten[m * E_DIM + 2 * p];
  vhi *= atten[m * E_DIM + 2 * p + 1];
  wpk[(size_t)slot * NPAIR + p] = packh(vlo, vhi);
}

// ---------------- CSR build: histogram, 3-phase scan, scatter --------------
__global__ __launch_bounds__(256) void k_hist(
    const int* __restrict__ rows, int* __restrict__ cnt, int n)
{
  int i = blockIdx.x * 256 + threadIdx.x;
  if (i < n) atomicAdd(&cnt[rows[i]], 1);
}

__global__ __launch_bounds__(256) void k_scan_a(
    const int* __restrict__ c0, const int* __restrict__ c1,
    int* __restrict__ bsum, int n)
{
  const int* c = blockIdx.y ? c1 : c0;
  int base = blockIdx.x * 1024;
  int s = 0;
  #pragma unroll
  for (int k = 0; k < 4; ++k) {
    int i = base + k * 256 + threadIdx.x;
    if (i < n) s += c[i];
  }
  #pragma unroll
  for (int off = 32; off > 0; off >>= 1) s += __shfl_xor(s, off, 64);
  __shared__ int ws[4];
  if ((threadIdx.x & 63) == 0) ws[threadIdx.x >> 6] = s;
  __syncthreads();
  if (threadIdx.x == 0)
    bsum[blockIdx.y * (NB_SCAN + 1) + blockIdx.x] = ws[0] + ws[1] + ws[2] + ws[3];
}

__global__ __launch_bounds__(64) void k_scan_b(int* __restrict__ bsum)
{
  if (threadIdx.x < 2) {
    int* b = bsum + threadIdx.x * (NB_SCAN + 1);
    int acc = 0;
    for (int i = 0; i < NB_SCAN; ++i) { int v = b[i]; b[i] = acc; acc += v; }
    b[NB_SCAN] = acc;
  }
}

__global__ __launch_bounds__(256) void k_scan_c(
    const int* __restrict__ c0, const int* __restrict__ c1,
    const int* __restrict__ bsum,
    int* __restrict__ s0, int* __restrict__ s1, int n)
{
  const int* c = blockIdx.y ? c1 : c0;
  int* sO = blockIdx.y ? s1 : s0;
  if (blockIdx.x == 0 && threadIdx.x == 0)
    sO[n] = bsum[blockIdx.y * (NB_SCAN + 1) + NB_SCAN];
  int boff = bsum[blockIdx.y * (NB_SCAN + 1) + blockIdx.x];
  int i0 = blockIdx.x * 1024 + threadIdx.x * 4;
  int4 v = {0, 0, 0, 0};
  if (i0 < n) v = ((const int4*)c)[i0 >> 2];
  int tsum = v.x + v.y + v.z + v.w;
  int lane = threadIdx.x & 63, wid = threadIdx.x >> 6;
  int inc = tsum;
  #pragma unroll
  for (int off = 1; off < 64; off <<= 1) {
    int u = __shfl_up(inc, off, 64);
    if (lane >= off) inc += u;
  }
  __shared__ int ws[4];
  if (lane == 63) ws[wid] = inc;
  __syncthreads();
  int woff = 0;
  if (wid > 0) woff += ws[0];
  if (wid > 1) woff += ws[1];
  if (wid > 2) woff += ws[2];
  int ex = boff + woff + inc - tsum;
  if (i0 < n) {
    int4 o;
    o.x = ex; o.y = ex + v.x; o.z = o.y + v.y; o.w = o.z + v.z;
    ((int4*)sO)[i0 >> 2] = o;
  }
}

__global__ __launch_bounds__(256) void k_scatter_eer(
    const int* __restrict__ eidx, const int* __restrict__ erel,
    const int* __restrict__ start, int* __restrict__ fill,
    int* __restrict__ scol, int* __restrict__ srel, int neer)
{
  int i = blockIdx.x * 256 + threadIdx.x;
  if (i >= neer) return;
  int row = eidx[i];
  int pos = start[row] + atomicAdd(&fill[row], 1);
  scol[pos] = eidx[neer + i];
  srel[pos] = erel[i];
}

__global__ __launch_bounds__(256) void k_scatter_adj(
    const int* __restrict__ aidx, const float* __restrict__ adata,
    const int* __restrict__ start, int* __restrict__ fill,
    int* __restrict__ scol, float* __restrict__ sval, int ne)
{
  int i = blockIdx.x * 256 + threadIdx.x;
  if (i >= ne) return;
  int row = aidx[i];
  int pos = start[row] + atomicAdd(&fill[row], 1);
  scol[pos] = aidx[ne + i];
  sval[pos] = adata[i];
}

// ---------------- attention: half-wave, packed-half2 math ------------------
__global__ __launch_bounds__(256) void k_att_csr(
    const __half* __restrict__ Eb, const unsigned* __restrict__ wpk,
    const int* __restrict__ start, const int* __restrict__ scol,
    const int* __restrict__ srel, const __half* __restrict__ baseb,
    float alpha, __half* __restrict__ outb)
{
  int wave = threadIdx.x >> 6, lane = threadIdx.x & 63;
  int half = lane >> 5, hl = lane & 31;
  int row = blockIdx.x * 4 + wave;
  if (row >= KG_E) return;
  int s = start[row], e = start[row + 1];
  const uint2* erp = (const uint2*)(Eb + (size_t)row * E_DIM);
  __half2 zero2 = __floats2half2_rn(0.f, 0.f);
  __half2 er[3][2], ac[3][2];
  #pragma unroll
  for (int c = 0; c < 3; ++c) {
    int m = c * 32 + hl;
    if (m < NP2) {
      uint2 u = erp[m];
      er[c][0] = u2h2(u.x); er[c][1] = u2h2(u.y);
    } else { er[c][0] = zero2; er[c][1] = zero2; }
    ac[c][0] = zero2; ac[c][1] = zero2;
  }
  float rs = 0.f;
  int nIter = (e - s + 1) >> 1;
  for (int it = 0; it < nIter; ++it) {
    int j = s + 2 * it + half;
    bool act = j < e;
    int col = act ? scol[j] : 0;
    int rel = act ? srel[j] : 0;
    const uint2* ecp = (const uint2*)(Eb + (size_t)col * E_DIM);
    const uint2* whp = (const uint2*)(wpk + (size_t)rel * NPAIR);
    const uint2* wtp = (const uint2*)(wpk + (size_t)(KG_R + rel) * NPAIR);
    __half2 ec[3][2];
    __half2 p2 = zero2;
    #pragma unroll
    for (int c = 0; c < 3; ++c) {
      int m = c * 32 + hl;
      if (m < NP2) {
        uint2 uc = ecp[m], uh = whp[m], ut = wtp[m];
        ec[c][0] = u2h2(uc.x); ec[c][1] = u2h2(uc.y);
        p2 = __hfma2(er[c][0], u2h2(uh.x), p2);
        p2 = __hfma2(er[c][1], u2h2(uh.y), p2);
        p2 = __hfma2(ec[c][0], u2h2(ut.x), p2);
        p2 = __hfma2(ec[c][1], u2h2(ut.y), p2);
      } else { ec[c][0] = zero2; ec[c][1] = zero2; }
    }
    float p4 = __low2float(p2) + __high2float(p2);
    #pragma unroll
    for (int off = 16; off > 0; off >>= 1) p4 += __shfl_xor(p4, off, 64);
    float la = p4 >= 0.f ? p4 : LRELU * p4;
    float at = act ? __expf(-la) : 0.f;
    rs += at;
    __half2 at2 = __float2half2_rn(at);
    #pragma unroll
    for (int c = 0; c < 3; ++c) {
      ac[c][0] = __hfma2(at2, ec[c][0], ac[c][0]);
      ac[c][1] = __hfma2(at2, ec[c][1], ac[c][1]);
    }
  }
  // merge halves
  rs += __shfl_xor(rs, 32, 64);
  #pragma unroll
  for (int c = 0; c < 3; ++c) {
    #pragma unroll
    for (int k = 0; k < 2; ++k) {
      unsigned o = __shfl_xor(h22u(ac[c][k]), 32, 64);
      ac[c][k] = __hadd2(ac[c][k], u2h2(o));
    }
  }
  if (half == 0) {
    float iv = (rs == 0.f) ? 0.f : 1.f / rs;
    const uint2* bp = (const uint2*)(baseb + (size_t)row * E_DIM);
    uint2* op = (uint2*)(outb + (size_t)row * E_DIM);
    #pragma unroll
    for (int c = 0; c < 3; ++c) {
      int m = c * 32 + hl;
      if (m < NP2) {
        uint2 ub = bp[m];
        float v0 = __low2float(ac[c][0]) * iv;  v0 = v0 > 0.f ? v0 : 0.f;
        float v1 = __high2float(ac[c][0]) * iv; v1 = v1 > 0.f ? v1 : 0.f;
        float v2 = __low2float(ac[c][1]) * iv;  v2 = v2 > 0.f ? v2 : 0.f;
        float v3 = __high2float(ac[c][1]) * iv; v3 = v3 > 0.f ? v3 : 0.f;
        uint2 o2;
        o2.x = packh(hlo(ub.x) + alpha * v0, hhi(ub.x) + alpha * v1);
        o2.y = packh(hlo(ub.y) + alpha * v2, hhi(ub.y) + alpha * v3);
        op[m] = o2;
      }
    }
  }
}

// ---------------- fused spmm + highway: half-wave, f32 accum ---------------
__global__ __launch_bounds__(256) void k_spmm_hw(
    const __half* __restrict__ Xb, const int* __restrict__ start,
    const int* __restrict__ scol, const float* __restrict__ sval,
    const __half* __restrict__ Gb, const __half* __restrict__ baseb,
    const float* __restrict__ br,
    __half* __restrict__ outb, float* __restrict__ outf)
{
  int wave = threadIdx.x >> 6, lane = threadIdx.x & 63;
  int half = lane >> 5, hl = lane & 31;
  int row = blockIdx.x * 4 + wave;
  if (row >= KG_E) return;
  int s = start[row], e = start[row + 1];
  float ac0[3] = {0,0,0}, ac1[3] = {0,0,0}, ac2[3] = {0,0,0}, ac3[3] = {0,0,0};
  int nIter = (e - s + 1) >> 1;
  for (int it = 0; it < nIter; ++it) {
    int j = s + 2 * it + half;
    bool act = j < e;
    int col = act ? scol[j] : 0;
    float v = act ? sval[j] : 0.f;
    const uint2* xp = (const uint2*)(Xb + (size_t)col * E_DIM);
    #pragma unroll
    for (int c = 0; c < 3; ++c) {
      int m = c * 32 + hl;
      if (m < NP2) {
        uint2 u = xp[m];
        ac0[c] += v * hlo(u.x); ac1[c] += v * hhi(u.x);
        ac2[c] += v * hlo(u.y); ac3[c] += v * hhi(u.y);
      }
    }
  }
  #pragma unroll
  for (int c = 0; c < 3; ++c) {
    ac0[c] += __shfl_xor(ac0[c], 32, 64);
    ac1[c] += __shfl_xor(ac1[c], 32, 64);
    ac2[c] += __shfl_xor(ac2[c], 32, 64);
    ac3[c] += __shfl_xor(ac3[c], 32, 64);
  }
  if (half == 0) {
    const uint2* gp = (const uint2*)(Gb + (size_t)row * E_DIM);
    const uint2* bp = (const uint2*)(baseb + (size_t)row * E_DIM);
    #pragma unroll
    for (int c = 0; c < 3; ++c) {
      int m = c * 32 + hl;
      if (m < NP2) {
        uint2 ug = gp[m], ub = bp[m];
        float4 b4 = ((const float4*)br)[m];
        float g0 = 1.f / (1.f + __expf(-(hlo(ug.x) + b4.x)));
        float g1 = 1.f / (1.f + __expf(-(hhi(ug.x) + b4.y)));
        float g2 = 1.f / (1.f + __expf(-(hlo(ug.y) + b4.z)));
        float g3 = 1.f / (1.f + __expf(-(hhi(ug.y) + b4.w)));
        float y0 = ac0[c] > 0.f ? ac0[c] : 0.f;
        float y1 = ac1[c] > 0.f ? ac1[c] : 0.f;
        float y2 = ac2[c] > 0.f ? ac2[c] : 0.f;
        float y3 = ac3[c] > 0.f ? ac3[c] : 0.f;
        float o0 = g0 * y0 + (1.f - g0) * hlo(ub.x);
        float o1 = g1 * y1 + (1.f - g1) * hhi(ub.x);
        float o2 = g2 * y2 + (1.f - g2) * hlo(ub.y);
        float o3 = g3 * y3 + (1.f - g3) * hhi(ub.y);
        if (outb) {
          uint2 ov;
          ov.x = packh(o0, o1); ov.y = packh(o2, o3);
          ((uint2*)(outb + (size_t)row * E_DIM))[m] = ov;
        } else {
          float4 of; of.x = o0; of.y = o1; of.z = o2; of.w = o3;
          ((float4*)(outf + (size_t)row * E_DIM))[m] = of;
        }
      }
    }
  }
}

// ---------------- pack W into MFMA B-fragment layout (fp16) ----------------
__global__ __launch_bounds__(64) void k_packW(
    const float* __restrict__ W1, const float* __restrict__ W2,
    __half* __restrict__ Wp)
{
  int lane = threadIdx.x;
  int t = blockIdx.x, s = blockIdx.y;
  int c = t * 16 + (lane & 15);
  __half v[8];
  #pragma unroll
  for (int j = 0; j < 8; ++j) {
    int k = s * 32 + (lane >> 4) * 8 + j;
    float x = 0.f;
    if (k < E_DIM && c < 2 * E_DIM)
      x = (c < E_DIM) ? W1[(size_t)k * E_DIM + c]
                      : W2[(size_t)k * E_DIM + (c - E_DIM)];
    v[j] = __float2half_rn(x);
  }
  size_t base = ((size_t)(t * NK + s) * 64 + lane) * 8;
  #pragma unroll
  for (int j = 0; j < 8; ++j) Wp[base + j] = v[j];
}

// ---------------- fused dual-GEMM: Y1,Y2 (fp16) = X @ {gcnW1, hwWr} --------
__global__ __launch_bounds__(256) void k_gemm2_mfma(
    const __half* __restrict__ Xb, const __half* __restrict__ Wp,
    __half* __restrict__ Y1, __half* __restrict__ Y2, int M)
{
  __shared__ __half Xs[32][XS_LD];
  int tid = threadIdx.x;
  int r0 = blockIdx.x * 32;
  int nb = blockIdx.y;

  for (int t = tid; t < 32 * (XS_LD / 2); t += 256) {
    int r = t / (XS_LD / 2), u = t % (XS_LD / 2);
    unsigned v = 0;
    int rg = r0 + r;
    if (rg < M && u < E_DIM / 2) v = ((const unsigned*)Xb)[(size_t)rg * (E_DIM / 2) + u];
    ((unsigned*)&Xs[0][0])[r * (XS_LD / 2) + u] = v;
  }
  __syncthreads();

  int wid = tid >> 6, lane = tid & 63;
  int wave_m = wid >> 1, wave_n = wid & 1;
  int rowA = wave_m * 16 + (lane & 15);
  int kgrp = (lane >> 4) * 8;
  int tb0 = nb * 8 + wave_n * 4;

  const f16x8* wfrag = (const f16x8*)Wp + (size_t)tb0 * (NK * 64) + lane;

  f32x4 acc[4] = {{0,0,0,0},{0,0,0,0},{0,0,0,0},{0,0,0,0}};
  #pragma unroll 2
  for (int ks = 0; ks < NK; ++ks) {
    f16x8 a = *(const f16x8*)&Xs[rowA][ks * 32 + kgrp];
    #pragma unroll
    for (int nt = 0; nt < 4; ++nt) {
      f16x8 b = wfrag[(nt * NK + ks) * 64];
      acc[nt] = __builtin_amdgcn_mfma_f32_16x16x32_f16(a, b, acc[nt], 0, 0, 0);
    }
  }

  int rbase = r0 + wave_m * 16 + ((lane >> 4) << 2);
  #pragma unroll
  for (int nt = 0; nt < 4; ++nt) {
    int c = (tb0 + nt) * 16 + (lane & 15);
    #pragma unroll
    for (int j = 0; j < 4; ++j) {
      int row = rbase + j;
      if (row < M) {
        __half hv = __float2half_rn(acc[nt][j]);
        if (c < E_DIM)            Y1[(size_t)row * E_DIM + c] = hv;
        else if (c < 2 * E_DIM)   Y2[(size_t)row * E_DIM + (c - E_DIM)] = hv;
      }
    }
  }
}

extern "C" void kernel_launch(void* const* d_in, const int* in_sizes, int n_in,
                              void* d_out, int out_size, void* d_ws, size_t ws_size,
                              hipStream_t stream)
{
  const float* primal      = (const float*)d_in[0];
  const float* r_head      = (const float*)d_in[1];
  const float* r_tail      = (const float*)d_in[2];
  const float* e_adj_data  = (const float*)d_in[3];
  const float* be_L        = (const float*)d_in[4];
  const float* be_R        = (const float*)d_in[5];
  const float* atten_r     = (const float*)d_in[6];
  const float* gcnW1       = (const float*)d_in[7];
  const float* hwWr        = (const float*)d_in[8];
  const float* hwbr        = (const float*)d_in[9];
  const int*   e_adj_index = (const int*)d_in[10];
  const int*   eer_idx     = (const int*)d_in[11];
  const int*   eer_rel     = (const int*)d_in[12];
  int ne   = in_sizes[10] / 2;
  int neer = in_sizes[11] / 2;

  char* ws = (char*)d_ws;
  size_t off = 0;
  auto take = [&](size_t bytes) {
    void* p = ws + off;
    off = (off + bytes + 255) & ~(size_t)255;
    return p;
  };
  int*   cnt      = (int*)  take((size_t)2 * KG_R * sizeof(int));
  float* inv      = (float*)take((size_t)2 * KG_R * sizeof(float));
  // ---- contiguous zero-init block (single memset) ----
  size_t z0 = off;
  int*   hcntA    = (int*)  take((size_t)KG_E * sizeof(int));
  int*   hcntB    = (int*)  take((size_t)KG_E * sizeof(int));
  int*   hfillA   = (int*)  take((size_t)KG_E * sizeof(int));
  int*   hfillB   = (int*)  take((size_t)KG_E * sizeof(int));
  int*   rfill    = (int*)  take((size_t)2 * KG_R * sizeof(int));
  float* rsumb    = (float*)take((size_t)2 * KG_R * sizeof(float));
  size_t z1 = off;
  // ----------------------------------------------------
  int*   lidx     = (int*)  take((size_t)2 * KG_R * CAP * sizeof(int));
  float* lsv      = (float*)take((size_t)2 * KG_R * CAP * sizeof(float));
  unsigned* wpk   = (unsigned*)take((size_t)2 * KG_R * NPAIR * sizeof(unsigned));
  int*   bsum     = (int*)  take((size_t)2 * (NB_SCAN + 1) * sizeof(int));
  int*   eer_start= (int*)  take((size_t)(KG_E + 4) * sizeof(int));
  int*   adj_start= (int*)  take((size_t)(KG_E + 4) * sizeof(int));
  int*   eer_scol = (int*)  take((size_t)neer * sizeof(int));
  int*   eer_srel = (int*)  take((size_t)neer * sizeof(int));
  int*   adj_scol = (int*)  take((size_t)ne * sizeof(int));
  float* adj_sval = (float*)take((size_t)ne * sizeof(float));
  __half* Wp = (__half*)take((size_t)NT * NK * 64 * 8 * sizeof(__half));
  __half* B0 = (__half*)take((size_t)KG_E * E_DIM * sizeof(__half)); // primal fp16
  __half* B1 = (__half*)take((size_t)KG_E * E_DIM * sizeof(__half)); // e1 / g2
  __half* B2 = (__half*)take((size_t)KG_E * E_DIM * sizeof(__half)); // e2
  __half* Fb = (__half*)take((size_t)KG_E * E_DIM * sizeof(__half)); // X@gcnW1
  __half* Gb = (__half*)take((size_t)KG_E * E_DIM * sizeof(__half)); // X@hwWr
  float* out      = (float*)d_out;
  (void)ws_size; (void)n_in; (void)out_size;

  int eg = (neer + 255) / 256;
  int ag = (ne + 255) / 256;

  // ---- single memset for all zero-init scratch ----
  hipMemsetAsync(ws + z0, 0, z1 - z0, stream);

  // ---- CSR builds (both graphs; shared 3-phase scan) ----
  k_hist<<<eg, 256, 0, stream>>>(eer_idx, hcntA, neer);
  k_hist<<<ag, 256, 0, stream>>>(e_adj_index, hcntB, ne);
  k_scan_a<<<dim3(NB_SCAN, 2), 256, 0, stream>>>(hcntA, hcntB, bsum, KG_E);
  k_scan_b<<<1, 64, 0, stream>>>(bsum);
  k_scan_c<<<dim3(NB_SCAN, 2), 256, 0, stream>>>(hcntA, hcntB, bsum,
                                                 eer_start, adj_start, KG_E);
  k_scatter_eer<<<eg, 256, 0, stream>>>(eer_idx, eer_rel, eer_start, hfillA,
                                        eer_scol, eer_srel, neer);
  k_scatter_adj<<<ag, 256, 0, stream>>>(e_adj_index, e_adj_data, adj_start, hfillB,
                                        adj_scol, adj_sval, ne);

  // ---- compact r_head/r_tail + pack weights + primal fp16 ----
  k_compact2<<<dim3(NCH, KG_R, 2), 256, 0, stream>>>(r_head, r_tail, be_L, be_R,
                                                     lidx, lsv, rfill, rsumb);
  k_rmeta<<<(2 * KG_R + 255) / 256, 256, 0, stream>>>(rfill, rsumb, cnt, inv);
  k_packW<<<dim3(NT, NK), 64, 0, stream>>>(gcnW1, hwWr, Wp);
  int n4 = KG_E * E_DIM / 4;
  k_toh<<<(n4 + 255) / 256, 256, 0, stream>>>(primal, B0, n4);

  int rg = (KG_E + 3) / 4;

  // ---- attention layer 1: e1 = primal + 0.1*att(primal) -> B1 ----
  k_rlayer<<<2 * KG_R, 192, 0, stream>>>(B0, lidx, lsv, cnt, inv, atten_r, wpk);
  k_att_csr<<<rg, 256, 0, stream>>>(B0, wpk, eer_start, eer_scol, eer_srel,
                                    B0, 0.1f, B1);
  // ---- attention layer 2: e2 = primal + 0.3*att(e1) -> B2 ----
  k_rlayer<<<2 * KG_R, 192, 0, stream>>>(B1, lidx, lsv, cnt, inv, atten_r, wpk);
  k_att_csr<<<rg, 256, 0, stream>>>(B1, wpk, eer_start, eer_scol, eer_srel,
                                    B0, 0.3f, B2);

  // ---- GCN + highway 1: Fb,Gb = e2 @ {gcnW1,hwWr}; g2 -> B1 ----
  dim3 gg((KG_E + 31) / 32, 5);
  k_gemm2_mfma<<<gg, 256, 0, stream>>>(B2, Wp, Fb, Gb, KG_E);
  k_spmm_hw<<<rg, 256, 0, stream>>>(Fb, adj_start, adj_scol, adj_sval,
                                    Gb, B2, hwbr, B1, (float*)nullptr);

  // ---- GCN + highway 2: Fb,Gb = g2 @ {gcnW1,hwWr}; out = highway ----
  k_gemm2_mfma<<<gg, 256, 0, stream>>>(B1, Wp, Fb, Gb, KG_E);
  k_spmm_hw<<<rg, 256, 0, stream>>>(Fb, adj_start, adj_scol, adj_sval,
                                    Gb, B1, hwbr, (__half*)nullptr, out);
}

// Round 11
// 791.265 us; speedup vs baseline: 1.8052x; 1.0149x over previous
//
#include <hip/hip_runtime.h>
#include <hip/hip_fp16.h>
#include <math.h>

#define KG_E  50000
#define KG_R  500
#define E_DIM 300
#define NPAIR 150         // E_DIM/2 fp16 pairs per row
#define NP2   75          // E_DIM/4 uint2 per row
#define CAP   1024
#define LRELU 0.2f

// MFMA GEMM geometry: Y[M,600(pad 640)] = X[M,300(pad 320)] @ Wcat
#define NK    10
#define NT    40
#define XS_LD 328

#define NB_SCAN 49        // ceil(KG_E/1024)

typedef __attribute__((ext_vector_type(8))) _Float16 f16x8;
typedef __attribute__((ext_vector_type(4))) float f32x4;

__device__ __forceinline__ __half2 u2h2(unsigned u) {
  union { unsigned u; __half2 h; } v; v.u = u; return v.h;
}
__device__ __forceinline__ unsigned h22u(__half2 h) {
  union { unsigned u; __half2 h; } v; v.h = h; return v.u;
}
__device__ __forceinline__ float hlo(unsigned u) { return __low2float(u2h2(u)); }
__device__ __forceinline__ float hhi(unsigned u) { return __high2float(u2h2(u)); }
__device__ __forceinline__ unsigned packh(float lo, float hi) {
  return h22u(__floats2half2_rn(lo, hi));
}

// ---------------- f32 -> fp16 table conversion -----------------------------
__global__ __launch_bounds__(256) void k_toh(
    const float* __restrict__ src, __half* __restrict__ dst, int n4)
{
  int i = blockIdx.x * 256 + threadIdx.x;
  if (i >= n4) return;
  float4 f = ((const float4*)src)[i];
  uint2 o;
  o.x = packh(f.x, f.y);
  o.y = packh(f.z, f.w);
  ((uint2*)dst)[i] = o;
}

// ---------------- compaction: 16 floats/thread, wave prefix, LDS staged ----
#define NCH 5
#define SCAP 1024
#define NF4 2500          // float4s per chunk = (KG_E/NCH)/4
__global__ __launch_bounds__(256) void k_compact2(
    const float* __restrict__ r_head, const float* __restrict__ r_tail,
    const float* __restrict__ be_L, const float* __restrict__ be_R,
    int* __restrict__ lidx, float* __restrict__ lsval,
    int* __restrict__ fill, float* __restrict__ rsum)
{
  __shared__ int   ls_e[SCAP];
  __shared__ float ls_v[SCAP];
  __shared__ int   ls_cnt;
  __shared__ float ls_sum;
  __shared__ int   ls_base;
  int m = blockIdx.z;
  int r = blockIdx.y;
  const float* rowp = (m ? r_tail : r_head) + (size_t)r * KG_E;
  const float* be   = m ? be_R : be_L;
  int slot = m * KG_R + r;
  int lane = threadIdx.x & 63;
  if (threadIdx.x == 0) { ls_cnt = 0; ls_sum = 0.f; }
  __syncthreads();

  const int CH = KG_E / NCH;       // 10000
  int c0 = blockIdx.x * CH;
  const float4* rp4 = (const float4*)(rowp + c0);
  float lsum = 0.f;

  #pragma unroll
  for (int i = 0; i < (NF4 + 1023) / 1024; ++i) {      // 3 granules
    int fi0 = i * 1024 + threadIdx.x;
    float vals[16];
    #pragma unroll
    for (int k = 0; k < 4; ++k) {
      int fi = fi0 + k * 256;
      float4 f = (fi < NF4) ? rp4[fi] : make_float4(0.f, 0.f, 0.f, 0.f);
      vals[k*4+0] = f.x; vals[k*4+1] = f.y; vals[k*4+2] = f.z; vals[k*4+3] = f.w;
    }
    int cnt16 = 0;
    #pragma unroll
    for (int q = 0; q < 16; ++q) {
      lsum += vals[q];
      cnt16 += (vals[q] != 0.f) ? 1 : 0;
    }
    // wave-wide inclusive prefix of cnt16
    int pre = cnt16;
    #pragma unroll
    for (int off = 1; off < 64; off <<= 1) {
      int u = __shfl_up(pre, off, 64);
      if (lane >= off) pre += u;
    }
    int wave_base = 0;
    if (lane == 63 && pre > 0) wave_base = atomicAdd(&ls_cnt, pre);
    wave_base = __shfl(wave_base, 63, 64);
    if (cnt16 > 0) {
      int o = wave_base + pre - cnt16;
      #pragma unroll
      for (int k = 0; k < 4; ++k) {
        int fi = fi0 + k * 256;
        #pragma unroll
        for (int q = 0; q < 4; ++q) {
          float v = vals[k*4+q];
          if (v != 0.f) {
            if (o < SCAP) {
              int e = c0 + fi * 4 + q;
              ls_e[o] = e;
              ls_v[o] = v * be[e];
            }
            ++o;
          }
        }
      }
    }
  }
  #pragma unroll
  for (int off = 32; off > 0; off >>= 1) lsum += __shfl_xor(lsum, off, 64);
  if (lane == 0 && lsum != 0.f) atomicAdd(&ls_sum, lsum);
  __syncthreads();

  int total = ls_cnt < SCAP ? ls_cnt : SCAP;
  if (threadIdx.x == 0) {
    ls_base = atomicAdd(&fill[slot], total);
    if (ls_sum != 0.f) atomicAdd(&rsum[slot], ls_sum);
  }
  __syncthreads();
  int gbase = ls_base;
  int*   li = lidx  + (size_t)slot * CAP;
  float* lv = lsval + (size_t)slot * CAP;
  for (int i = threadIdx.x; i < total; i += 256) {
    int pos = gbase + i;
    if (pos < CAP) { li[pos] = ls_e[i]; lv[pos] = ls_v[i]; }
  }
}

__global__ __launch_bounds__(256) void k_rmeta(
    const int* __restrict__ fill, const float* __restrict__ rsum,
    int* __restrict__ cnt, float* __restrict__ inv)
{
  int i = blockIdx.x * 256 + threadIdx.x;
  if (i < 2 * KG_R) {
    int c = fill[i];
    cnt[i] = c > CAP ? CAP : c;
    float s = rsum[i];
    inv[i] = (s == 0.f) ? 0.f : 1.f / s;
  }
}

// ---------------- r-layer: fp16 pair gathers, f32 accum, packed-h2 out -----
__global__ __launch_bounds__(192) void k_rlayer(
    const __half* __restrict__ Eb, const int* __restrict__ lidx,
    const float* __restrict__ lsval, const int* __restrict__ cnt,
    const float* __restrict__ inv, const float* __restrict__ atten,
    unsigned* __restrict__ wpk)
{
  int b = blockIdx.x;
  int m = b / KG_R, r = b % KG_R;
  int p = threadIdx.x;
  if (p >= NPAIR) return;
  int slot = m * KG_R + r;
  int n = cnt[slot];
  const int*   li = lidx  + (size_t)slot * CAP;
  const float* lv = lsval + (size_t)slot * CAP;
  float alo = 0.f, ahi = 0.f;
  #pragma unroll 4
  for (int i = 0; i < n; ++i) {
    int e = li[i];
    float s = lv[i];
    unsigned u = ((const unsigned*)(Eb + (size_t)e * E_DIM))[p];
    alo += s * hlo(u);
    ahi += s * hhi(u);
  }
  float iv = inv[slot];
  float vlo = alo * iv; vlo = vlo > 0.f ? vlo : 0.f;
  float vhi = ahi * iv; vhi = vhi > 0.f ? vhi : 0.f;
  vlo *= atten[m * E_DIM + 2 * p];
  vhi *= atten[m * E_DIM + 2 * p + 1];
  wpk[(size_t)slot * NPAIR + p] = packh(vlo, vhi);
}

// ---------------- CSR build: histogram, 3-phase scan, scatter --------------
__global__ __launch_bounds__(256) void k_hist(
    const int* __restrict__ rows, int* __restrict__ cnt, int n)
{
  int i = blockIdx.x * 256 + threadIdx.x;
  if (i < n) atomicAdd(&cnt[rows[i]], 1);
}

__global__ __launch_bounds__(256) void k_scan_a(
    const int* __restrict__ c0, const int* __restrict__ c1,
    int* __restrict__ bsum, int n)
{
  const int* c = blockIdx.y ? c1 : c0;
  int base = blockIdx.x * 1024;
  int s = 0;
  #pragma unroll
  for (int k = 0; k < 4; ++k) {
    int i = base + k * 256 + threadIdx.x;
    if (i < n) s += c[i];
  }
  #pragma unroll
  for (int off = 32; off > 0; off >>= 1) s += __shfl_xor(s, off, 64);
  __shared__ int ws[4];
  if ((threadIdx.x & 63) == 0) ws[threadIdx.x >> 6] = s;
  __syncthreads();
  if (threadIdx.x == 0)
    bsum[blockIdx.y * (NB_SCAN + 1) + blockIdx.x] = ws[0] + ws[1] + ws[2] + ws[3];
}

__global__ __launch_bounds__(64) void k_scan_b(int* __restrict__ bsum)
{
  if (threadIdx.x < 2) {
    int* b = bsum + threadIdx.x * (NB_SCAN + 1);
    int acc = 0;
    for (int i = 0; i < NB_SCAN; ++i) { int v = b[i]; b[i] = acc; acc += v; }
    b[NB_SCAN] = acc;
  }
}

__global__ __launch_bounds__(256) void k_scan_c(
    const int* __restrict__ c0, const int* __restrict__ c1,
    const int* __restrict__ bsum,
    int* __restrict__ s0, int* __restrict__ s1, int n)
{
  const int* c = blockIdx.y ? c1 : c0;
  int* sO = blockIdx.y ? s1 : s0;
  if (blockIdx.x == 0 && threadIdx.x == 0)
    sO[n] = bsum[blockIdx.y * (NB_SCAN + 1) + NB_SCAN];
  int boff = bsum[blockIdx.y * (NB_SCAN + 1) + blockIdx.x];
  int i0 = blockIdx.x * 1024 + threadIdx.x * 4;
  int4 v = {0, 0, 0, 0};
  if (i0 < n) v = ((const int4*)c)[i0 >> 2];
  int tsum = v.x + v.y + v.z + v.w;
  int lane = threadIdx.x & 63, wid = threadIdx.x >> 6;
  int inc = tsum;
  #pragma unroll
  for (int off = 1; off < 64; off <<= 1) {
    int u = __shfl_up(inc, off, 64);
    if (lane >= off) inc += u;
  }
  __shared__ int ws[4];
  if (lane == 63) ws[wid] = inc;
  __syncthreads();
  int woff = 0;
  if (wid > 0) woff += ws[0];
  if (wid > 1) woff += ws[1];
  if (wid > 2) woff += ws[2];
  int ex = boff + woff + inc - tsum;
  if (i0 < n) {
    int4 o;
    o.x = ex; o.y = ex + v.x; o.z = o.y + v.y; o.w = o.z + v.z;
    ((int4*)sO)[i0 >> 2] = o;
  }
}

__global__ __launch_bounds__(256) void k_scatter_eer(
    const int* __restrict__ eidx, const int* __restrict__ erel,
    const int* __restrict__ start, int* __restrict__ fill,
    int* __restrict__ scol, int* __restrict__ srel, int neer)
{
  int i = blockIdx.x * 256 + threadIdx.x;
  if (i >= neer) return;
  int row = eidx[i];
  int pos = start[row] + atomicAdd(&fill[row], 1);
  scol[pos] = eidx[neer + i];
  srel[pos] = erel[i];
}

__global__ __launch_bounds__(256) void k_scatter_adj(
    const int* __restrict__ aidx, const float* __restrict__ adata,
    const int* __restrict__ start, int* __restrict__ fill,
    int* __restrict__ scol, float* __restrict__ sval, int ne)
{
  int i = blockIdx.x * 256 + threadIdx.x;
  if (i >= ne) return;
  int row = aidx[i];
  int pos = start[row] + atomicAdd(&fill[row], 1);
  scol[pos] = aidx[ne + i];
  sval[pos] = adata[i];
}

// ---------------- attention: half-wave, packed-half2 math, 2 ILP chains ----
__global__ __launch_bounds__(256) void k_att_csr(
    const __half* __restrict__ Eb, const unsigned* __restrict__ wpk,
    const int* __restrict__ start, const int* __restrict__ scol,
    const int* __restrict__ srel, const __half* __restrict__ baseb,
    float alpha, __half* __restrict__ outb)
{
  int wave = threadIdx.x >> 6, lane = threadIdx.x & 63;
  int half = lane >> 5, hl = lane & 31;
  int row = blockIdx.x * 4 + wave;
  if (row >= KG_E) return;
  int s = start[row], e = start[row + 1];
  const uint2* erp = (const uint2*)(Eb + (size_t)row * E_DIM);
  __half2 zero2 = __floats2half2_rn(0.f, 0.f);
  __half2 er[3][2], ac[3][2];
  #pragma unroll
  for (int c = 0; c < 3; ++c) {
    int m = c * 32 + hl;
    if (m < NP2) {
      uint2 u = erp[m];
      er[c][0] = u2h2(u.x); er[c][1] = u2h2(u.y);
    } else { er[c][0] = zero2; er[c][1] = zero2; }
    ac[c][0] = zero2; ac[c][1] = zero2;
  }
  float rs = 0.f;
  int nIter = (e - s + 1) >> 1;
  for (int it = 0; it < nIter; ++it) {
    int j = s + 2 * it + half;
    bool act = j < e;
    int col = act ? scol[j] : 0;
    int rel = act ? srel[j] : 0;
    const uint2* ecp = (const uint2*)(Eb + (size_t)col * E_DIM);
    const uint2* whp = (const uint2*)(wpk + (size_t)rel * NPAIR);
    const uint2* wtp = (const uint2*)(wpk + (size_t)(KG_R + rel) * NPAIR);
    __half2 ec[3][2];
    __half2 p2a = zero2, p2b = zero2;
    #pragma unroll
    for (int c = 0; c < 3; ++c) {
      int m = c * 32 + hl;
      if (m < NP2) {
        uint2 uc = ecp[m], uh = whp[m], ut = wtp[m];
        ec[c][0] = u2h2(uc.x); ec[c][1] = u2h2(uc.y);
        p2a = __hfma2(er[c][0], u2h2(uh.x), p2a);
        p2b = __hfma2(er[c][1], u2h2(uh.y), p2b);
        p2a = __hfma2(ec[c][0], u2h2(ut.x), p2a);
        p2b = __hfma2(ec[c][1], u2h2(ut.y), p2b);
      } else { ec[c][0] = zero2; ec[c][1] = zero2; }
    }
    __half2 p2 = __hadd2(p2a, p2b);
    float p4 = __low2float(p2) + __high2float(p2);
    #pragma unroll
    for (int off = 16; off > 0; off >>= 1) p4 += __shfl_xor(p4, off, 64);
    float la = p4 >= 0.f ? p4 : LRELU * p4;
    float at = act ? __expf(-la) : 0.f;
    rs += at;
    __half2 at2 = __float2half2_rn(at);
    #pragma unroll
    for (int c = 0; c < 3; ++c) {
      ac[c][0] = __hfma2(at2, ec[c][0], ac[c][0]);
      ac[c][1] = __hfma2(at2, ec[c][1], ac[c][1]);
    }
  }
  // merge halves
  rs += __shfl_xor(rs, 32, 64);
  #pragma unroll
  for (int c = 0; c < 3; ++c) {
    #pragma unroll
    for (int k = 0; k < 2; ++k) {
      unsigned o = __shfl_xor(h22u(ac[c][k]), 32, 64);
      ac[c][k] = __hadd2(ac[c][k], u2h2(o));
    }
  }
  if (half == 0) {
    float iv = (rs == 0.f) ? 0.f : 1.f / rs;
    const uint2* bp = (const uint2*)(baseb + (size_t)row * E_DIM);
    uint2* op = (uint2*)(outb + (size_t)row * E_DIM);
    #pragma unroll
    for (int c = 0; c < 3; ++c) {
      int m = c * 32 + hl;
      if (m < NP2) {
        uint2 ub = bp[m];
        float v0 = __low2float(ac[c][0]) * iv;  v0 = v0 > 0.f ? v0 : 0.f;
        float v1 = __high2float(ac[c][0]) * iv; v1 = v1 > 0.f ? v1 : 0.f;
        float v2 = __low2float(ac[c][1]) * iv;  v2 = v2 > 0.f ? v2 : 0.f;
        float v3 = __high2float(ac[c][1]) * iv; v3 = v3 > 0.f ? v3 : 0.f;
        uint2 o2;
        o2.x = packh(hlo(ub.x) + alpha * v0, hhi(ub.x) + alpha * v1);
        o2.y = packh(hlo(ub.y) + alpha * v2, hhi(ub.y) + alpha * v3);
        op[m] = o2;
      }
    }
  }
}

// ---------------- fused spmm + highway: half-wave, f32 accum ---------------
__global__ __launch_bounds__(256) void k_spmm_hw(
    const __half* __restrict__ Xb, const int* __restrict__ start,
    const int* __restrict__ scol, const float* __restrict__ sval,
    const __half* __restrict__ Gb, const __half* __restrict__ baseb,
    const float* __restrict__ br,
    __half* __restrict__ outb, float* __restrict__ outf)
{
  int wave = threadIdx.x >> 6, lane = threadIdx.x & 63;
  int half = lane >> 5, hl = lane & 31;
  int row = blockIdx.x * 4 + wave;
  if (row >= KG_E) return;
  int s = start[row], e = start[row + 1];
  float ac0[3] = {0,0,0}, ac1[3] = {0,0,0}, ac2[3] = {0,0,0}, ac3[3] = {0,0,0};
  int nIter = (e - s + 1) >> 1;
  for (int it = 0; it < nIter; ++it) {
    int j = s + 2 * it + half;
    bool act = j < e;
    int col = act ? scol[j] : 0;
    float v = act ? sval[j] : 0.f;
    const uint2* xp = (const uint2*)(Xb + (size_t)col * E_DIM);
    #pragma unroll
    for (int c = 0; c < 3; ++c) {
      int m = c * 32 + hl;
      if (m < NP2) {
        uint2 u = xp[m];
        ac0[c] += v * hlo(u.x); ac1[c] += v * hhi(u.x);
        ac2[c] += v * hlo(u.y); ac3[c] += v * hhi(u.y);
      }
    }
  }
  #pragma unroll
  for (int c = 0; c < 3; ++c) {
    ac0[c] += __shfl_xor(ac0[c], 32, 64);
    ac1[c] += __shfl_xor(ac1[c], 32, 64);
    ac2[c] += __shfl_xor(ac2[c], 32, 64);
    ac3[c] += __shfl_xor(ac3[c], 32, 64);
  }
  if (half == 0) {
    const uint2* gp = (const uint2*)(Gb + (size_t)row * E_DIM);
    const uint2* bp = (const uint2*)(baseb + (size_t)row * E_DIM);
    #pragma unroll
    for (int c = 0; c < 3; ++c) {
      int m = c * 32 + hl;
      if (m < NP2) {
        uint2 ug = gp[m], ub = bp[m];
        float4 b4 = ((const float4*)br)[m];
        float g0 = 1.f / (1.f + __expf(-(hlo(ug.x) + b4.x)));
        float g1 = 1.f / (1.f + __expf(-(hhi(ug.x) + b4.y)));
        float g2 = 1.f / (1.f + __expf(-(hlo(ug.y) + b4.z)));
        float g3 = 1.f / (1.f + __expf(-(hhi(ug.y) + b4.w)));
        float y0 = ac0[c] > 0.f ? ac0[c] : 0.f;
        float y1 = ac1[c] > 0.f ? ac1[c] : 0.f;
        float y2 = ac2[c] > 0.f ? ac2[c] : 0.f;
        float y3 = ac3[c] > 0.f ? ac3[c] : 0.f;
        float o0 = g0 * y0 + (1.f - g0) * hlo(ub.x);
        float o1 = g1 * y1 + (1.f - g1) * hhi(ub.x);
        float o2 = g2 * y2 + (1.f - g2) * hlo(ub.y);
        float o3 = g3 * y3 + (1.f - g3) * hhi(ub.y);
        if (outb) {
          uint2 ov;
          ov.x = packh(o0, o1); ov.y = packh(o2, o3);
          ((uint2*)(outb + (size_t)row * E_DIM))[m] = ov;
        } else {
          float4 of; of.x = o0; of.y = o1; of.z = o2; of.w = o3;
          ((float4*)(outf + (size_t)row * E_DIM))[m] = of;
        }
      }
    }
  }
}

// ---------------- pack W into MFMA B-fragment layout (fp16) ----------------
__global__ __launch_bounds__(64) void k_packW(
    const float* __restrict__ W1, const float* __restrict__ W2,
    __half* __restrict__ Wp)
{
  int lane = threadIdx.x;
  int t = blockIdx.x, s = blockIdx.y;
  int c = t * 16 + (lane & 15);
  __half v[8];
  #pragma unroll
  for (int j = 0; j < 8; ++j) {
    int k = s * 32 + (lane >> 4) * 8 + j;
    float x = 0.f;
    if (k < E_DIM && c < 2 * E_DIM)
      x = (c < E_DIM) ? W1[(size_t)k * E_DIM + c]
                      : W2[(size_t)k * E_DIM + (c - E_DIM)];
    v[j] = __float2half_rn(x);
  }
  size_t base = ((size_t)(t * NK + s) * 64 + lane) * 8;
  #pragma unroll
  for (int j = 0; j < 8; ++j) Wp[base + j] = v[j];
}

// ---------------- fused dual-GEMM: Y1,Y2 (fp16) = X @ {gcnW1, hwWr} --------
__global__ __launch_bounds__(256) void k_gemm2_mfma(
    const __half* __restrict__ Xb, const __half* __restrict__ Wp,
    __half* __restrict__ Y1, __half* __restrict__ Y2, int M)
{
  __shared__ __half Xs[32][XS_LD];
  int tid = threadIdx.x;
  int r0 = blockIdx.x * 32;
  int nb = blockIdx.y;

  for (int t = tid; t < 32 * (XS_LD / 2); t += 256) {
    int r = t / (XS_LD / 2), u = t % (XS_LD / 2);
    unsigned v = 0;
    int rg = r0 + r;
    if (rg < M && u < E_DIM / 2) v = ((const unsigned*)Xb)[(size_t)rg * (E_DIM / 2) + u];
    ((unsigned*)&Xs[0][0])[r * (XS_LD / 2) + u] = v;
  }
  __syncthreads();

  int wid = tid >> 6, lane = tid & 63;
  int wave_m = wid >> 1, wave_n = wid & 1;
  int rowA = wave_m * 16 + (lane & 15);
  int kgrp = (lane >> 4) * 8;
  int tb0 = nb * 8 + wave_n * 4;

  const f16x8* wfrag = (const f16x8*)Wp + (size_t)tb0 * (NK * 64) + lane;

  f32x4 acc[4] = {{0,0,0,0},{0,0,0,0},{0,0,0,0},{0,0,0,0}};
  #pragma unroll 2
  for (int ks = 0; ks < NK; ++ks) {
    f16x8 a = *(const f16x8*)&Xs[rowA][ks * 32 + kgrp];
    #pragma unroll
    for (int nt = 0; nt < 4; ++nt) {
      f16x8 b = wfrag[(nt * NK + ks) * 64];
      acc[nt] = __builtin_amdgcn_mfma_f32_16x16x32_f16(a, b, acc[nt], 0, 0, 0);
    }
  }

  int rbase = r0 + wave_m * 16 + ((lane >> 4) << 2);
  #pragma unroll
  for (int nt = 0; nt < 4; ++nt) {
    int c = (tb0 + nt) * 16 + (lane & 15);
    #pragma unroll
    for (int j = 0; j < 4; ++j) {
      int row = rbase + j;
      if (row < M) {
        __half hv = __float2half_rn(acc[nt][j]);
        if (c < E_DIM)            Y1[(size_t)row * E_DIM + c] = hv;
        else if (c < 2 * E_DIM)   Y2[(size_t)row * E_DIM + (c - E_DIM)] = hv;
      }
    }
  }
}

extern "C" void kernel_launch(void* const* d_in, const int* in_sizes, int n_in,
                              void* d_out, int out_size, void* d_ws, size_t ws_size,
                              hipStream_t stream)
{
  const float* primal      = (const float*)d_in[0];
  const float* r_head      = (const float*)d_in[1];
  const float* r_tail      = (const float*)d_in[2];
  const float* e_adj_data  = (const float*)d_in[3];
  const float* be_L        = (const float*)d_in[4];
  const float* be_R        = (const float*)d_in[5];
  const float* atten_r     = (const float*)d_in[6];
  const float* gcnW1       = (const float*)d_in[7];
  const float* hwWr        = (const float*)d_in[8];
  const float* hwbr        = (const float*)d_in[9];
  const int*   e_adj_index = (const int*)d_in[10];
  const int*   eer_idx     = (const int*)d_in[11];
  const int*   eer_rel     = (const int*)d_in[12];
  int ne   = in_sizes[10] / 2;
  int neer = in_sizes[11] / 2;

  char* ws = (char*)d_ws;
  size_t off = 0;
  auto take = [&](size_t bytes) {
    void* p = ws + off;
    off = (off + bytes + 255) & ~(size_t)255;
    return p;
  };
  int*   cnt      = (int*)  take((size_t)2 * KG_R * sizeof(int));
  float* inv      = (float*)take((size_t)2 * KG_R * sizeof(float));
  // ---- contiguous zero-init block (single memset) ----
  size_t z0 = off;
  int*   hcntA    = (int*)  take((size_t)KG_E * sizeof(int));
  int*   hcntB    = (int*)  take((size_t)KG_E * sizeof(int));
  int*   hfillA   = (int*)  take((size_t)KG_E * sizeof(int));
  int*   hfillB   = (int*)  take((size_t)KG_E * sizeof(int));
  int*   rfill    = (int*)  take((size_t)2 * KG_R * sizeof(int));
  float* rsumb    = (float*)take((size_t)2 * KG_R * sizeof(float));
  size_t z1 = off;
  // ----------------------------------------------------
  int*   lidx     = (int*)  take((size_t)2 * KG_R * CAP * sizeof(int));
  float* lsv      = (float*)take((size_t)2 * KG_R * CAP * sizeof(float));
  unsigned* wpk   = (unsigned*)take((size_t)2 * KG_R * NPAIR * sizeof(unsigned));
  int*   bsum     = (int*)  take((size_t)2 * (NB_SCAN + 1) * sizeof(int));
  int*   eer_start= (int*)  take((size_t)(KG_E + 4) * sizeof(int));
  int*   adj_start= (int*)  take((size_t)(KG_E + 4) * sizeof(int));
  int*   eer_scol = (int*)  take((size_t)neer * sizeof(int));
  int*   eer_srel = (int*)  take((size_t)neer * sizeof(int));
  int*   adj_scol = (int*)  take((size_t)ne * sizeof(int));
  float* adj_sval = (float*)take((size_t)ne * sizeof(float));
  __half* Wp = (__half*)take((size_t)NT * NK * 64 * 8 * sizeof(__half));
  __half* B0 = (__half*)take((size_t)KG_E * E_DIM * sizeof(__half)); // primal fp16
  __half* B1 = (__half*)take((size_t)KG_E * E_DIM * sizeof(__half)); // e1 / g2
  __half* B2 = (__half*)take((size_t)KG_E * E_DIM * sizeof(__half)); // e2
  __half* Fb = (__half*)take((size_t)KG_E * E_DIM * sizeof(__half)); // X@gcnW1
  __half* Gb = (__half*)take((size_t)KG_E * E_DIM * sizeof(__half)); // X@hwWr
  float* out      = (float*)d_out;
  (void)ws_size; (void)n_in; (void)out_size;

  int eg = (neer + 255) / 256;
  int ag = (ne + 255) / 256;

  // ---- single memset for all zero-init scratch ----
  hipMemsetAsync(ws + z0, 0, z1 - z0, stream);

  // ---- CSR builds (both graphs; shared 3-phase scan) ----
  k_hist<<<eg, 256, 0, stream>>>(eer_idx, hcntA, neer);
  k_hist<<<ag, 256, 0, stream>>>(e_adj_index, hcntB, ne);
  k_scan_a<<<dim3(NB_SCAN, 2), 256, 0, stream>>>(hcntA, hcntB, bsum, KG_E);
  k_scan_b<<<1, 64, 0, stream>>>(bsum);
  k_scan_c<<<dim3(NB_SCAN, 2), 256, 0, stream>>>(hcntA, hcntB, bsum,
                                                 eer_start, adj_start, KG_E);
  k_scatter_eer<<<eg, 256, 0, stream>>>(eer_idx, eer_rel, eer_start, hfillA,
                                        eer_scol, eer_srel, neer);
  k_scatter_adj<<<ag, 256, 0, stream>>>(e_adj_index, e_adj_data, adj_start, hfillB,
                                        adj_scol, adj_sval, ne);

  // ---- compact r_head/r_tail + pack weights + primal fp16 ----
  k_compact2<<<dim3(NCH, KG_R, 2), 256, 0, stream>>>(r_head, r_tail, be_L, be_R,
                                                     lidx, lsv, rfill, rsumb);
  k_rmeta<<<(2 * KG_R + 255) / 256, 256, 0, stream>>>(rfill, rsumb, cnt, inv);
  k_packW<<<dim3(NT, NK), 64, 0, stream>>>(gcnW1, hwWr, Wp);
  int n4 = KG_E * E_DIM / 4;
  k_toh<<<(n4 + 255) / 256, 256, 0, stream>>>(primal, B0, n4);

  int rg = (KG_E + 3) / 4;

  // ---- attention layer 1: e1 = primal + 0.1*att(primal) -> B1 ----
  k_rlayer<<<2 * KG_R, 192, 0, stream>>>(B0, lidx, lsv, cnt, inv, atten_r, wpk);
  k_att_csr<<<rg, 256, 0, stream>>>(B0, wpk, eer_start, eer_scol, eer_srel,
                                    B0, 0.1f, B1);
  // ---- attention layer 2: e2 = primal + 0.3*att(e1) -> B2 ----
  k_rlayer<<<2 * KG_R, 192, 0, stream>>>(B1, lidx, lsv, cnt, inv, atten_r, wpk);
  k_att_csr<<<rg, 256, 0, stream>>>(B1, wpk, eer_start, eer_scol, eer_srel,
                                    B0, 0.3f, B2);

  // ---- GCN + highway 1: Fb,Gb = e2 @ {gcnW1,hwWr}; g2 -> B1 ----
  dim3 gg((KG_E + 31) / 32, 5);
  k_gemm2_mfma<<<gg, 256, 0, stream>>>(B2, Wp, Fb, Gb, KG_E);
  k_spmm_hw<<<rg, 256, 0, stream>>>(Fb, adj_start, adj_scol, adj_sval,
                                    Gb, B2, hwbr, B1, (float*)nullptr);

  // ---- GCN + highway 2: Fb,Gb = g2 @ {gcnW1,hwWr}; out = highway ----
  k_gemm2_mfma<<<gg, 256, 0, stream>>>(B1, Wp, Fb, Gb, KG_E);
  k_spmm_hw<<<rg, 256, 0, stream>>>(Fb, adj_start, adj_scol, adj_sval,
                                    Gb, B1, hwbr, (__half*)nullptr, out);
}

// Round 12
// 766.728 us; speedup vs baseline: 1.8630x; 1.0320x over previous
//
#include <hip/hip_runtime.h>
#include <hip/hip_fp16.h>
#include <math.h>

#define KG_E  50000
#define KG_R  500
#define E_DIM 300
#define NPAIR 150         // E_DIM/2 fp16 pairs per row
#define NP2   75          // E_DIM/4 uint2 per row
#define CAP   1024
#define LRELU 0.2f

// MFMA GEMM geometry: Y[M,600(pad 640)] = X[M,300(pad 320)] @ Wcat
#define NK    10
#define NT    40
#define XS_LD 328

#define NB_SCAN 49        // ceil(KG_E/1024)

typedef __attribute__((ext_vector_type(8))) _Float16 f16x8;
typedef __attribute__((ext_vector_type(4))) float f32x4;

__device__ __forceinline__ __half2 u2h2(unsigned u) {
  union { unsigned u; __half2 h; } v; v.u = u; return v.h;
}
__device__ __forceinline__ unsigned h22u(__half2 h) {
  union { unsigned u; __half2 h; } v; v.h = h; return v.u;
}
__device__ __forceinline__ float hlo(unsigned u) { return __low2float(u2h2(u)); }
__device__ __forceinline__ float hhi(unsigned u) { return __high2float(u2h2(u)); }
__device__ __forceinline__ unsigned packh(float lo, float hi) {
  return h22u(__floats2half2_rn(lo, hi));
}

// ---------------- f32 -> fp16 table conversion -----------------------------
__global__ __launch_bounds__(256) void k_toh(
    const float* __restrict__ src, __half* __restrict__ dst, int n4)
{
  int i = blockIdx.x * 256 + threadIdx.x;
  if (i >= n4) return;
  float4 f = ((const float4*)src)[i];
  uint2 o;
  o.x = packh(f.x, f.y);
  o.y = packh(f.z, f.w);
  ((uint2*)dst)[i] = o;
}

// ---------------- compaction: 16 floats/thread, wave prefix, LDS staged ----
#define NCH 5
#define SCAP 1024
#define NF4 2500          // float4s per chunk = (KG_E/NCH)/4
__global__ __launch_bounds__(256) void k_compact2(
    const float* __restrict__ r_head, const float* __restrict__ r_tail,
    const float* __restrict__ be_L, const float* __restrict__ be_R,
    int* __restrict__ lidx, float* __restrict__ lsval,
    int* __restrict__ fill, float* __restrict__ rsum)
{
  __shared__ int   ls_e[SCAP];
  __shared__ float ls_v[SCAP];
  __shared__ int   ls_cnt;
  __shared__ float ls_sum;
  __shared__ int   ls_base;
  int m = blockIdx.z;
  int r = blockIdx.y;
  const float* rowp = (m ? r_tail : r_head) + (size_t)r * KG_E;
  const float* be   = m ? be_R : be_L;
  int slot = m * KG_R + r;
  int lane = threadIdx.x & 63;
  if (threadIdx.x == 0) { ls_cnt = 0; ls_sum = 0.f; }
  __syncthreads();

  const int CH = KG_E / NCH;       // 10000
  int c0 = blockIdx.x * CH;
  const float4* rp4 = (const float4*)(rowp + c0);
  float lsum = 0.f;

  #pragma unroll
  for (int i = 0; i < (NF4 + 1023) / 1024; ++i) {      // 3 granules
    int fi0 = i * 1024 + threadIdx.x;
    float vals[16];
    #pragma unroll
    for (int k = 0; k < 4; ++k) {
      int fi = fi0 + k * 256;
      float4 f = (fi < NF4) ? rp4[fi] : make_float4(0.f, 0.f, 0.f, 0.f);
      vals[k*4+0] = f.x; vals[k*4+1] = f.y; vals[k*4+2] = f.z; vals[k*4+3] = f.w;
    }
    int cnt16 = 0;
    #pragma unroll
    for (int q = 0; q < 16; ++q) {
      lsum += vals[q];
      cnt16 += (vals[q] != 0.f) ? 1 : 0;
    }
    int pre = cnt16;
    #pragma unroll
    for (int off = 1; off < 64; off <<= 1) {
      int u = __shfl_up(pre, off, 64);
      if (lane >= off) pre += u;
    }
    int wave_base = 0;
    if (lane == 63 && pre > 0) wave_base = atomicAdd(&ls_cnt, pre);
    wave_base = __shfl(wave_base, 63, 64);
    if (cnt16 > 0) {
      int o = wave_base + pre - cnt16;
      #pragma unroll
      for (int k = 0; k < 4; ++k) {
        int fi = fi0 + k * 256;
        #pragma unroll
        for (int q = 0; q < 4; ++q) {
          float v = vals[k*4+q];
          if (v != 0.f) {
            if (o < SCAP) {
              int e = c0 + fi * 4 + q;
              ls_e[o] = e;
              ls_v[o] = v * be[e];
            }
            ++o;
          }
        }
      }
    }
  }
  #pragma unroll
  for (int off = 32; off > 0; off >>= 1) lsum += __shfl_xor(lsum, off, 64);
  if (lane == 0 && lsum != 0.f) atomicAdd(&ls_sum, lsum);
  __syncthreads();

  int total = ls_cnt < SCAP ? ls_cnt : SCAP;
  if (threadIdx.x == 0) {
    ls_base = atomicAdd(&fill[slot], total);
    if (ls_sum != 0.f) atomicAdd(&rsum[slot], ls_sum);
  }
  __syncthreads();
  int gbase = ls_base;
  int*   li = lidx  + (size_t)slot * CAP;
  float* lv = lsval + (size_t)slot * CAP;
  for (int i = threadIdx.x; i < total; i += 256) {
    int pos = gbase + i;
    if (pos < CAP) { li[pos] = ls_e[i]; lv[pos] = ls_v[i]; }
  }
}

__global__ __launch_bounds__(256) void k_rmeta(
    const int* __restrict__ fill, const float* __restrict__ rsum,
    int* __restrict__ cnt, float* __restrict__ inv)
{
  int i = blockIdx.x * 256 + threadIdx.x;
  if (i < 2 * KG_R) {
    int c = fill[i];
    cnt[i] = c > CAP ? CAP : c;
    float s = rsum[i];
    inv[i] = (s == 0.f) ? 0.f : 1.f / s;
  }
}

// ---------------- r-layer: fp16 pair gathers, f32 accum, packed-h2 out -----
__global__ __launch_bounds__(192) void k_rlayer(
    const __half* __restrict__ Eb, const int* __restrict__ lidx,
    const float* __restrict__ lsval, const int* __restrict__ cnt,
    const float* __restrict__ inv, const float* __restrict__ atten,
    unsigned* __restrict__ wpk)
{
  int b = blockIdx.x;
  int m = b / KG_R, r = b % KG_R;
  int p = threadIdx.x;
  if (p >= NPAIR) return;
  int slot = m * KG_R + r;
  int n = cnt[slot];
  const int*   li = lidx  + (size_t)slot * CAP;
  const float* lv = lsval + (size_t)slot * CAP;
  float alo = 0.f, ahi = 0.f;
  #pragma unroll 4
  for (int i = 0; i < n; ++i) {
    int e = li[i];
    float s = lv[i];
    unsigned u = ((const unsigned*)(Eb + (size_t)e * E_DIM))[p];
    alo += s * hlo(u);
    ahi += s * hhi(u);
  }
  float iv = inv[slot];
  float vlo = alo * iv; vlo = vlo > 0.f ? vlo : 0.f;
  float vhi = ahi * iv; vhi = vhi > 0.f ? vhi : 0.f;
  vlo *= atten[m * E_DIM + 2 * p];
  vhi *= atten[m * E_DIM + 2 * p + 1];
  wpk[(size_t)slot * NPAIR + p] = packh(vlo, vhi);
}

// ---------------- CSR build: histogram, 3-phase scan, scatter --------------
__global__ __launch_bounds__(256) void k_hist(
    const int* __restrict__ rows, int* __restrict__ cnt, int n)
{
  int i = blockIdx.x * 256 + threadIdx.x;
  if (i < n) atomicAdd(&cnt[rows[i]], 1);
}

__global__ __launch_bounds__(256) void k_scan_a(
    const int* __restrict__ c0, const int* __restrict__ c1,
    int* __restrict__ bsum, int n)
{
  const int* c = blockIdx.y ? c1 : c0;
  int base = blockIdx.x * 1024;
  int s = 0;
  #pragma unroll
  for (int k = 0; k < 4; ++k) {
    int i = base + k * 256 + threadIdx.x;
    if (i < n) s += c[i];
  }
  #pragma unroll
  for (int off = 32; off > 0; off >>= 1) s += __shfl_xor(s, off, 64);
  __shared__ int ws[4];
  if ((threadIdx.x & 63) == 0) ws[threadIdx.x >> 6] = s;
  __syncthreads();
  if (threadIdx.x == 0)
    bsum[blockIdx.y * (NB_SCAN + 1) + blockIdx.x] = ws[0] + ws[1] + ws[2] + ws[3];
}

__global__ __launch_bounds__(64) void k_scan_b(int* __restrict__ bsum)
{
  if (threadIdx.x < 2) {
    int* b = bsum + threadIdx.x * (NB_SCAN + 1);
    int acc = 0;
    for (int i = 0; i < NB_SCAN; ++i) { int v = b[i]; b[i] = acc; acc += v; }
    b[NB_SCAN] = acc;
  }
}

__global__ __launch_bounds__(256) void k_scan_c(
    const int* __restrict__ c0, const int* __restrict__ c1,
    const int* __restrict__ bsum,
    int* __restrict__ s0, int* __restrict__ s1, int n)
{
  const int* c = blockIdx.y ? c1 : c0;
  int* sO = blockIdx.y ? s1 : s0;
  if (blockIdx.x == 0 && threadIdx.x == 0)
    sO[n] = bsum[blockIdx.y * (NB_SCAN + 1) + NB_SCAN];
  int boff = bsum[blockIdx.y * (NB_SCAN + 1) + blockIdx.x];
  int i0 = blockIdx.x * 1024 + threadIdx.x * 4;
  int4 v = {0, 0, 0, 0};
  if (i0 < n) v = ((const int4*)c)[i0 >> 2];
  int tsum = v.x + v.y + v.z + v.w;
  int lane = threadIdx.x & 63, wid = threadIdx.x >> 6;
  int inc = tsum;
  #pragma unroll
  for (int off = 1; off < 64; off <<= 1) {
    int u = __shfl_up(inc, off, 64);
    if (lane >= off) inc += u;
  }
  __shared__ int ws[4];
  if (lane == 63) ws[wid] = inc;
  __syncthreads();
  int woff = 0;
  if (wid > 0) woff += ws[0];
  if (wid > 1) woff += ws[1];
  if (wid > 2) woff += ws[2];
  int ex = boff + woff + inc - tsum;
  if (i0 < n) {
    int4 o;
    o.x = ex; o.y = ex + v.x; o.z = o.y + v.y; o.w = o.z + v.z;
    ((int4*)sO)[i0 >> 2] = o;
  }
}

__global__ __launch_bounds__(256) void k_scatter_eer(
    const int* __restrict__ eidx, const int* __restrict__ erel,
    const int* __restrict__ start, int* __restrict__ fill,
    int* __restrict__ scol, int* __restrict__ srel, int neer)
{
  int i = blockIdx.x * 256 + threadIdx.x;
  if (i >= neer) return;
  int row = eidx[i];
  int pos = start[row] + atomicAdd(&fill[row], 1);
  scol[pos] = eidx[neer + i];
  srel[pos] = erel[i];
}

__global__ __launch_bounds__(256) void k_scatter_adj(
    const int* __restrict__ aidx, const float* __restrict__ adata,
    const int* __restrict__ start, int* __restrict__ fill,
    int* __restrict__ scol, float* __restrict__ sval, int ne)
{
  int i = blockIdx.x * 256 + threadIdx.x;
  if (i >= ne) return;
  int row = aidx[i];
  int pos = start[row] + atomicAdd(&fill[row], 1);
  scol[pos] = aidx[ne + i];
  sval[pos] = adata[i];
}

// ---------------- attention: half-wave, fp16 math, ec-gather prefetch ------
__global__ __launch_bounds__(256) void k_att_csr(
    const __half* __restrict__ Eb, const unsigned* __restrict__ wpk,
    const int* __restrict__ start, const int* __restrict__ scol,
    const int* __restrict__ srel, const __half* __restrict__ baseb,
    float alpha, __half* __restrict__ outb)
{
  int wave = threadIdx.x >> 6, lane = threadIdx.x & 63;
  int half = lane >> 5, hl = lane & 31;
  int row = blockIdx.x * 4 + wave;
  if (row >= KG_E) return;
  int s = start[row], e = start[row + 1];
  const uint2* erp = (const uint2*)(Eb + (size_t)row * E_DIM);
  __half2 zero2 = __floats2half2_rn(0.f, 0.f);
  __half2 er[3][2], ac[3][2];
  #pragma unroll
  for (int c = 0; c < 3; ++c) {
    int m = c * 32 + hl;
    if (m < NP2) {
      uint2 u = erp[m];
      er[c][0] = u2h2(u.x); er[c][1] = u2h2(u.y);
    } else { er[c][0] = zero2; er[c][1] = zero2; }
    ac[c][0] = zero2; ac[c][1] = zero2;
  }
  float rs = 0.f;
  int nIter = (e - s + 1) >> 1;

  // pipeline stage registers: prefetched ec gather + rel for current edge
  bool actA = false; int relA = 0;
  uint2 CA[3];
  #pragma unroll
  for (int c = 0; c < 3; ++c) CA[c] = make_uint2(0u, 0u);
  {
    int j0 = s + half;
    if (nIter > 0 && j0 < e) {
      actA = true;
      int col = scol[j0]; relA = srel[j0];
      const uint2* ecp = (const uint2*)(Eb + (size_t)col * E_DIM);
      #pragma unroll
      for (int c = 0; c < 3; ++c) {
        int m = c * 32 + hl;
        if (m < NP2) CA[c] = ecp[m];
      }
    }
  }

  for (int it = 0; it < nIter; ++it) {
    // ---- prefetch next edge's ec gather ----
    bool actB = false; int relB = 0;
    uint2 CB[3];
    #pragma unroll
    for (int c = 0; c < 3; ++c) CB[c] = make_uint2(0u, 0u);
    {
      int jn = s + 2 * (it + 1) + half;
      if (it + 1 < nIter && jn < e) {
        actB = true;
        int col = scol[jn]; relB = srel[jn];
        const uint2* ecp = (const uint2*)(Eb + (size_t)col * E_DIM);
        #pragma unroll
        for (int c = 0; c < 3; ++c) {
          int m = c * 32 + hl;
          if (m < NP2) CB[c] = ecp[m];
        }
      }
    }
    // ---- compute current (wh/wt loads inline; L2-hot 600KB table) ----
    const uint2* whp = (const uint2*)(wpk + (size_t)relA * NPAIR);
    const uint2* wtp = (const uint2*)(wpk + (size_t)(KG_R + relA) * NPAIR);
    __half2 p2a = zero2, p2b = zero2;
    #pragma unroll
    for (int c = 0; c < 3; ++c) {
      int m = c * 32 + hl;
      if (m < NP2) {
        uint2 uh = whp[m], ut = wtp[m];
        p2a = __hfma2(er[c][0], u2h2(uh.x), p2a);
        p2b = __hfma2(er[c][1], u2h2(uh.y), p2b);
        p2a = __hfma2(u2h2(CA[c].x), u2h2(ut.x), p2a);
        p2b = __hfma2(u2h2(CA[c].y), u2h2(ut.y), p2b);
      }
    }
    __half2 p2 = __hadd2(p2a, p2b);
    float p4 = __low2float(p2) + __high2float(p2);
    #pragma unroll
    for (int off = 16; off > 0; off >>= 1) p4 += __shfl_xor(p4, off, 64);
    float la = p4 >= 0.f ? p4 : LRELU * p4;
    float at = actA ? __expf(-la) : 0.f;
    rs += at;
    __half2 at2 = __float2half2_rn(at);
    #pragma unroll
    for (int c = 0; c < 3; ++c) {
      ac[c][0] = __hfma2(at2, u2h2(CA[c].x), ac[c][0]);
      ac[c][1] = __hfma2(at2, u2h2(CA[c].y), ac[c][1]);
    }
    // ---- rotate pipeline ----
    actA = actB; relA = relB;
    #pragma unroll
    for (int c = 0; c < 3; ++c) CA[c] = CB[c];
  }
  // merge halves
  rs += __shfl_xor(rs, 32, 64);
  #pragma unroll
  for (int c = 0; c < 3; ++c) {
    #pragma unroll
    for (int k = 0; k < 2; ++k) {
      unsigned o = __shfl_xor(h22u(ac[c][k]), 32, 64);
      ac[c][k] = __hadd2(ac[c][k], u2h2(o));
    }
  }
  if (half == 0) {
    float iv = (rs == 0.f) ? 0.f : 1.f / rs;
    const uint2* bp = (const uint2*)(baseb + (size_t)row * E_DIM);
    uint2* op = (uint2*)(outb + (size_t)row * E_DIM);
    #pragma unroll
    for (int c = 0; c < 3; ++c) {
      int m = c * 32 + hl;
      if (m < NP2) {
        uint2 ub = bp[m];
        float v0 = __low2float(ac[c][0]) * iv;  v0 = v0 > 0.f ? v0 : 0.f;
        float v1 = __high2float(ac[c][0]) * iv; v1 = v1 > 0.f ? v1 : 0.f;
        float v2 = __low2float(ac[c][1]) * iv;  v2 = v2 > 0.f ? v2 : 0.f;
        float v3 = __high2float(ac[c][1]) * iv; v3 = v3 > 0.f ? v3 : 0.f;
        uint2 o2;
        o2.x = packh(hlo(ub.x) + alpha * v0, hhi(ub.x) + alpha * v1);
        o2.y = packh(hlo(ub.y) + alpha * v2, hhi(ub.y) + alpha * v3);
        op[m] = o2;
      }
    }
  }
}

// ---------------- fused spmm + highway: half-wave, gather prefetch ---------
__global__ __launch_bounds__(256) void k_spmm_hw(
    const __half* __restrict__ Xb, const int* __restrict__ start,
    const int* __restrict__ scol, const float* __restrict__ sval,
    const __half* __restrict__ Gb, const __half* __restrict__ baseb,
    const float* __restrict__ br,
    __half* __restrict__ outb, float* __restrict__ outf)
{
  int wave = threadIdx.x >> 6, lane = threadIdx.x & 63;
  int half = lane >> 5, hl = lane & 31;
  int row = blockIdx.x * 4 + wave;
  if (row >= KG_E) return;
  int s = start[row], e = start[row + 1];
  float ac0[3] = {0,0,0}, ac1[3] = {0,0,0}, ac2[3] = {0,0,0}, ac3[3] = {0,0,0};
  int nIter = (e - s + 1) >> 1;

  float vA = 0.f;
  uint2 XA[3];
  #pragma unroll
  for (int c = 0; c < 3; ++c) XA[c] = make_uint2(0u, 0u);
  {
    int j0 = s + half;
    if (nIter > 0 && j0 < e) {
      int col = scol[j0]; vA = sval[j0];
      const uint2* xp = (const uint2*)(Xb + (size_t)col * E_DIM);
      #pragma unroll
      for (int c = 0; c < 3; ++c) {
        int m = c * 32 + hl;
        if (m < NP2) XA[c] = xp[m];
      }
    }
  }
  for (int it = 0; it < nIter; ++it) {
    float vB = 0.f;
    uint2 XB[3];
    #pragma unroll
    for (int c = 0; c < 3; ++c) XB[c] = make_uint2(0u, 0u);
    {
      int jn = s + 2 * (it + 1) + half;
      if (it + 1 < nIter && jn < e) {
        int col = scol[jn]; vB = sval[jn];
        const uint2* xp = (const uint2*)(Xb + (size_t)col * E_DIM);
        #pragma unroll
        for (int c = 0; c < 3; ++c) {
          int m = c * 32 + hl;
          if (m < NP2) XB[c] = xp[m];
        }
      }
    }
    #pragma unroll
    for (int c = 0; c < 3; ++c) {
      ac0[c] += vA * hlo(XA[c].x); ac1[c] += vA * hhi(XA[c].x);
      ac2[c] += vA * hlo(XA[c].y); ac3[c] += vA * hhi(XA[c].y);
    }
    vA = vB;
    #pragma unroll
    for (int c = 0; c < 3; ++c) XA[c] = XB[c];
  }
  #pragma unroll
  for (int c = 0; c < 3; ++c) {
    ac0[c] += __shfl_xor(ac0[c], 32, 64);
    ac1[c] += __shfl_xor(ac1[c], 32, 64);
    ac2[c] += __shfl_xor(ac2[c], 32, 64);
    ac3[c] += __shfl_xor(ac3[c], 32, 64);
  }
  if (half == 0) {
    const uint2* gp = (const uint2*)(Gb + (size_t)row * E_DIM);
    const uint2* bp = (const uint2*)(baseb + (size_t)row * E_DIM);
    #pragma unroll
    for (int c = 0; c < 3; ++c) {
      int m = c * 32 + hl;
      if (m < NP2) {
        uint2 ug = gp[m], ub = bp[m];
        float4 b4 = ((const float4*)br)[m];
        float g0 = 1.f / (1.f + __expf(-(hlo(ug.x) + b4.x)));
        float g1 = 1.f / (1.f + __expf(-(hhi(ug.x) + b4.y)));
        float g2 = 1.f / (1.f + __expf(-(hlo(ug.y) + b4.z)));
        float g3 = 1.f / (1.f + __expf(-(hhi(ug.y) + b4.w)));
        float y0 = ac0[c] > 0.f ? ac0[c] : 0.f;
        float y1 = ac1[c] > 0.f ? ac1[c] : 0.f;
        float y2 = ac2[c] > 0.f ? ac2[c] : 0.f;
        float y3 = ac3[c] > 0.f ? ac3[c] : 0.f;
        float o0 = g0 * y0 + (1.f - g0) * hlo(ub.x);
        float o1 = g1 * y1 + (1.f - g1) * hhi(ub.x);
        float o2 = g2 * y2 + (1.f - g2) * hlo(ub.y);
        float o3 = g3 * y3 + (1.f - g3) * hhi(ub.y);
        if (outb) {
          uint2 ov;
          ov.x = packh(o0, o1); ov.y = packh(o2, o3);
          ((uint2*)(outb + (size_t)row * E_DIM))[m] = ov;
        } else {
          float4 of; of.x = o0; of.y = o1; of.z = o2; of.w = o3;
          ((float4*)(outf + (size_t)row * E_DIM))[m] = of;
        }
      }
    }
  }
}

// ---------------- pack W into MFMA B-fragment layout (fp16) ----------------
__global__ __launch_bounds__(64) void k_packW(
    const float* __restrict__ W1, const float* __restrict__ W2,
    __half* __restrict__ Wp)
{
  int lane = threadIdx.x;
  int t = blockIdx.x, s = blockIdx.y;
  int c = t * 16 + (lane & 15);
  __half v[8];
  #pragma unroll
  for (int j = 0; j < 8; ++j) {
    int k = s * 32 + (lane >> 4) * 8 + j;
    float x = 0.f;
    if (k < E_DIM && c < 2 * E_DIM)
      x = (c < E_DIM) ? W1[(size_t)k * E_DIM + c]
                      : W2[(size_t)k * E_DIM + (c - E_DIM)];
    v[j] = __float2half_rn(x);
  }
  size_t base = ((size_t)(t * NK + s) * 64 + lane) * 8;
  #pragma unroll
  for (int j = 0; j < 8; ++j) Wp[base + j] = v[j];
}

// ---------------- fused dual-GEMM: Y1,Y2 (fp16) = X @ {gcnW1, hwWr} --------
__global__ __launch_bounds__(256) void k_gemm2_mfma(
    const __half* __restrict__ Xb, const __half* __restrict__ Wp,
    __half* __restrict__ Y1, __half* __restrict__ Y2, int M)
{
  __shared__ __half Xs[32][XS_LD];
  int tid = threadIdx.x;
  int r0 = blockIdx.x * 32;
  int nb = blockIdx.y;

  for (int t = tid; t < 32 * (XS_LD / 2); t += 256) {
    int r = t / (XS_LD / 2), u = t % (XS_LD / 2);
    unsigned v = 0;
    int rg = r0 + r;
    if (rg < M && u < E_DIM / 2) v = ((const unsigned*)Xb)[(size_t)rg * (E_DIM / 2) + u];
    ((unsigned*)&Xs[0][0])[r * (XS_LD / 2) + u] = v;
  }
  __syncthreads();

  int wid = tid >> 6, lane = tid & 63;
  int wave_m = wid >> 1, wave_n = wid & 1;
  int rowA = wave_m * 16 + (lane & 15);
  int kgrp = (lane >> 4) * 8;
  int tb0 = nb * 8 + wave_n * 4;

  const f16x8* wfrag = (const f16x8*)Wp + (size_t)tb0 * (NK * 64) + lane;

  f32x4 acc[4] = {{0,0,0,0},{0,0,0,0},{0,0,0,0},{0,0,0,0}};
  #pragma unroll 2
  for (int ks = 0; ks < NK; ++ks) {
    f16x8 a = *(const f16x8*)&Xs[rowA][ks * 32 + kgrp];
    #pragma unroll
    for (int nt = 0; nt < 4; ++nt) {
      f16x8 b = wfrag[(nt * NK + ks) * 64];
      acc[nt] = __builtin_amdgcn_mfma_f32_16x16x32_f16(a, b, acc[nt], 0, 0, 0);
    }
  }

  int rbase = r0 + wave_m * 16 + ((lane >> 4) << 2);
  #pragma unroll
  for (int nt = 0; nt < 4; ++nt) {
    int c = (tb0 + nt) * 16 + (lane & 15);
    #pragma unroll
    for (int j = 0; j < 4; ++j) {
      int row = rbase + j;
      if (row < M) {
        __half hv = __float2half_rn(acc[nt][j]);
        if (c < E_DIM)            Y1[(size_t)row * E_DIM + c] = hv;
        else if (c < 2 * E_DIM)   Y2[(size_t)row * E_DIM + (c - E_DIM)] = hv;
      }
    }
  }
}

extern "C" void kernel_launch(void* const* d_in, const int* in_sizes, int n_in,
                              void* d_out, int out_size, void* d_ws, size_t ws_size,
                              hipStream_t stream)
{
  const float* primal      = (const float*)d_in[0];
  const float* r_head      = (const float*)d_in[1];
  const float* r_tail      = (const float*)d_in[2];
  const float* e_adj_data  = (const float*)d_in[3];
  const float* be_L        = (const float*)d_in[4];
  const float* be_R        = (const float*)d_in[5];
  const float* atten_r     = (const float*)d_in[6];
  const float* gcnW1       = (const float*)d_in[7];
  const float* hwWr        = (const float*)d_in[8];
  const float* hwbr        = (const float*)d_in[9];
  const int*   e_adj_index = (const int*)d_in[10];
  const int*   eer_idx     = (const int*)d_in[11];
  const int*   eer_rel     = (const int*)d_in[12];
  int ne   = in_sizes[10] / 2;
  int neer = in_sizes[11] / 2;

  char* ws = (char*)d_ws;
  size_t off = 0;
  auto take = [&](size_t bytes) {
    void* p = ws + off;
    off = (off + bytes + 255) & ~(size_t)255;
    return p;
  };
  int*   cnt      = (int*)  take((size_t)2 * KG_R * sizeof(int));
  float* inv      = (float*)take((size_t)2 * KG_R * sizeof(float));
  // ---- contiguous zero-init block (single memset) ----
  size_t z0 = off;
  int*   hcntA    = (int*)  take((size_t)KG_E * sizeof(int));
  int*   hcntB    = (int*)  take((size_t)KG_E * sizeof(int));
  int*   hfillA   = (int*)  take((size_t)KG_E * sizeof(int));
  int*   hfillB   = (int*)  take((size_t)KG_E * sizeof(int));
  int*   rfill    = (int*)  take((size_t)2 * KG_R * sizeof(int));
  float* rsumb    = (float*)take((size_t)2 * KG_R * sizeof(float));
  size_t z1 = off;
  // ----------------------------------------------------
  int*   lidx     = (int*)  take((size_t)2 * KG_R * CAP * sizeof(int));
  float* lsv      = (float*)take((size_t)2 * KG_R * CAP * sizeof(float));
  unsigned* wpk   = (unsigned*)take((size_t)2 * KG_R * NPAIR * sizeof(unsigned));
  int*   bsum     = (int*)  take((size_t)2 * (NB_SCAN + 1) * sizeof(int));
  int*   eer_start= (int*)  take((size_t)(KG_E + 4) * sizeof(int));
  int*   adj_start= (int*)  take((size_t)(KG_E + 4) * sizeof(int));
  int*   eer_scol = (int*)  take((size_t)neer * sizeof(int));
  int*   eer_srel = (int*)  take((size_t)neer * sizeof(int));
  int*   adj_scol = (int*)  take((size_t)ne * sizeof(int));
  float* adj_sval = (float*)take((size_t)ne * sizeof(float));
  __half* Wp = (__half*)take((size_t)NT * NK * 64 * 8 * sizeof(__half));
  __half* B0 = (__half*)take((size_t)KG_E * E_DIM * sizeof(__half)); // primal fp16
  __half* B1 = (__half*)take((size_t)KG_E * E_DIM * sizeof(__half)); // e1 / g2
  __half* B2 = (__half*)take((size_t)KG_E * E_DIM * sizeof(__half)); // e2
  __half* Fb = (__half*)take((size_t)KG_E * E_DIM * sizeof(__half)); // X@gcnW1
  __half* Gb = (__half*)take((size_t)KG_E * E_DIM * sizeof(__half)); // X@hwWr
  float* out      = (float*)d_out;
  (void)ws_size; (void)n_in; (void)out_size;

  int eg = (neer + 255) / 256;
  int ag = (ne + 255) / 256;

  // ---- single memset for all zero-init scratch ----
  hipMemsetAsync(ws + z0, 0, z1 - z0, stream);

  // ---- CSR builds (both graphs; shared 3-phase scan) ----
  k_hist<<<eg, 256, 0, stream>>>(eer_idx, hcntA, neer);
  k_hist<<<ag, 256, 0, stream>>>(e_adj_index, hcntB, ne);
  k_scan_a<<<dim3(NB_SCAN, 2), 256, 0, stream>>>(hcntA, hcntB, bsum, KG_E);
  k_scan_b<<<1, 64, 0, stream>>>(bsum);
  k_scan_c<<<dim3(NB_SCAN, 2), 256, 0, stream>>>(hcntA, hcntB, bsum,
                                                 eer_start, adj_start, KG_E);
  k_scatter_eer<<<eg, 256, 0, stream>>>(eer_idx, eer_rel, eer_start, hfillA,
                                        eer_scol, eer_srel, neer);
  k_scatter_adj<<<ag, 256, 0, stream>>>(e_adj_index, e_adj_data, adj_start, hfillB,
                                        adj_scol, adj_sval, ne);

  // ---- compact r_head/r_tail + pack weights + primal fp16 ----
  k_compact2<<<dim3(NCH, KG_R, 2), 256, 0, stream>>>(r_head, r_tail, be_L, be_R,
                                                     lidx, lsv, rfill, rsumb);
  k_rmeta<<<(2 * KG_R + 255) / 256, 256, 0, stream>>>(rfill, rsumb, cnt, inv);
  k_packW<<<dim3(NT, NK), 64, 0, stream>>>(gcnW1, hwWr, Wp);
  int n4 = KG_E * E_DIM / 4;
  k_toh<<<(n4 + 255) / 256, 256, 0, stream>>>(primal, B0, n4);

  int rg = (KG_E + 3) / 4;

  // ---- attention layer 1: e1 = primal + 0.1*att(primal) -> B1 ----
  k_rlayer<<<2 * KG_R, 192, 0, stream>>>(B0, lidx, lsv, cnt, inv, atten_r, wpk);
  k_att_csr<<<rg, 256, 0, stream>>>(B0, wpk, eer_start, eer_scol, eer_srel,
                                    B0, 0.1f, B1);
  // ---- attention layer 2: e2 = primal + 0.3*att(e1) -> B2 ----
  k_rlayer<<<2 * KG_R, 192, 0, stream>>>(B1, lidx, lsv, cnt, inv, atten_r, wpk);
  k_att_csr<<<rg, 256, 0, stream>>>(B1, wpk, eer_start, eer_scol, eer_srel,
                                    B0, 0.3f, B2);

  // ---- GCN + highway 1: Fb,Gb = e2 @ {gcnW1,hwWr}; g2 -> B1 ----
  dim3 gg((KG_E + 31) / 32, 5);
  k_gemm2_mfma<<<gg, 256, 0, stream>>>(B2, Wp, Fb, Gb, KG_E);
  k_spmm_hw<<<rg, 256, 0, stream>>>(Fb, adj_start, adj_scol, adj_sval,
                                    Gb, B2, hwbr, B1, (float*)nullptr);

  // ---- GCN + highway 2: Fb,Gb = g2 @ {gcnW1,hwWr}; out = highway ----
  k_gemm2_mfma<<<gg, 256, 0, stream>>>(B1, Wp, Fb, Gb, KG_E);
  k_spmm_hw<<<rg, 256, 0, stream>>>(Fb, adj_start, adj_scol, adj_sval,
                                    Gb, B1, hwbr, (__half*)nullptr, out);
}